// Round 1
// baseline (1503.478 us; speedup 1.0000x reference)
//
#include <hip/hip_runtime.h>
#include <cstddef>
#include <algorithm>

#define KN 9

// ---------------------------------------------------------------------------
// one-hot row -> column index (pool matrices are one-hot gathers)
// ---------------------------------------------------------------------------
__global__ void extract_idx(const float* __restrict__ L, int M, int* __restrict__ out)
{
    int p = blockIdx.x;
    const float* row = L + (size_t)p * M;
    for (int m = threadIdx.x; m < M; m += 256)
        if (row[m] > 0.5f) out[p] = m;   // exactly one 1.0 per row
}

// ---------------------------------------------------------------------------
// gather rows (dense one-hot spmm == gather): out[b,p,:] = in[b,idx[p],:]
// ---------------------------------------------------------------------------
__global__ void gather_rows(const float* __restrict__ in, const int* __restrict__ idx,
                            float* __restrict__ out, int Nin, int P, int F4, int total)
{
    int t = blockIdx.x * 256 + threadIdx.x;
    if (t >= total) return;
    int f  = t % F4;
    int bp = t / F4;
    int p  = bp % P;
    int b  = bp / P;
    const float4* src = (const float4*)in;
    ((float4*)out)[t] = src[((size_t)b * Nin + idx[p]) * F4 + f];
}

// ---------------------------------------------------------------------------
// FeaSt "attention" part: per (b, row) wave computes
//   xn[f][i] = x[b, nbr[n,i], f]          (i = neighbor slot)
//   L[i][j]  = bm[i] + sum_f (xn[f][j]-xn[f][0]) * wm[i][f]
//   P[i][j]  = softmax_i L[i][j]
//   agg[f][j]= sum_i xn[f][i] * P[i][j]   -> agg row [F*9], q = f*9+j
// (derived from einsum 'bnfk,of->bnok' / softmax axis=2 / 'bnfk,bnko->bnfo':
//  the softmax axis is CONTRACTED with xn's neighbor axis.)
// n = sel ? sel[p] : p  (sel = fused encoder pooling row-selection)
// ---------------------------------------------------------------------------
template<int F>
__global__ __launch_bounds__(256) void feast_agg(
    const float* __restrict__ x, const int* __restrict__ nbr,
    const int* __restrict__ sel,
    const float* __restrict__ wm, const float* __restrict__ bm,
    float* __restrict__ agg,
    int Nin, int P, int m0, int Mc)
{
    constexpr int FS = (F % 4 == 0) ? F + 4 : F + 1;   // padded stride (bank + f4 align)
    constexpr int Q  = F * KN;
    __shared__ float s_wm[KN * FS];
    __shared__ float s_bm[KN];
    __shared__ float s_xn[4][KN * FS];
    __shared__ float s_lg[4][81];
    __shared__ float s_pm[4][81];
    __shared__ int   s_idx[4][KN];

    int tid = threadIdx.x, wid = tid >> 6, lane = tid & 63;
    for (int t = tid; t < KN * F; t += 256) { int i = t / F, f = t - i * F; s_wm[i * FS + f] = wm[t]; }
    if (tid < KN) s_bm[tid] = bm[tid];

    int wg = blockIdx.x * 4 + wid;
    bool aw = wg < Mc;
    int b = 0, p = 0, n = 0;
    if (aw) {
        int row = m0 + wg;
        b = row / P; p = row - b * P;
        n = sel ? sel[p] : p;
    }
    if (aw && lane < KN) s_idx[wid][lane] = nbr[n * KN + lane];
    __syncthreads();

    if (aw) {
        const float* xb = x + (size_t)b * Nin * F;
        if constexpr (F % 4 == 0) {
            constexpr int F4 = F / 4;
            for (int t = lane; t < KN * F4; t += 64) {
                int i = t / F4, f4 = t - i * F4;
                float4 v = *(const float4*)(xb + (size_t)s_idx[wid][i] * F + f4 * 4);
                *(float4*)&s_xn[wid][i * FS + f4 * 4] = v;
            }
        } else {
            for (int t = lane; t < KN * F; t += 64) {
                int i = t / F, f = t - i * F;
                s_xn[wid][i * FS + f] = xb[(size_t)s_idx[wid][i] * F + f];
            }
        }
    }
    __syncthreads();

    if (aw) {
        for (int pr = lane; pr < 81; pr += 64) {
            int i = pr / KN, j = pr - i * KN;
            float acc = s_bm[i];
            if constexpr (F % 4 == 0) {
                #pragma unroll 4
                for (int f = 0; f < F; f += 4) {
                    float4 xj = *(const float4*)&s_xn[wid][j * FS + f];
                    float4 x0 = *(const float4*)&s_xn[wid][f];
                    float4 wv = *(const float4*)&s_wm[i * FS + f];
                    acc += (xj.x - x0.x) * wv.x;
                    acc += (xj.y - x0.y) * wv.y;
                    acc += (xj.z - x0.z) * wv.z;
                    acc += (xj.w - x0.w) * wv.w;
                }
            } else {
                for (int f = 0; f < F; ++f)
                    acc += (s_xn[wid][j * FS + f] - s_xn[wid][f]) * s_wm[i * FS + f];
            }
            s_lg[wid][pr] = acc;
        }
    }
    __syncthreads();

    if (aw && lane < KN) {              // softmax over i for fixed j
        int j = lane;
        float mx = -1e30f;
        #pragma unroll
        for (int i = 0; i < KN; ++i) mx = fmaxf(mx, s_lg[wid][i * KN + j]);
        float sm = 0.f, ev[KN];
        #pragma unroll
        for (int i = 0; i < KN; ++i) { ev[i] = expf(s_lg[wid][i * KN + j] - mx); sm += ev[i]; }
        float inv = 1.f / sm;
        #pragma unroll
        for (int i = 0; i < KN; ++i) s_pm[wid][i * KN + j] = ev[i] * inv;
    }
    __syncthreads();

    if (aw) {
        float* out = agg + (size_t)wg * Q;
        for (int t = lane; t < Q; t += 64) {
            int f = t / KN, j = t - f * KN;
            float acc = 0.f;
            #pragma unroll
            for (int i = 0; i < KN; ++i) acc += s_xn[wid][i * FS + f] * s_pm[wid][i * KN + j];
            out[t] = acc;
        }
    }
}

// ---------------------------------------------------------------------------
// fully fused feast for layers where wc fits in LDS (e0: 64x27, d2: 3x576)
// ---------------------------------------------------------------------------
template<int F, int C, int ACT>
__global__ __launch_bounds__(256) void feast_fused(
    const float* __restrict__ x, const int* __restrict__ nbr,
    const int* __restrict__ sel,
    const float* __restrict__ wm, const float* __restrict__ bm,
    const float* __restrict__ wc, const float* __restrict__ bc,
    float* __restrict__ y,
    int Nin, int P, int Nlevel, int Mtot)
{
    constexpr int FS = (F % 4 == 0) ? F + 4 : F + 1;
    constexpr int Q  = F * KN;
    constexpr int CC = (C < 64) ? C : 64;
    constexpr int G  = 64 / CC;          // lanes cooperating per output channel
    __shared__ float s_wm[KN * FS];
    __shared__ float s_wc[C * Q];
    __shared__ float s_bm[KN];
    __shared__ float s_xn[4][KN * FS];
    __shared__ float s_lg[4][81];
    __shared__ float s_pm[4][81];
    __shared__ float s_ag[4][Q];
    __shared__ float s_red[4][64];
    __shared__ int   s_idx[4][KN];

    int tid = threadIdx.x, wid = tid >> 6, lane = tid & 63;
    for (int t = tid; t < KN * F; t += 256) { int i = t / F, f = t - i * F; s_wm[i * FS + f] = wm[t]; }
    for (int t = tid; t < C * Q; t += 256) s_wc[t] = wc[t];
    if (tid < KN) s_bm[tid] = bm[tid];

    int wg = blockIdx.x * 4 + wid;
    bool aw = wg < Mtot;
    int b = 0, p = 0, n = 0;
    if (aw) {
        b = wg / P; p = wg - b * P;
        n = sel ? sel[p] : p;
    }
    if (aw && lane < KN) s_idx[wid][lane] = nbr[n * KN + lane];
    __syncthreads();

    if (aw) {
        const float* xb = x + (size_t)b * Nin * F;
        if constexpr (F % 4 == 0) {
            constexpr int F4 = F / 4;
            for (int t = lane; t < KN * F4; t += 64) {
                int i = t / F4, f4 = t - i * F4;
                float4 v = *(const float4*)(xb + (size_t)s_idx[wid][i] * F + f4 * 4);
                *(float4*)&s_xn[wid][i * FS + f4 * 4] = v;
            }
        } else {
            for (int t = lane; t < KN * F; t += 64) {
                int i = t / F, f = t - i * F;
                s_xn[wid][i * FS + f] = xb[(size_t)s_idx[wid][i] * F + f];
            }
        }
    }
    __syncthreads();

    if (aw) {
        for (int pr = lane; pr < 81; pr += 64) {
            int i = pr / KN, j = pr - i * KN;
            float acc = s_bm[i];
            if constexpr (F % 4 == 0) {
                #pragma unroll 4
                for (int f = 0; f < F; f += 4) {
                    float4 xj = *(const float4*)&s_xn[wid][j * FS + f];
                    float4 x0 = *(const float4*)&s_xn[wid][f];
                    float4 wv = *(const float4*)&s_wm[i * FS + f];
                    acc += (xj.x - x0.x) * wv.x;
                    acc += (xj.y - x0.y) * wv.y;
                    acc += (xj.z - x0.z) * wv.z;
                    acc += (xj.w - x0.w) * wv.w;
                }
            } else {
                for (int f = 0; f < F; ++f)
                    acc += (s_xn[wid][j * FS + f] - s_xn[wid][f]) * s_wm[i * FS + f];
            }
            s_lg[wid][pr] = acc;
        }
    }
    __syncthreads();

    if (aw && lane < KN) {
        int j = lane;
        float mx = -1e30f;
        #pragma unroll
        for (int i = 0; i < KN; ++i) mx = fmaxf(mx, s_lg[wid][i * KN + j]);
        float sm = 0.f, ev[KN];
        #pragma unroll
        for (int i = 0; i < KN; ++i) { ev[i] = expf(s_lg[wid][i * KN + j] - mx); sm += ev[i]; }
        float inv = 1.f / sm;
        #pragma unroll
        for (int i = 0; i < KN; ++i) s_pm[wid][i * KN + j] = ev[i] * inv;
    }
    __syncthreads();

    if (aw) {
        for (int t = lane; t < Q; t += 64) {
            int f = t / KN, j = t - f * KN;
            float acc = 0.f;
            #pragma unroll
            for (int i = 0; i < KN; ++i) acc += s_xn[wid][i * FS + f] * s_pm[wid][i * KN + j];
            s_ag[wid][t] = acc;
        }
    }
    __syncthreads();

    // linear: G lanes per channel, strided partials, LDS reduce when G > 1
    if (aw) {
        int c  = lane / G;
        int st = lane - c * G;
        float partial = 0.f;
        if (c < CC) {
            for (int q = st; q < Q; q += G)
                partial += s_wc[c * Q + q] * s_ag[wid][q];
        }
        if constexpr (G == 1) {
            float val = partial + bc[c];
            if constexpr (ACT == 1) val = val > 0.f ? val : expm1f(val);
            if (n == Nlevel - 1) val = 0.f;
            y[(size_t)wg * C + c] = val;
        } else {
            s_red[wid][lane] = (c < CC) ? partial : 0.f;
        }
    }
    if constexpr (G > 1) {
        __syncthreads();
        if (aw && lane < C) {
            float s = 0.f;
            #pragma unroll
            for (int g = 0; g < G; ++g) s += s_red[wid][lane * G + g];
            float val = s + bc[lane];
            if constexpr (ACT == 1) val = val > 0.f ? val : expm1f(val);
            if (n == Nlevel - 1) val = 0.f;
            y[(size_t)wg * C + lane] = val;
        }
    }
}

// ---------------------------------------------------------------------------
// tiled fp32 GEMM: Y[m0+m, c] = act( sum_k A[m,k] * W[c,k] + bias[c] ), 64x64x32
// MASK zeroes rows whose vertex is the padding vertex (n == Nlevel-1).
// C must be a multiple of 64 (holds for 128/256/64/20480); Kd multiple of 32.
// ---------------------------------------------------------------------------
template<int ACT, bool MASK>
__global__ __launch_bounds__(256) void gemm_kernel(
    const float* __restrict__ A, const float* __restrict__ W,
    const float* __restrict__ bias, float* __restrict__ Y,
    const int* __restrict__ sel,
    int Mc, int m0, int Kd, int C, int P, int Nlevel)
{
    __shared__ float As[32][68];
    __shared__ float Ws[32][68];
    int tid = threadIdx.x;
    int mBase = blockIdx.x * 64, cBase = blockIdx.y * 64;
    int tx = tid & 15, ty = tid >> 4;
    float acc[4][4] = {};

    for (int k0 = 0; k0 < Kd; k0 += 32) {
        #pragma unroll
        for (int r = 0; r < 8; ++r) {
            int t = tid + r * 256;
            int kk = t & 31, i = t >> 5;
            int m = mBase + i;
            As[kk][i] = (m < Mc) ? A[(size_t)m * Kd + k0 + kk] : 0.f;
        }
        #pragma unroll
        for (int r = 0; r < 8; ++r) {
            int t = tid + r * 256;
            int kk = t & 31, i = t >> 5;
            Ws[kk][i] = W[(size_t)(cBase + i) * Kd + k0 + kk];
        }
        __syncthreads();
        #pragma unroll
        for (int kk = 0; kk < 32; ++kk) {
            float4 av = *(const float4*)&As[kk][ty * 4];
            float4 wv = *(const float4*)&Ws[kk][tx * 4];
            float a[4] = {av.x, av.y, av.z, av.w};
            float w[4] = {wv.x, wv.y, wv.z, wv.w};
            #pragma unroll
            for (int u = 0; u < 4; ++u)
                #pragma unroll
                for (int v = 0; v < 4; ++v)
                    acc[u][v] += a[u] * w[v];
        }
        __syncthreads();
    }

    #pragma unroll
    for (int u = 0; u < 4; ++u) {
        int m = mBase + ty * 4 + u;
        if (m >= Mc) continue;
        int gm = m0 + m;
        bool zero = false;
        if (MASK) {
            int pp = gm % P;
            int n = sel ? sel[pp] : pp;
            zero = (n == Nlevel - 1);
        }
        float* yr = Y + (size_t)gm * C + cBase + tx * 4;
        #pragma unroll
        for (int v = 0; v < 4; ++v) {
            float val = acc[u][v] + bias[cBase + tx * 4 + v];
            if (ACT == 1) val = val > 0.f ? val : expm1f(val);
            yr[v] = zero ? 0.f : val;
        }
    }
}

// ---------------------------------------------------------------------------
// latent encode: z[b,l] = sum_j x[b,j] * w[l,j] + bias[l]   (M=32,N=256,K=20480)
// one block per l; 32 accumulators per thread; wave shfl reduce.
// ---------------------------------------------------------------------------
__global__ __launch_bounds__(256) void fce_kernel(
    const float* __restrict__ x, const float* __restrict__ w,
    const float* __restrict__ bias, float* __restrict__ z)
{
    int l = blockIdx.x;
    const float* wr = w + (size_t)l * 20480;
    float acc[32];
    #pragma unroll
    for (int b = 0; b < 32; ++b) acc[b] = 0.f;
    for (int j = threadIdx.x; j < 20480; j += 256) {
        float wv = wr[j];
        #pragma unroll
        for (int b = 0; b < 32; ++b) acc[b] += x[b * 20480 + j] * wv;
    }
    __shared__ float s_part[4][32];
    int wid = threadIdx.x >> 6, lane = threadIdx.x & 63;
    #pragma unroll
    for (int b = 0; b < 32; ++b) {
        float v = acc[b];
        for (int off = 32; off > 0; off >>= 1) v += __shfl_down(v, off, 64);
        if (lane == 0) s_part[wid][b] = v;
    }
    __syncthreads();
    if (threadIdx.x < 32) {
        float s = s_part[0][threadIdx.x] + s_part[1][threadIdx.x]
                + s_part[2][threadIdx.x] + s_part[3][threadIdx.x];
        z[threadIdx.x * 256 + l] = s + bias[l];
    }
}

// ---------------------------------------------------------------------------
// host-side: one feast layer = chunked (agg kernel + GEMM), agg scratch bounded
// ---------------------------------------------------------------------------
template<int F>
static void run_layer(const float* xin, const int* nbr, const int* sel,
                      const float* wm, const float* bm,
                      const float* wc, const float* bcv, float* yout,
                      int Nin, int P, int Nlevel, int C,
                      float* aggbuf, size_t aggCap, hipStream_t stream)
{
    const int Kd = F * KN;
    const int M = 32 * P;
    long long capLL = (long long)(aggCap / (size_t)Kd);
    int cap = (int)std::min<long long>((long long)M, capLL);
    if (cap < 1) cap = 1;
    for (int m0 = 0; m0 < M; m0 += cap) {
        int ch = std::min(cap, M - m0);
        feast_agg<F><<<(ch + 3) / 4, 256, 0, stream>>>(xin, nbr, sel, wm, bm, aggbuf,
                                                       Nin, P, m0, ch);
        dim3 g((ch + 63) / 64, C / 64);
        gemm_kernel<1, true><<<g, 256, 0, stream>>>(aggbuf, wc, bcv, yout, sel,
                                                    ch, m0, Kd, C, P, Nlevel);
    }
}

extern "C" void kernel_launch(void* const* d_in, const int* in_sizes, int n_in,
                              void* d_out, int out_size, void* d_ws, size_t ws_size,
                              hipStream_t stream)
{
    const float* x     = (const float*)d_in[0];
    const int*   nbr0  = (const int*)d_in[1];
    const int*   nbr1  = (const int*)d_in[2];
    const int*   nbr2  = (const int*)d_in[3];
    const float* D0    = (const float*)d_in[4];
    const float* U0    = (const float*)d_in[5];
    const float* D1    = (const float*)d_in[6];
    const float* U1    = (const float*)d_in[7];
    const float* D2    = (const float*)d_in[8];
    const float* U2    = (const float*)d_in[9];
    const float* e0_wm = (const float*)d_in[10]; const float* e0_bm = (const float*)d_in[11];
    const float* e0_wc = (const float*)d_in[12]; const float* e0_bc = (const float*)d_in[13];
    const float* e1_wm = (const float*)d_in[14]; const float* e1_bm = (const float*)d_in[15];
    const float* e1_wc = (const float*)d_in[16]; const float* e1_bc = (const float*)d_in[17];
    const float* e2_wm = (const float*)d_in[18]; const float* e2_bm = (const float*)d_in[19];
    const float* e2_wc = (const float*)d_in[20]; const float* e2_bc = (const float*)d_in[21];
    const float* fce_w = (const float*)d_in[22]; const float* fce_b = (const float*)d_in[23];
    const float* fcd_w = (const float*)d_in[24]; const float* fcd_b = (const float*)d_in[25];
    const float* d0_wm = (const float*)d_in[26]; const float* d0_bm = (const float*)d_in[27];
    const float* d0_wc = (const float*)d_in[28]; const float* d0_bc = (const float*)d_in[29];
    const float* d1_wm = (const float*)d_in[30]; const float* d1_bm = (const float*)d_in[31];
    const float* d1_wc = (const float*)d_in[32]; const float* d1_bc = (const float*)d_in[33];
    const float* d2_wm = (const float*)d_in[34]; const float* d2_bm = (const float*)d_in[35];
    const float* d2_wc = (const float*)d_in[36]; const float* d2_bc = (const float*)d_in[37];

    float* ws = (float*)d_ws;
    int* idxD0 = (int*)ws;              // 1257
    int* idxD1 = idxD0 + 1257;          // 315
    int* idxD2 = idxD1 + 315;           // 80
    int* idxU0 = idxD2 + 80;            // 5024
    int* idxU1 = idxU0 + 5024;          // 1257
    int* idxU2 = idxU1 + 1257;          // 315  (ends at float-offset 8248)
    size_t off = 8256;
    float* zbuf = ws + off; off += 8192;            // [32,256]
    float* bufA = ws + off; off += 10289152;        // max [32,5024,64]
    float* bufB = ws + off; off += 2574336;         // max [32,1257,64]
    float* aggbuf = ws + off;
    size_t aggCap = (ws_size / 4 > off) ? (ws_size / 4 - off) : 0;

    // pool matrices -> gather indices
    extract_idx<<<1257, 256, 0, stream>>>(D0, 5024, idxD0);
    extract_idx<<<315,  256, 0, stream>>>(D1, 1257, idxD1);
    extract_idx<<<80,   256, 0, stream>>>(D2, 315,  idxD2);
    extract_idx<<<5024, 256, 0, stream>>>(U0, 1257, idxU0);
    extract_idx<<<1257, 256, 0, stream>>>(U1, 315,  idxU1);
    extract_idx<<<315,  256, 0, stream>>>(U2, 80,   idxU2);

    // ---- encoder (feast fused with pooling via row selection) ----
    {   // e0: [32,5024,3] -> pooled0 bufA [32,1257,64]
        int M = 32 * 1257;
        feast_fused<3, 64, 1><<<(M + 3) / 4, 256, 0, stream>>>(
            x, nbr0, idxD0, e0_wm, e0_bm, e0_wc, e0_bc, bufA, 5024, 1257, 5024, M);
    }
    // e1: pooled0 -> pooled1 bufB [32,315,128]
    run_layer<64>(bufA, nbr1, idxD1, e1_wm, e1_bm, e1_wc, e1_bc, bufB,
                  1257, 315, 1257, 128, aggbuf, aggCap, stream);
    // e2: pooled1 -> pooled2 bufA [32,80,256]
    run_layer<128>(bufB, nbr2, idxD2, e2_wm, e2_bm, e2_wc, e2_bc, bufA,
                   315, 80, 315, 256, aggbuf, aggCap, stream);

    // ---- bottleneck FCs ----
    fce_kernel<<<256, 256, 0, stream>>>(bufA, fce_w, fce_b, zbuf);
    {   // fcd: z[32,256] -> bufB [32,20480] (= [32,80,256])
        dim3 g(1, 20480 / 64);
        gemm_kernel<0, false><<<g, 256, 0, stream>>>(zbuf, fcd_w, fcd_b, bufB, nullptr,
                                                     32, 0, 256, 20480, 1, 1);
    }

    // ---- decoder ----
    {   // up-pool U2: bufB [32,80,256] -> bufA [32,315,256]
        int total = 32 * 315 * (256 / 4);
        gather_rows<<<(total + 255) / 256, 256, 0, stream>>>(bufB, idxU2, bufA, 80, 315, 256 / 4, total);
    }
    // d0: -> bufB [32,315,128]
    run_layer<256>(bufA, nbr2, nullptr, d0_wm, d0_bm, d0_wc, d0_bc, bufB,
                   315, 315, 315, 128, aggbuf, aggCap, stream);
    {   // up-pool U1: bufB -> bufA [32,1257,128]
        int total = 32 * 1257 * (128 / 4);
        gather_rows<<<(total + 255) / 256, 256, 0, stream>>>(bufB, idxU1, bufA, 315, 1257, 128 / 4, total);
    }
    // d1: -> bufB [32,1257,64]
    run_layer<128>(bufA, nbr1, nullptr, d1_wm, d1_bm, d1_wc, d1_bc, bufB,
                   1257, 1257, 1257, 64, aggbuf, aggCap, stream);
    {   // up-pool U0: bufB -> bufA [32,5024,64]
        int total = 32 * 5024 * (64 / 4);
        gather_rows<<<(total + 255) / 256, 256, 0, stream>>>(bufB, idxU0, bufA, 1257, 5024, 64 / 4, total);
    }
    {   // d2 (identity act, C=3): bufA -> d_out [32,5024,3]
        int M = 32 * 5024;
        feast_fused<64, 3, 0><<<(M + 3) / 4, 256, 0, stream>>>(
            bufA, nbr0, nullptr, d2_wm, d2_bm, d2_wc, d2_bc, (float*)d_out,
            5024, 5024, 5024, M);
    }
}

// Round 2
// 694.890 us; speedup vs baseline: 2.1636x; 2.1636x over previous
//
#include <hip/hip_runtime.h>
#include <cstddef>
#include <algorithm>

#define KN 9
typedef unsigned short u16;
typedef unsigned int u32;
typedef __attribute__((ext_vector_type(8))) short short8;
typedef __attribute__((ext_vector_type(4))) float f32x4;

__device__ inline u16 f2b(float f) {
    union { float f; u32 u; } v; v.f = f;
    u32 r = v.u + 0x7FFFu + ((v.u >> 16) & 1u);
    return (u16)(r >> 16);
}
__device__ inline float b2f(u16 h) {
    union { u32 u; float f; } v; v.u = ((u32)h) << 16; return v.f;
}

// ---------------------------------------------------------------------------
// one-hot row -> column index
// ---------------------------------------------------------------------------
__global__ void extract_idx(const float* __restrict__ L, int M, int* __restrict__ out)
{
    int p = blockIdx.x;
    const float* row = L + (size_t)p * M;
    for (int m = threadIdx.x; m < M; m += 256)
        if (row[m] > 0.5f) out[p] = m;
}

// ---------------------------------------------------------------------------
// weight prep
// ---------------------------------------------------------------------------
// wcr[c][j*F+f] = wc[c][f*9+j], bf16
__global__ void cvt_wcr(const float* __restrict__ wc, u16* __restrict__ out, int C, int F)
{
    int t = blockIdx.x * 256 + threadIdx.x;
    int tot = C * F * KN;
    if (t >= tot) return;
    int c = t / (F * KN), rem = t - c * F * KN, j = rem / F, f = rem - j * F;
    out[t] = f2b(wc[(size_t)c * F * KN + f * KN + j]);
}
// ccW[n][f] = (n<9) ? wm[n][f] : 0, bf16  ([64][F])
__global__ void cvt_ccw(const float* __restrict__ wm, u16* __restrict__ out, int F)
{
    int t = blockIdx.x * 256 + threadIdx.x;
    int tot = 64 * F;
    if (t >= tot) return;
    int n = t / F, f = t - n * F;
    out[t] = (n < KN) ? f2b(wm[n * F + f]) : (u16)0;
}
// W3 [64 n][64 k=f]: n<9 -> wm_d2[n][f]; n in [12,39) -> wc_d2[c][f*9+j] (c=(n-12)/9, j=(n-12)%9)
__global__ void build_w3(const float* __restrict__ wm, const float* __restrict__ wc, u16* __restrict__ out)
{
    int t = blockIdx.x * 256 + threadIdx.x;
    if (t >= 4096) return;
    int n = t >> 6, k = t & 63;
    float v = 0.f;
    if (n < KN) v = wm[n * 64 + k];
    else if (n >= 12 && n < 39) {
        int cj = n - 12, c = cj / KN, j = cj - c * KN;
        v = wc[(size_t)c * 576 + k * KN + j];
    }
    out[t] = f2b(v);
}

// ---------------------------------------------------------------------------
// gathers (one-hot pooling)
// ---------------------------------------------------------------------------
__global__ void gather_b2b(const u16* __restrict__ in, const int* __restrict__ idx,
                           u16* __restrict__ out, int Nin, int Pp, int F8, int total)
{
    int t = blockIdx.x * 256 + threadIdx.x;
    if (t >= total) return;
    int f = t % F8, bp = t / F8, p = bp % Pp, b = bp / Pp;
    ((uint4*)out)[t] = ((const uint4*)in)[((size_t)b * Nin + idx[p]) * F8 + f];
}
__global__ void gather_f2b(const float* __restrict__ in, const int* __restrict__ idx,
                           u16* __restrict__ out, int Nin, int Pp, int F4, int total)
{
    int t = blockIdx.x * 256 + threadIdx.x;
    if (t >= total) return;
    int f = t % F4, bp = t / F4, p = bp % Pp, b = bp / Pp;
    float4 v = ((const float4*)in)[((size_t)b * Nin + idx[p]) * F4 + f];
    uint2 o;
    o.x = (u32)f2b(v.x) | ((u32)f2b(v.y) << 16);
    o.y = (u32)f2b(v.z) | ((u32)f2b(v.w) << 16);
    ((uint2*)out)[t] = o;
}

// ---------------------------------------------------------------------------
// bf16 MFMA GEMM: Y[m0+m][n] = act(sum_k A[m][k]*W[n][k] + bias[n]) (+pad mask)
// BM=BN=BK=64, 4 waves of 32x32, 16x16x32 bf16 MFMA. K,N multiples of 64.
// ---------------------------------------------------------------------------
template<int ACT, int MASK, int OUTBF>
__global__ __launch_bounds__(256) void mfma_gemm(
    const u16* __restrict__ A, const u16* __restrict__ W,
    const float* __restrict__ bias, void* __restrict__ Yv,
    const int* __restrict__ sel,
    int Mc, int m0, int K, int N, int P, int Nlevel)
{
    __shared__ u16 As[64 * 72];
    __shared__ u16 Ws[64 * 72];
    int tid = threadIdx.x;
    int mT = blockIdx.x * 64, nT = blockIdx.y * 64;
    int wid = tid >> 6, lane = tid & 63;
    int wr = wid >> 1, wc = wid & 1;
    int r = lane & 15, g = lane >> 4;
    f32x4 acc[2][2];
    #pragma unroll
    for (int i = 0; i < 2; ++i)
        #pragma unroll
        for (int j = 0; j < 2; ++j)
            acc[i][j] = (f32x4){0.f, 0.f, 0.f, 0.f};

    for (int k0 = 0; k0 < K; k0 += 64) {
        #pragma unroll
        for (int h = 0; h < 2; ++h) {
            int gi = tid + h * 256;
            int m = gi >> 3, kg = gi & 7;
            uint4 va = {0u, 0u, 0u, 0u};
            int row = mT + m;
            if (row < Mc) va = *(const uint4*)(A + (size_t)row * K + k0 + kg * 8);
            *(uint4*)&As[m * 72 + kg * 8] = va;
            uint4 vw = *(const uint4*)(W + (size_t)(nT + m) * K + k0 + kg * 8);
            *(uint4*)&Ws[m * 72 + kg * 8] = vw;
        }
        __syncthreads();
        #pragma unroll
        for (int S = 0; S < 2; ++S) {
            short8 af[2], bf[2];
            #pragma unroll
            for (int R = 0; R < 2; ++R)
                af[R] = *(const short8*)&As[(wr * 32 + R * 16 + r) * 72 + S * 32 + g * 8];
            #pragma unroll
            for (int C2 = 0; C2 < 2; ++C2)
                bf[C2] = *(const short8*)&Ws[(wc * 32 + C2 * 16 + r) * 72 + S * 32 + g * 8];
            #pragma unroll
            for (int R = 0; R < 2; ++R)
                #pragma unroll
                for (int C2 = 0; C2 < 2; ++C2)
                    acc[R][C2] = __builtin_amdgcn_mfma_f32_16x16x32_bf16(af[R], bf[C2], acc[R][C2], 0, 0, 0);
        }
        __syncthreads();
    }

    #pragma unroll
    for (int R = 0; R < 2; ++R)
        #pragma unroll
        for (int C2 = 0; C2 < 2; ++C2)
            #pragma unroll
            for (int q = 0; q < 4; ++q) {
                int mm = mT + wr * 32 + R * 16 + g * 4 + q;
                if (mm >= Mc) continue;
                int nn = nT + wc * 32 + C2 * 16 + r;
                float v = acc[R][C2][q];
                if (bias) v += bias[nn];
                if (ACT == 1) v = v > 0.f ? v : expm1f(v);
                int gm = m0 + mm;
                if (MASK) {
                    int p = gm % P;
                    int vtx = sel ? sel[p] : p;
                    if (vtx == Nlevel - 1) v = 0.f;
                }
                if (OUTBF) ((u16*)Yv)[(size_t)gm * N + nn] = f2b(v);
                else       ((float*)Yv)[(size_t)gm * N + nn] = v;
            }
}

// ---------------------------------------------------------------------------
// feast agg (cc-gather logits + register agg):
//   L[i][j] = bm[i] + cc[nbr_j][i] - cc[nbr_0][i];  P = softmax_i
//   agg[row][j*F+f] = sum_i P[i][j] * x[nbr_i][f]   (bf16 out, [j][f] layout)
// one wave per row; F in {64,128,256}
// ---------------------------------------------------------------------------
template<int F>
__global__ __launch_bounds__(256) void feast_agg2(
    const u16* __restrict__ x, const float* __restrict__ cc,
    const int* __restrict__ nbr, const int* __restrict__ sel,
    const float* __restrict__ bm,
    u16* __restrict__ agg,
    int Nin, int P, int m0, int Mc)
{
    constexpr int FC = F / 64;
    __shared__ float s_p[4][81];
    __shared__ int s_nb[4][KN];
    int tid = threadIdx.x, wid = tid >> 6, lane = tid & 63;
    int wg = blockIdx.x * 4 + wid;
    bool aw = wg < Mc;
    int b = 0, p = 0, n = 0;
    if (aw) {
        int row = m0 + wg;
        b = row / P; p = row - b * P;
        n = sel ? sel[p] : p;
    }
    if (aw && lane < KN) s_nb[wid][lane] = nbr[n * KN + lane];
    __syncthreads();

    if (aw && lane < KN) {
        int j = lane;
        const float* c0 = cc + ((size_t)b * Nin + s_nb[wid][0]) * 64;
        const float* cj = cc + ((size_t)b * Nin + s_nb[wid][j]) * 64;
        float L[KN];
        #pragma unroll
        for (int i = 0; i < KN; ++i) L[i] = bm[i] + cj[i] - c0[i];
        float mx = L[0];
        #pragma unroll
        for (int i = 1; i < KN; ++i) mx = fmaxf(mx, L[i]);
        float s = 0.f;
        #pragma unroll
        for (int i = 0; i < KN; ++i) { L[i] = __expf(L[i] - mx); s += L[i]; }
        float inv = 1.f / s;
        #pragma unroll
        for (int i = 0; i < KN; ++i) s_p[wid][i * KN + j] = L[i] * inv;
    }
    __syncthreads();

    if (aw) {
        const u16* xb = x + (size_t)b * Nin * F;
        float xn[KN][FC];
        #pragma unroll
        for (int i = 0; i < KN; ++i) {
            const u16* xr = xb + (size_t)s_nb[wid][i] * F;
            #pragma unroll
            for (int c = 0; c < FC; ++c) xn[i][c] = b2f(xr[lane + c * 64]);
        }
        #pragma unroll
        for (int j = 0; j < KN; ++j) {
            float a[FC];
            #pragma unroll
            for (int c = 0; c < FC; ++c) a[c] = 0.f;
            #pragma unroll
            for (int i = 0; i < KN; ++i) {
                float pv = s_p[wid][i * KN + j];
                #pragma unroll
                for (int c = 0; c < FC; ++c) a[c] += xn[i][c] * pv;
            }
            u16* orow = agg + (size_t)wg * (KN * F) + j * F;
            #pragma unroll
            for (int c = 0; c < FC; ++c) orow[lane + c * 64] = f2b(a[c]);
        }
    }
}

// ---------------------------------------------------------------------------
// d2 mix: y[c] = bc[c] + sum_{i,j} P[i][j] * gw[nbr_i][c][j]
// ccgw row layout: [0..8]=cc, [12+c*9+j]=gw.  one thread per row.
// ---------------------------------------------------------------------------
__global__ __launch_bounds__(256) void mix_d2(
    const float* __restrict__ ccgw, const int* __restrict__ nbr,
    const float* __restrict__ bm9, const float* __restrict__ bc3,
    float* __restrict__ out, int b0, int nb)
{
    int t = blockIdx.x * 256 + threadIdx.x;
    int Mloc = nb * 5024;
    if (t >= Mloc) return;
    int bl = t / 5024, v = t - bl * 5024;
    int nbi[KN];
    #pragma unroll
    for (int i = 0; i < KN; ++i) nbi[i] = nbr[v * KN + i];
    const float* base = ccgw + (size_t)bl * 5024 * 64;
    float cc0[12];
    {
        const float* r0 = base + (size_t)nbi[0] * 64;
        *(float4*)&cc0[0] = *(const float4*)(r0);
        *(float4*)&cc0[4] = *(const float4*)(r0 + 4);
        *(float4*)&cc0[8] = *(const float4*)(r0 + 8);
    }
    float Pm[81];
    #pragma unroll
    for (int j = 0; j < KN; ++j) {
        float cj[12];
        const float* rj = base + (size_t)nbi[j] * 64;
        *(float4*)&cj[0] = *(const float4*)(rj);
        *(float4*)&cj[4] = *(const float4*)(rj + 4);
        *(float4*)&cj[8] = *(const float4*)(rj + 8);
        #pragma unroll
        for (int i = 0; i < KN; ++i) Pm[i * KN + j] = bm9[i] + cj[i] - cc0[i];
    }
    #pragma unroll
    for (int j = 0; j < KN; ++j) {
        float mx = Pm[j];
        #pragma unroll
        for (int i = 1; i < KN; ++i) mx = fmaxf(mx, Pm[i * KN + j]);
        float s = 0.f;
        #pragma unroll
        for (int i = 0; i < KN; ++i) { float e = __expf(Pm[i * KN + j] - mx); Pm[i * KN + j] = e; s += e; }
        float inv = 1.f / s;
        #pragma unroll
        for (int i = 0; i < KN; ++i) Pm[i * KN + j] *= inv;
    }
    float a0 = bc3[0], a1 = bc3[1], a2 = bc3[2];
    #pragma unroll
    for (int i = 0; i < KN; ++i) {
        float gv[28];
        const float* gr = base + (size_t)nbi[i] * 64 + 12;
        *(float4*)&gv[0]  = *(const float4*)(gr);
        *(float4*)&gv[4]  = *(const float4*)(gr + 4);
        *(float4*)&gv[8]  = *(const float4*)(gr + 8);
        *(float4*)&gv[12] = *(const float4*)(gr + 12);
        *(float4*)&gv[16] = *(const float4*)(gr + 16);
        *(float4*)&gv[20] = *(const float4*)(gr + 20);
        *(float4*)&gv[24] = *(const float4*)(gr + 24);
        #pragma unroll
        for (int j = 0; j < KN; ++j) {
            float pv = Pm[i * KN + j];
            a0 += pv * gv[0 * KN + j];
            a1 += pv * gv[1 * KN + j];
            a2 += pv * gv[2 * KN + j];
        }
    }
    if (v == 5023) { a0 = 0.f; a1 = 0.f; a2 = 0.f; }
    size_t row = (size_t)(b0 + bl) * 5024 + v;
    out[row * 3 + 0] = a0;
    out[row * 3 + 1] = a1;
    out[row * 3 + 2] = a2;
}

// ---------------------------------------------------------------------------
// e0 fused feast (F=3 -> C=64), bf16 output, fused D0 pooling via sel
// ---------------------------------------------------------------------------
__global__ __launch_bounds__(256) void feast_e0(
    const float* __restrict__ x, const int* __restrict__ nbr,
    const int* __restrict__ sel,
    const float* __restrict__ wm, const float* __restrict__ bm,
    const float* __restrict__ wcw, const float* __restrict__ bc,
    u16* __restrict__ y,
    int Nin, int P, int Nlevel, int Mtot)
{
    constexpr int F = 3, C = 64, FS = 4, Q = 27;
    __shared__ float s_wm[KN * FS];
    __shared__ float s_wc[C * Q];
    __shared__ float s_bm[KN];
    __shared__ float s_xn[4][KN * FS];
    __shared__ float s_lg[4][81];
    __shared__ float s_pm[4][81];
    __shared__ float s_ag[4][Q];
    __shared__ int   s_idx[4][KN];

    int tid = threadIdx.x, wid = tid >> 6, lane = tid & 63;
    for (int t = tid; t < KN * F; t += 256) { int i = t / F, f = t - i * F; s_wm[i * FS + f] = wm[t]; }
    for (int t = tid; t < C * Q; t += 256) s_wc[t] = wcw[t];
    if (tid < KN) s_bm[tid] = bm[tid];

    int wg = blockIdx.x * 4 + wid;
    bool aw = wg < Mtot;
    int b = 0, p = 0, n = 0;
    if (aw) {
        b = wg / P; p = wg - b * P;
        n = sel ? sel[p] : p;
    }
    if (aw && lane < KN) s_idx[wid][lane] = nbr[n * KN + lane];
    __syncthreads();

    if (aw) {
        const float* xb = x + (size_t)b * Nin * F;
        for (int t = lane; t < KN * F; t += 64) {
            int i = t / F, f = t - i * F;
            s_xn[wid][i * FS + f] = xb[(size_t)s_idx[wid][i] * F + f];
        }
    }
    __syncthreads();

    if (aw) {
        for (int pr = lane; pr < 81; pr += 64) {
            int i = pr / KN, j = pr - i * KN;
            float acc = s_bm[i];
            for (int f = 0; f < F; ++f)
                acc += (s_xn[wid][j * FS + f] - s_xn[wid][f]) * s_wm[i * FS + f];
            s_lg[wid][pr] = acc;
        }
    }
    __syncthreads();

    if (aw && lane < KN) {
        int j = lane;
        float mx = -1e30f;
        #pragma unroll
        for (int i = 0; i < KN; ++i) mx = fmaxf(mx, s_lg[wid][i * KN + j]);
        float sm = 0.f, ev[KN];
        #pragma unroll
        for (int i = 0; i < KN; ++i) { ev[i] = __expf(s_lg[wid][i * KN + j] - mx); sm += ev[i]; }
        float inv = 1.f / sm;
        #pragma unroll
        for (int i = 0; i < KN; ++i) s_pm[wid][i * KN + j] = ev[i] * inv;
    }
    __syncthreads();

    if (aw) {
        for (int t = lane; t < Q; t += 64) {
            int f = t / KN, j = t - f * KN;
            float acc = 0.f;
            #pragma unroll
            for (int i = 0; i < KN; ++i) acc += s_xn[wid][i * FS + f] * s_pm[wid][i * KN + j];
            s_ag[wid][t] = acc;
        }
    }
    __syncthreads();

    if (aw) {
        int c = lane;
        float acc = 0.f;
        #pragma unroll
        for (int q = 0; q < Q; ++q)
            acc += s_wc[c * Q + q] * s_ag[wid][q];
        float val = acc + bc[c];
        val = val > 0.f ? val : expm1f(val);
        if (n == Nlevel - 1) val = 0.f;
        y[(size_t)wg * C + c] = f2b(val);
    }
}

// ---------------------------------------------------------------------------
// fce: z[b][l] = sum_j x_bf16[b][j] * w[l][j] + bias[l]   (K=20480)
// ---------------------------------------------------------------------------
__global__ __launch_bounds__(256) void fce_kernel(
    const u16* __restrict__ x, const float* __restrict__ w,
    const float* __restrict__ bias, float* __restrict__ z)
{
    int l = blockIdx.x;
    const float* wr = w + (size_t)l * 20480;
    float acc[32];
    #pragma unroll
    for (int b = 0; b < 32; ++b) acc[b] = 0.f;
    for (int j0 = threadIdx.x * 8; j0 < 20480; j0 += 2048) {
        float wv[8];
        *(float4*)&wv[0] = *(const float4*)(wr + j0);
        *(float4*)&wv[4] = *(const float4*)(wr + j0 + 4);
        #pragma unroll
        for (int b = 0; b < 32; ++b) {
            uint4 xv = *(const uint4*)(x + (size_t)b * 20480 + j0);
            const u16* xs = (const u16*)&xv;
            #pragma unroll
            for (int e = 0; e < 8; ++e) acc[b] += b2f(xs[e]) * wv[e];
        }
    }
    __shared__ float s_part[4][32];
    int wid = threadIdx.x >> 6, lane = threadIdx.x & 63;
    #pragma unroll
    for (int b = 0; b < 32; ++b) {
        float v = acc[b];
        for (int off = 32; off > 0; off >>= 1) v += __shfl_down(v, off, 64);
        if (lane == 0) s_part[wid][b] = v;
    }
    __syncthreads();
    if (threadIdx.x < 32) {
        float s = s_part[0][threadIdx.x] + s_part[1][threadIdx.x]
                + s_part[2][threadIdx.x] + s_part[3][threadIdx.x];
        z[threadIdx.x * 256 + l] = s + bias[l];
    }
}

// ---------------------------------------------------------------------------
// fp32 tiled GEMM (kept for fcd: z[32x256] @ fcd_w^T -> [32x20480])
// ---------------------------------------------------------------------------
template<int ACT>
__global__ __launch_bounds__(256) void gemm_f32(
    const float* __restrict__ A, const float* __restrict__ W,
    const float* __restrict__ bias, float* __restrict__ Y,
    int Mc, int Kd, int C)
{
    __shared__ float As[32][68];
    __shared__ float Ws[32][68];
    int tid = threadIdx.x;
    int mBase = blockIdx.x * 64, cBase = blockIdx.y * 64;
    int tx = tid & 15, ty = tid >> 4;
    float acc[4][4] = {};

    for (int k0 = 0; k0 < Kd; k0 += 32) {
        #pragma unroll
        for (int rr = 0; rr < 8; ++rr) {
            int t = tid + rr * 256;
            int kk = t & 31, i = t >> 5;
            int m = mBase + i;
            As[kk][i] = (m < Mc) ? A[(size_t)m * Kd + k0 + kk] : 0.f;
        }
        #pragma unroll
        for (int rr = 0; rr < 8; ++rr) {
            int t = tid + rr * 256;
            int kk = t & 31, i = t >> 5;
            Ws[kk][i] = W[(size_t)(cBase + i) * Kd + k0 + kk];
        }
        __syncthreads();
        #pragma unroll
        for (int kk = 0; kk < 32; ++kk) {
            float4 av = *(const float4*)&As[kk][ty * 4];
            float4 wv = *(const float4*)&Ws[kk][tx * 4];
            float a[4] = {av.x, av.y, av.z, av.w};
            float wv2[4] = {wv.x, wv.y, wv.z, wv.w};
            #pragma unroll
            for (int u = 0; u < 4; ++u)
                #pragma unroll
                for (int v = 0; v < 4; ++v)
                    acc[u][v] += a[u] * wv2[v];
        }
        __syncthreads();
    }

    #pragma unroll
    for (int u = 0; u < 4; ++u) {
        int m = mBase + ty * 4 + u;
        if (m >= Mc) continue;
        float* yr = Y + (size_t)m * C + cBase + tx * 4;
        #pragma unroll
        for (int v = 0; v < 4; ++v) {
            float val = acc[u][v] + bias[cBase + tx * 4 + v];
            if (ACT == 1) val = val > 0.f ? val : expm1f(val);
            yr[v] = val;
        }
    }
}

// ---------------------------------------------------------------------------
extern "C" void kernel_launch(void* const* d_in, const int* in_sizes, int n_in,
                              void* d_out, int out_size, void* d_ws, size_t ws_size,
                              hipStream_t stream)
{
    const float* x     = (const float*)d_in[0];
    const int*   nbr0  = (const int*)d_in[1];
    const int*   nbr1  = (const int*)d_in[2];
    const int*   nbr2  = (const int*)d_in[3];
    const float* D0    = (const float*)d_in[4];
    const float* U0    = (const float*)d_in[5];
    const float* D1    = (const float*)d_in[6];
    const float* U1    = (const float*)d_in[7];
    const float* D2    = (const float*)d_in[8];
    const float* U2    = (const float*)d_in[9];
    const float* e0_wm = (const float*)d_in[10]; const float* e0_bm = (const float*)d_in[11];
    const float* e0_wc = (const float*)d_in[12]; const float* e0_bc = (const float*)d_in[13];
    const float* e1_wm = (const float*)d_in[14]; const float* e1_bm = (const float*)d_in[15];
    const float* e1_wc = (const float*)d_in[16]; const float* e1_bc = (const float*)d_in[17];
    const float* e2_wm = (const float*)d_in[18]; const float* e2_bm = (const float*)d_in[19];
    const float* e2_wc = (const float*)d_in[20]; const float* e2_bc = (const float*)d_in[21];
    const float* fce_w = (const float*)d_in[22]; const float* fce_b = (const float*)d_in[23];
    const float* fcd_w = (const float*)d_in[24]; const float* fcd_b = (const float*)d_in[25];
    const float* d0_wm = (const float*)d_in[26]; const float* d0_bm = (const float*)d_in[27];
    const float* d0_wc = (const float*)d_in[28]; const float* d0_bc = (const float*)d_in[29];
    const float* d1_wm = (const float*)d_in[30]; const float* d1_bm = (const float*)d_in[31];
    const float* d1_wc = (const float*)d_in[32]; const float* d1_bc = (const float*)d_in[33];
    const float* d2_wm = (const float*)d_in[34]; const float* d2_bm = (const float*)d_in[35];
    const float* d2_wc = (const float*)d_in[36]; const float* d2_bc = (const float*)d_in[37];

    char* w = (char*)d_ws;
    const size_t MBc = 1024 * 1024;
    int* idxD0 = (int*)(w);
    int* idxD1 = idxD0 + 1257;
    int* idxD2 = idxD1 + 315;
    int* idxU0 = idxD2 + 80;
    int* idxU1 = idxU0 + 5024;
    int* idxU2 = idxU1 + 1257;           // ends at 8248*4 = 32992
    float* zbuf  = (float*)(w + 33024);  // 32x256 f32
    u16* wcrE1 = (u16*)(w + 66048);      // 128*576
    u16* wcrE2 = (u16*)(w + 213504);     // 256*1152
    u16* wcrD0 = (u16*)(w + 803328);     // 128*2304
    u16* wcrD1 = (u16*)(w + 1393152);    // 64*1152
    u16* ccwE1 = (u16*)(w + 1540608);    // 64*64
    u16* ccwE2 = (u16*)(w + 1548800);    // 64*128
    u16* ccwD0 = (u16*)(w + 1565184);    // 64*256
    u16* ccwD1 = (u16*)(w + 1597952);    // 64*128
    u16* w3    = (u16*)(w + 1614336);    // 64*64 -> ends 1622528

    u16*   X1   = (u16*)  (w + 2 * MBc);        // [40224][64] bf16
    float* CC1  = (float*)(w + 7602176);        // [40224][64] f32
    u16*   AGG1 = (u16*)  (w + 18087936);       // [10080][576] bf16
    u16*   X2   = (u16*)  (w + 2 * MBc);        // [10080][128]
    float* CC2  = (float*)(w + 4849664);        // [10080][64]
    u16*   AGG2 = (u16*)  (w + 7602176);        // [2560][1152]
    u16*   X3   = (u16*)  (w + 13893632);       // [2560][256]
    float* X3D  = (float*)(w + 15335424);       // [32][20480] f32
    u16*   XD0  = (u16*)  (w + 18087936);       // [10080][256]
    float* CCD0 = (float*)(w + 23592960);       // [10080][64]
    u16*   XD1P = (u16*)  (w + 26345472);       // [10080][128]
    u16*   XD1  = (u16*)  (w + 7602176);        // [40224][128]
    float* CCD1 = (float*)(w + 18481152);       // [40224][64]
    u16*   AGGR = (u16*)  (w + 30408704);       // 18MB chunk region
    u16*   XD2P = (u16*)  (w + 2 * MBc);        // [40224][64]
    u16*   XD2  = (u16*)  (w + 29360128);       // [160768][64]
    float* CCGW = (float*)(w + 7602176);        // [40192][64] f32 (8-batch chunk)

    // pool matrices -> gather indices
    extract_idx<<<1257, 256, 0, stream>>>(D0, 5024, idxD0);
    extract_idx<<<315,  256, 0, stream>>>(D1, 1257, idxD1);
    extract_idx<<<80,   256, 0, stream>>>(D2, 315,  idxD2);
    extract_idx<<<5024, 256, 0, stream>>>(U0, 1257, idxU0);
    extract_idx<<<1257, 256, 0, stream>>>(U1, 315,  idxU1);
    extract_idx<<<315,  256, 0, stream>>>(U2, 80,   idxU2);

    // weight prep
    cvt_wcr<<<(73728 + 255) / 256, 256, 0, stream>>>(e1_wc, wcrE1, 128, 64);
    cvt_wcr<<<(294912 + 255) / 256, 256, 0, stream>>>(e2_wc, wcrE2, 256, 128);
    cvt_wcr<<<(294912 + 255) / 256, 256, 0, stream>>>(d0_wc, wcrD0, 128, 256);
    cvt_wcr<<<(73728 + 255) / 256, 256, 0, stream>>>(d1_wc, wcrD1, 64, 128);
    cvt_ccw<<<16, 256, 0, stream>>>(e1_wm, ccwE1, 64);
    cvt_ccw<<<32, 256, 0, stream>>>(e2_wm, ccwE2, 128);
    cvt_ccw<<<64, 256, 0, stream>>>(d0_wm, ccwD0, 256);
    cvt_ccw<<<32, 256, 0, stream>>>(d1_wm, ccwD1, 128);
    build_w3<<<16, 256, 0, stream>>>(d2_wm, d2_wc, w3);

    // ---- e0 (fused, with D0 pooling) -> X1 [32,1257,64] bf16 ----
    feast_e0<<<(40224 + 3) / 4, 256, 0, stream>>>(
        x, nbr0, idxD0, e0_wm, e0_bm, e0_wc, e0_bc, X1, 5024, 1257, 5024, 40224);

    // ---- e1 ----
    mfma_gemm<0, 0, 0><<<dim3(629, 1), 256, 0, stream>>>(
        X1, ccwE1, nullptr, CC1, nullptr, 40224, 0, 64, 64, 1, 1);
    feast_agg2<64><<<(10080 + 3) / 4, 256, 0, stream>>>(
        X1, CC1, nbr1, idxD1, e1_bm, AGG1, 1257, 315, 0, 10080);
    mfma_gemm<1, 1, 1><<<dim3(158, 2), 256, 0, stream>>>(
        AGG1, wcrE1, e1_bc, X2, idxD1, 10080, 0, 576, 128, 315, 1257);

    // ---- e2 ----
    mfma_gemm<0, 0, 0><<<dim3(158, 1), 256, 0, stream>>>(
        X2, ccwE2, nullptr, CC2, nullptr, 10080, 0, 128, 64, 1, 1);
    feast_agg2<128><<<(2560 + 3) / 4, 256, 0, stream>>>(
        X2, CC2, nbr2, idxD2, e2_bm, AGG2, 315, 80, 0, 2560);
    mfma_gemm<1, 1, 1><<<dim3(40, 4), 256, 0, stream>>>(
        AGG2, wcrE2, e2_bc, X3, idxD2, 2560, 0, 1152, 256, 80, 315);

    // ---- bottleneck ----
    fce_kernel<<<256, 256, 0, stream>>>(X3, fce_w, fce_b, zbuf);
    gemm_f32<0><<<dim3(1, 320), 256, 0, stream>>>(zbuf, fcd_w, fcd_b, X3D, 32, 256, 20480);

    // ---- decoder ----
    {   // U2 up-pool: X3D f32 [32,80,256] -> XD0 bf16 [32,315,256]
        int total = 32 * 315 * 64;
        gather_f2b<<<(total + 255) / 256, 256, 0, stream>>>(X3D, idxU2, XD0, 80, 315, 64, total);
    }
    // d0
    mfma_gemm<0, 0, 0><<<dim3(158, 1), 256, 0, stream>>>(
        XD0, ccwD0, nullptr, CCD0, nullptr, 10080, 0, 256, 64, 1, 1);
    for (int m0 = 0; m0 < 10080; m0 += 4096) {
        int ch = std::min(4096, 10080 - m0);
        feast_agg2<256><<<(ch + 3) / 4, 256, 0, stream>>>(
            XD0, CCD0, nbr2, nullptr, d0_bm, AGGR, 315, 315, m0, ch);
        mfma_gemm<1, 1, 1><<<dim3((ch + 63) / 64, 2), 256, 0, stream>>>(
            AGGR, wcrD0, d0_bc, XD1P, nullptr, ch, m0, 2304, 128, 315, 315);
    }
    {   // U1 up-pool: XD1P [32,315,128] -> XD1 [32,1257,128]
        int total = 32 * 1257 * 16;
        gather_b2b<<<(total + 255) / 256, 256, 0, stream>>>(XD1P, idxU1, XD1, 315, 1257, 16, total);
    }
    // d1
    mfma_gemm<0, 0, 0><<<dim3(629, 1), 256, 0, stream>>>(
        XD1, ccwD1, nullptr, CCD1, nullptr, 40224, 0, 128, 64, 1, 1);
    for (int m0 = 0; m0 < 40224; m0 += 8192) {
        int ch = std::min(8192, 40224 - m0);
        feast_agg2<128><<<(ch + 3) / 4, 256, 0, stream>>>(
            XD1, CCD1, nbr1, nullptr, d1_bm, AGGR, 1257, 1257, m0, ch);
        mfma_gemm<1, 1, 1><<<dim3((ch + 63) / 64, 1), 256, 0, stream>>>(
            AGGR, wcrD1, d1_bc, XD2P, nullptr, ch, m0, 1152, 64, 1257, 1257);
    }
    {   // U0 up-pool: XD2P [32,1257,64] -> XD2 [32,5024,64]
        int total = 32 * 5024 * 8;
        gather_b2b<<<(total + 255) / 256, 256, 0, stream>>>(XD2P, idxU0, XD2, 1257, 5024, 8, total);
    }
    // d2: fused cc+gw GEMM per 8 batches, then gather-mix
    for (int b0 = 0; b0 < 32; b0 += 8) {
        mfma_gemm<0, 0, 0><<<dim3(628, 1), 256, 0, stream>>>(
            XD2 + (size_t)b0 * 5024 * 64, w3, nullptr, CCGW, nullptr, 40192, 0, 64, 64, 1, 1);
        mix_d2<<<157, 256, 0, stream>>>(CCGW, nbr0, d2_bm, d2_bc, (float*)d_out, b0, 8);
    }
}

// Round 4
// 484.117 us; speedup vs baseline: 3.1056x; 1.4354x over previous
//
#include <hip/hip_runtime.h>
#include <cstddef>

#define KN 9
typedef unsigned short u16;
typedef unsigned int u32;
typedef __attribute__((ext_vector_type(8))) short short8;
typedef __attribute__((ext_vector_type(4))) float f32x4;

__device__ inline u16 f2b(float f) {
    union { float f; u32 u; } v; v.f = f;
    u32 r = v.u + 0x7FFFu + ((v.u >> 16) & 1u);
    return (u16)(r >> 16);
}
__device__ inline float b2f(u16 h) {
    union { u32 u; float f; } v; v.u = ((u32)h) << 16; return v.f;
}

// ---------------------------------------------------------------------------
// all 6 one-hot pool matrices -> gather indices, one kernel
// ---------------------------------------------------------------------------
__global__ void extract_idx_all(
    const float* __restrict__ D0, const float* __restrict__ D1, const float* __restrict__ D2,
    const float* __restrict__ U0, const float* __restrict__ U1, const float* __restrict__ U2,
    int* __restrict__ iD0, int* __restrict__ iD1, int* __restrict__ iD2,
    int* __restrict__ iU0, int* __restrict__ iU1, int* __restrict__ iU2)
{
    int blk = blockIdx.x;
    const float* L; int M; int* out; int p;
    if      (blk < 1257) { L = D0; M = 5024; out = iD0; p = blk; }
    else if (blk < 1572) { L = D1; M = 1257; out = iD1; p = blk - 1257; }
    else if (blk < 1652) { L = D2; M = 315;  out = iD2; p = blk - 1572; }
    else if (blk < 6676) { L = U0; M = 1257; out = iU0; p = blk - 1652; }
    else if (blk < 7933) { L = U1; M = 315;  out = iU1; p = blk - 6676; }
    else                 { L = U2; M = 80;   out = iU2; p = blk - 7933; }
    const float* row = L + (size_t)p * M;
    for (int m = threadIdx.x; m < M; m += 256)
        if (row[m] > 0.5f) out[p] = m;
}

// ---------------------------------------------------------------------------
// weight conversions + zbuf zeroing, one kernel
// ---------------------------------------------------------------------------
__device__ inline void wcr_one(const float* __restrict__ wc, u16* __restrict__ out, int t, int F) {
    int FK = F * KN;
    int c = t / FK, rem = t - c * FK, j = rem / F, f = rem - j * F;
    out[t] = f2b(wc[(size_t)c * FK + f * KN + j]);
}
__device__ inline void ccw_one(const float* __restrict__ wm, u16* __restrict__ out, int t, int F) {
    int n = t / F, f = t - n * F;
    out[t] = (n < KN) ? f2b(wm[n * F + f]) : (u16)0;
}
__global__ void cvt_weights(
    const float* __restrict__ e1_wc, const float* __restrict__ e2_wc,
    const float* __restrict__ d0_wc, const float* __restrict__ d1_wc,
    const float* __restrict__ e1_wm, const float* __restrict__ e2_wm,
    const float* __restrict__ d0_wm, const float* __restrict__ d1_wm,
    const float* __restrict__ d2_wm, const float* __restrict__ d2_wc,
    u16* __restrict__ wcrE1, u16* __restrict__ wcrE2,
    u16* __restrict__ wcrD0, u16* __restrict__ wcrD1,
    u16* __restrict__ ccwE1, u16* __restrict__ ccwE2,
    u16* __restrict__ ccwD0, u16* __restrict__ ccwD1,
    u16* __restrict__ w3, float* __restrict__ zbuf)
{
    int t = blockIdx.x * 256 + threadIdx.x;
    if (t < 73728)  { wcr_one(e1_wc, wcrE1, t, 64);  return; } t -= 73728;
    if (t < 294912) { wcr_one(e2_wc, wcrE2, t, 128); return; } t -= 294912;
    if (t < 294912) { wcr_one(d0_wc, wcrD0, t, 256); return; } t -= 294912;
    if (t < 73728)  { wcr_one(d1_wc, wcrD1, t, 128); return; } t -= 73728;
    if (t < 4096)   { ccw_one(e1_wm, ccwE1, t, 64);  return; } t -= 4096;
    if (t < 8192)   { ccw_one(e2_wm, ccwE2, t, 128); return; } t -= 8192;
    if (t < 16384)  { ccw_one(d0_wm, ccwD0, t, 256); return; } t -= 16384;
    if (t < 8192)   { ccw_one(d1_wm, ccwD1, t, 128); return; } t -= 8192;
    if (t < 4096) {
        int n = t >> 6, k = t & 63;
        float v = 0.f;
        if (n < KN) v = d2_wm[n * 64 + k];
        else if (n >= 12 && n < 39) {
            int cj = n - 12, c = cj / KN, j = cj - c * KN;
            v = d2_wc[(size_t)c * 576 + k * KN + j];
        }
        w3[t] = f2b(v);
        return;
    } t -= 4096;
    if (t < 8192) zbuf[t] = 0.f;
}

// ---------------------------------------------------------------------------
// composed neighbor tables (stride 12) + encoder pad masks
// ---------------------------------------------------------------------------
__global__ void compose_tables(
    const int* __restrict__ nbr0, const int* __restrict__ nbr1, const int* __restrict__ nbr2,
    const int* __restrict__ idxD1, const int* __restrict__ idxD2,
    const int* __restrict__ idxU0, const int* __restrict__ idxU1, const int* __restrict__ idxU2,
    int* __restrict__ nbrD1, int* __restrict__ nbrD2,
    int* __restrict__ nbrU2, int* __restrict__ nbrU1, int* __restrict__ nbrU0,
    int* __restrict__ maskE1, int* __restrict__ maskE2)
{
    int t = blockIdx.x * 256 + threadIdx.x;
    if (t < 2835)  { int p = t / 9, j = t - p * 9; nbrD1[p * 12 + j] = nbr1[idxD1[p] * 9 + j]; return; } t -= 2835;
    if (t < 720)   { int p = t / 9, j = t - p * 9; nbrD2[p * 12 + j] = nbr2[idxD2[p] * 9 + j]; return; } t -= 720;
    if (t < 2835)  { int p = t / 9, j = t - p * 9; nbrU2[p * 12 + j] = idxU2[nbr2[p * 9 + j]]; return; } t -= 2835;
    if (t < 11313) { int p = t / 9, j = t - p * 9; nbrU1[p * 12 + j] = idxU1[nbr1[p * 9 + j]]; return; } t -= 11313;
    if (t < 45216) { int p = t / 9, j = t - p * 9; nbrU0[p * 12 + j] = idxU0[nbr0[p * 9 + j]]; return; } t -= 45216;
    if (t < 315)   { maskE1[t] = (idxD1[t] == 1256) ? 1 : 0; return; } t -= 315;
    if (t < 80)    { maskE2[t] = (idxD2[t] == 314) ? 1 : 0; }
}

// ---------------------------------------------------------------------------
// cc GEMM: out[m][nn<NW] = sum_f A[m][f]*W[nn][f]   (f32 out, row stride OS)
// A bf16 [M][F], W bf16 [64][F]. grid ceil(M/64).
// ---------------------------------------------------------------------------
template<int NW, int OS>
__global__ __launch_bounds__(256) void cc_gemm(
    const u16* __restrict__ A, const u16* __restrict__ W,
    float* __restrict__ out, int M, int F)
{
    __shared__ u16 As[64 * 72];
    __shared__ u16 Ws[64 * 72];
    int tid = threadIdx.x;
    int mT = blockIdx.x * 64;
    int wid = tid >> 6, lane = tid & 63;
    int wr = wid >> 1, wcq = wid & 1;
    int r = lane & 15, g = lane >> 4;
    f32x4 acc[2][2];
    #pragma unroll
    for (int i = 0; i < 2; ++i)
        #pragma unroll
        for (int j = 0; j < 2; ++j)
            acc[i][j] = (f32x4){0.f, 0.f, 0.f, 0.f};

    for (int k0 = 0; k0 < F; k0 += 64) {
        #pragma unroll
        for (int h = 0; h < 2; ++h) {
            int gi = tid + h * 256;
            int m = gi >> 3, kg = gi & 7;
            uint4 va = {0u, 0u, 0u, 0u};
            int row = mT + m;
            if (row < M) va = *(const uint4*)(A + (size_t)row * F + k0 + kg * 8);
            *(uint4*)&As[m * 72 + kg * 8] = va;
            *(uint4*)&Ws[m * 72 + kg * 8] = *(const uint4*)(W + (size_t)m * F + k0 + kg * 8);
        }
        __syncthreads();
        #pragma unroll
        for (int S = 0; S < 2; ++S) {
            short8 af[2], bf[2];
            #pragma unroll
            for (int R = 0; R < 2; ++R)
                af[R] = *(const short8*)&As[(wr * 32 + R * 16 + r) * 72 + S * 32 + g * 8];
            #pragma unroll
            for (int C2 = 0; C2 < 2; ++C2)
                bf[C2] = *(const short8*)&Ws[(wcq * 32 + C2 * 16 + r) * 72 + S * 32 + g * 8];
            #pragma unroll
            for (int R = 0; R < 2; ++R)
                #pragma unroll
                for (int C2 = 0; C2 < 2; ++C2)
                    acc[R][C2] = __builtin_amdgcn_mfma_f32_16x16x32_bf16(af[R], bf[C2], acc[R][C2], 0, 0, 0);
        }
        __syncthreads();
    }
    #pragma unroll
    for (int R = 0; R < 2; ++R)
        #pragma unroll
        for (int C2 = 0; C2 < 2; ++C2)
            #pragma unroll
            for (int q = 0; q < 4; ++q) {
                int mm = mT + wr * 32 + R * 16 + g * 4 + q;
                int nn = wcq * 32 + C2 * 16 + r;
                if (mm < M && nn < NW)
                    out[(size_t)mm * OS + nn] = acc[R][C2][q];
            }
}

// ---------------------------------------------------------------------------
// fused feast layer: P from gathered cc, A-tile built on the fly, MFMA linear.
//   row = b*P + p; vertex indices via composed nbrT[p][12]; x rows b*Pin + nbrT.
// MASKSEL: 1 = encoder (mask from maskT), 0 = decoder (mask p==P-1)
// ---------------------------------------------------------------------------
template<int F, int C, int MASKSEL>
__global__ __launch_bounds__(256) void feast_lin(
    const u16* __restrict__ x, const float* __restrict__ cc,
    const int* __restrict__ nbrT, const int* __restrict__ maskT,
    const float* __restrict__ bm, const u16* __restrict__ wcr,
    const float* __restrict__ bc, u16* __restrict__ y,
    int Pin, int P, int Mtot)
{
    constexpr int NT = C / 64;
    constexpr int FT = F / 64;
    constexpr int K  = KN * F;
    __shared__ float sP[64][84];
    __shared__ u16   sA[64][72];
    __shared__ u16   sW[64 * 72];     // FLAT — indexed as sW[row*72 + col]
    __shared__ int   sNB[64][12];
    __shared__ float sC0[64][12];
    __shared__ float sBM[12];

    int tid = threadIdx.x;
    int m = tid >> 2, s = tid & 3;
    int row = blockIdx.x * 64 + m;
    bool aw = row < Mtot;
    int b = 0, p = 0;
    if (aw) { b = row / P; p = row - b * P; }
    if (tid < KN) sBM[tid] = bm[tid];
    if (aw) {
        for (int j = s; j < KN; j += 4)
            sNB[m][j] = b * Pin + nbrT[p * 12 + j];
    }
    __syncthreads();
    if (aw && s == 0) {
        const float* c0 = cc + (size_t)sNB[m][0] * 16;
        #pragma unroll
        for (int i = 0; i < KN; ++i) sC0[m][i] = c0[i];
    }
    __syncthreads();
    if (aw) {
        for (int j = s; j < KN; j += 4) {
            const float* cj = cc + (size_t)sNB[m][j] * 16;
            float L[KN];
            #pragma unroll
            for (int i = 0; i < KN; ++i) L[i] = sBM[i] + cj[i] - sC0[m][i];
            float mx = L[0];
            #pragma unroll
            for (int i = 1; i < KN; ++i) mx = fmaxf(mx, L[i]);
            float sm = 0.f;
            #pragma unroll
            for (int i = 0; i < KN; ++i) { L[i] = __expf(L[i] - mx); sm += L[i]; }
            float inv = 1.f / sm;
            #pragma unroll
            for (int i = 0; i < KN; ++i) sP[m][i * KN + j] = L[i] * inv;
        }
    }
    __syncthreads();

    int wid = tid >> 6, lane = tid & 63;
    int wr = wid >> 1, wcq = wid & 1;
    int r = lane & 15, g = lane >> 4;
    f32x4 acc[NT][2][2];
    #pragma unroll
    for (int nt = 0; nt < NT; ++nt)
        #pragma unroll
        for (int i = 0; i < 2; ++i)
            #pragma unroll
            for (int j = 0; j < 2; ++j)
                acc[nt][i][j] = (f32x4){0.f, 0.f, 0.f, 0.f};

    for (int ft = 0; ft < FT; ++ft) {
        uint4 xs[KN][2];
        if (aw) {
            #pragma unroll
            for (int i = 0; i < KN; ++i) {
                const u16* xb = x + (size_t)sNB[m][i] * F + ft * 64 + s * 16;
                xs[i][0] = *(const uint4*)xb;
                xs[i][1] = *(const uint4*)(xb + 8);
            }
        }
        for (int j = 0; j < KN; ++j) {
            float pv[KN];
            #pragma unroll
            for (int i = 0; i < KN; ++i) pv[i] = sP[m][i * KN + j];
            u16 o[16];
            if (aw) {
                #pragma unroll
                for (int h = 0; h < 2; ++h)
                    #pragma unroll
                    for (int e = 0; e < 8; ++e) {
                        float a = 0.f;
                        #pragma unroll
                        for (int i = 0; i < KN; ++i) {
                            const u16* px = (const u16*)&xs[i][h];
                            a += pv[i] * b2f(px[e]);
                        }
                        o[h * 8 + e] = f2b(a);
                    }
            } else {
                #pragma unroll
                for (int e = 0; e < 16; ++e) o[e] = 0;
            }
            *(uint4*)&sA[m][s * 16]     = *(const uint4*)&o[0];
            *(uint4*)&sA[m][s * 16 + 8] = *(const uint4*)&o[8];
            for (int nt = 0; nt < NT; ++nt) {
                {
                    int rr = tid >> 2, q = tid & 3;
                    const u16* wsrc = wcr + (size_t)(nt * 64 + rr) * K + j * F + ft * 64 + q * 16;
                    *(uint4*)&sW[rr * 72 + q * 16]     = *(const uint4*)(wsrc);
                    *(uint4*)&sW[rr * 72 + q * 16 + 8] = *(const uint4*)(wsrc + 8);
                }
                __syncthreads();
                #pragma unroll
                for (int S = 0; S < 2; ++S) {
                    short8 af[2], bf[2];
                    #pragma unroll
                    for (int R = 0; R < 2; ++R)
                        af[R] = *(const short8*)&sA[wr * 32 + R * 16 + r][S * 32 + g * 8];
                    #pragma unroll
                    for (int C2 = 0; C2 < 2; ++C2)
                        bf[C2] = *(const short8*)&sW[(wcq * 32 + C2 * 16 + r) * 72 + S * 32 + g * 8];
                    #pragma unroll
                    for (int R = 0; R < 2; ++R)
                        #pragma unroll
                        for (int C2 = 0; C2 < 2; ++C2)
                            acc[nt][R][C2] = __builtin_amdgcn_mfma_f32_16x16x32_bf16(af[R], bf[C2], acc[nt][R][C2], 0, 0, 0);
                }
                __syncthreads();
            }
        }
    }

    #pragma unroll
    for (int nt = 0; nt < NT; ++nt)
        #pragma unroll
        for (int R = 0; R < 2; ++R)
            #pragma unroll
            for (int C2 = 0; C2 < 2; ++C2)
                #pragma unroll
                for (int q = 0; q < 4; ++q) {
                    int mm = wr * 32 + R * 16 + g * 4 + q;
                    int grow = blockIdx.x * 64 + mm;
                    if (grow >= Mtot) continue;
                    int bb = grow / P, pp = grow - bb * P;
                    int nn = nt * 64 + wcq * 32 + C2 * 16 + r;
                    float v = acc[nt][R][C2][q] + bc[nn];
                    v = v > 0.f ? v : expm1f(v);
                    bool z = MASKSEL ? (maskT[pp] != 0) : (pp == P - 1);
                    if (z) v = 0.f;
                    y[(size_t)grow * C + nn] = f2b(v);
                }
}

// ---------------------------------------------------------------------------
// e0 fused feast (F=3 -> C=64), bf16 output, fused D0 pooling via sel
// ---------------------------------------------------------------------------
__global__ __launch_bounds__(256) void feast_e0(
    const float* __restrict__ x, const int* __restrict__ nbr,
    const int* __restrict__ sel,
    const float* __restrict__ wm, const float* __restrict__ bm,
    const float* __restrict__ wcw, const float* __restrict__ bc,
    u16* __restrict__ y,
    int Nin, int P, int Nlevel, int Mtot)
{
    constexpr int F = 3, C = 64, FS = 4, Q = 27;
    __shared__ float s_wm[KN * FS];
    __shared__ float s_wc[C * Q];
    __shared__ float s_bm[KN];
    __shared__ float s_xn[4][KN * FS];
    __shared__ float s_lg[4][81];
    __shared__ float s_pm[4][81];
    __shared__ float s_ag[4][Q];
    __shared__ int   s_idx[4][KN];

    int tid = threadIdx.x, wid = tid >> 6, lane = tid & 63;
    for (int t = tid; t < KN * F; t += 256) { int i = t / F, f = t - i * F; s_wm[i * FS + f] = wm[t]; }
    for (int t = tid; t < C * Q; t += 256) s_wc[t] = wcw[t];
    if (tid < KN) s_bm[tid] = bm[tid];

    int wg = blockIdx.x * 4 + wid;
    bool aw = wg < Mtot;
    int b = 0, p = 0, n = 0;
    if (aw) {
        b = wg / P; p = wg - b * P;
        n = sel[p];
    }
    if (aw && lane < KN) s_idx[wid][lane] = nbr[n * KN + lane];
    __syncthreads();

    if (aw) {
        const float* xb = x + (size_t)b * Nin * F;
        for (int t = lane; t < KN * F; t += 64) {
            int i = t / F, f = t - i * F;
            s_xn[wid][i * FS + f] = xb[(size_t)s_idx[wid][i] * F + f];
        }
    }
    __syncthreads();

    if (aw) {
        for (int pr = lane; pr < 81; pr += 64) {
            int i = pr / KN, j = pr - i * KN;
            float acc = s_bm[i];
            for (int f = 0; f < F; ++f)
                acc += (s_xn[wid][j * FS + f] - s_xn[wid][f]) * s_wm[i * FS + f];
            s_lg[wid][pr] = acc;
        }
    }
    __syncthreads();

    if (aw && lane < KN) {
        int j = lane;
        float mx = -1e30f;
        #pragma unroll
        for (int i = 0; i < KN; ++i) mx = fmaxf(mx, s_lg[wid][i * KN + j]);
        float sm = 0.f, ev[KN];
        #pragma unroll
        for (int i = 0; i < KN; ++i) { ev[i] = __expf(s_lg[wid][i * KN + j] - mx); sm += ev[i]; }
        float inv = 1.f / sm;
        #pragma unroll
        for (int i = 0; i < KN; ++i) s_pm[wid][i * KN + j] = ev[i] * inv;
    }
    __syncthreads();

    if (aw) {
        for (int t = lane; t < Q; t += 64) {
            int f = t / KN, j = t - f * KN;
            float acc = 0.f;
            #pragma unroll
            for (int i = 0; i < KN; ++i) acc += s_xn[wid][i * FS + f] * s_pm[wid][i * KN + j];
            s_ag[wid][t] = acc;
        }
    }
    __syncthreads();

    if (aw) {
        int c = lane;
        float acc = 0.f;
        #pragma unroll
        for (int q = 0; q < Q; ++q)
            acc += s_wc[c * Q + q] * s_ag[wid][q];
        float val = acc + bc[c];
        val = val > 0.f ? val : expm1f(val);
        if (n == Nlevel - 1) val = 0.f;
        y[(size_t)wg * C + c] = f2b(val);
    }
}

// ---------------------------------------------------------------------------
// fce split-K: z[b][l] += sum_{k in slice} X3[b][k]*w[l][k]  (+bias at ks==0)
// grid (256, 8); z pre-zeroed.
// ---------------------------------------------------------------------------
__global__ __launch_bounds__(256) void fce2(
    const u16* __restrict__ X3, const float* __restrict__ w,
    const float* __restrict__ bias, float* __restrict__ z)
{
    int l = blockIdx.x, ks = blockIdx.y;
    int k0 = ks * 2560;
    float acc[32];
    #pragma unroll
    for (int b = 0; b < 32; ++b) acc[b] = 0.f;
    for (int it = 0; it < 10; ++it) {
        int k = k0 + it * 256 + threadIdx.x;
        float wv = w[(size_t)l * 20480 + k];
        #pragma unroll
        for (int b = 0; b < 32; ++b) acc[b] += b2f(X3[(size_t)b * 20480 + k]) * wv;
    }
    __shared__ float sp[4][32];
    int wid = threadIdx.x >> 6, lane = threadIdx.x & 63;
    #pragma unroll
    for (int b = 0; b < 32; ++b) {
        float v = acc[b];
        for (int off = 32; off > 0; off >>= 1) v += __shfl_down(v, off, 64);
        if (lane == 0) sp[wid][b] = v;
    }
    __syncthreads();
    if (threadIdx.x < 32) {
        float sv = sp[0][threadIdx.x] + sp[1][threadIdx.x]
                 + sp[2][threadIdx.x] + sp[3][threadIdx.x];
        if (ks == 0) sv += bias[l];
        atomicAdd(&z[threadIdx.x * 256 + l], sv);
    }
}

// ---------------------------------------------------------------------------
// fp32 tiled GEMM for fcd (M=32, K=256, N=20480), bf16 output
// ---------------------------------------------------------------------------
__global__ __launch_bounds__(256) void gemm_fcd(
    const float* __restrict__ A, const float* __restrict__ W,
    const float* __restrict__ bias, u16* __restrict__ Y,
    int Mc, int Kd, int C)
{
    __shared__ float As[32][68];
    __shared__ float Ws[32][68];
    int tid = threadIdx.x;
    int mBase = blockIdx.x * 64, cBase = blockIdx.y * 64;
    int tx = tid & 15, ty = tid >> 4;
    float acc[4][4] = {};

    for (int k0 = 0; k0 < Kd; k0 += 32) {
        #pragma unroll
        for (int rr = 0; rr < 8; ++rr) {
            int t = tid + rr * 256;
            int kk = t & 31, i = t >> 5;
            int mi = mBase + i;
            As[kk][i] = (mi < Mc) ? A[(size_t)mi * Kd + k0 + kk] : 0.f;
        }
        #pragma unroll
        for (int rr = 0; rr < 8; ++rr) {
            int t = tid + rr * 256;
            int kk = t & 31, i = t >> 5;
            Ws[kk][i] = W[(size_t)(cBase + i) * Kd + k0 + kk];
        }
        __syncthreads();
        #pragma unroll
        for (int kk = 0; kk < 32; ++kk) {
            float4 av = *(const float4*)&As[kk][ty * 4];
            float4 wv = *(const float4*)&Ws[kk][tx * 4];
            float a[4] = {av.x, av.y, av.z, av.w};
            float wv2[4] = {wv.x, wv.y, wv.z, wv.w};
            #pragma unroll
            for (int u = 0; u < 4; ++u)
                #pragma unroll
                for (int v = 0; v < 4; ++v)
                    acc[u][v] += a[u] * wv2[v];
        }
        __syncthreads();
    }
    #pragma unroll
    for (int u = 0; u < 4; ++u) {
        int mi = mBase + ty * 4 + u;
        if (mi >= Mc) continue;
        #pragma unroll
        for (int v = 0; v < 4; ++v) {
            float val = acc[u][v] + bias[cBase + tx * 4 + v];
            Y[(size_t)mi * C + cBase + tx * 4 + v] = f2b(val);
        }
    }
}

// ---------------------------------------------------------------------------
// d2 mix: y[c] = bc[c] + sum_{i,j} P[i][j]*gw[nbr_i][c][j], via composed nbrU0
// ccgw rows stride 40: [0..8]=cc, [12..38]=gw
// ---------------------------------------------------------------------------
__global__ __launch_bounds__(256) void mix_d2(
    const float* __restrict__ ccgw, const int* __restrict__ nbrT,
    const float* __restrict__ bm9, const float* __restrict__ bc3,
    float* __restrict__ out)
{
    int t = blockIdx.x * 256 + threadIdx.x;
    if (t >= 160768) return;
    int b = t / 5024, v = t - b * 5024;
    int nbi[KN];
    #pragma unroll
    for (int i = 0; i < KN; ++i) nbi[i] = nbrT[v * 12 + i];
    const float* base = ccgw + (size_t)b * 1257 * 40;
    float cc0[12];
    {
        const float* r0 = base + (size_t)nbi[0] * 40;
        *(float4*)&cc0[0] = *(const float4*)(r0);
        *(float4*)&cc0[4] = *(const float4*)(r0 + 4);
        *(float4*)&cc0[8] = *(const float4*)(r0 + 8);
    }
    float Pm[81];
    #pragma unroll
    for (int j = 0; j < KN; ++j) {
        float cj[12];
        const float* rj = base + (size_t)nbi[j] * 40;
        *(float4*)&cj[0] = *(const float4*)(rj);
        *(float4*)&cj[4] = *(const float4*)(rj + 4);
        *(float4*)&cj[8] = *(const float4*)(rj + 8);
        #pragma unroll
        for (int i = 0; i < KN; ++i) Pm[i * KN + j] = bm9[i] + cj[i] - cc0[i];
    }
    #pragma unroll
    for (int j = 0; j < KN; ++j) {
        float mx = Pm[j];
        #pragma unroll
        for (int i = 1; i < KN; ++i) mx = fmaxf(mx, Pm[i * KN + j]);
        float sm = 0.f;
        #pragma unroll
        for (int i = 0; i < KN; ++i) { float e = __expf(Pm[i * KN + j] - mx); Pm[i * KN + j] = e; sm += e; }
        float inv = 1.f / sm;
        #pragma unroll
        for (int i = 0; i < KN; ++i) Pm[i * KN + j] *= inv;
    }
    float a0 = bc3[0], a1 = bc3[1], a2 = bc3[2];
    #pragma unroll
    for (int i = 0; i < KN; ++i) {
        float gv[28];
        const float* gr = base + (size_t)nbi[i] * 40 + 12;
        *(float4*)&gv[0]  = *(const float4*)(gr);
        *(float4*)&gv[4]  = *(const float4*)(gr + 4);
        *(float4*)&gv[8]  = *(const float4*)(gr + 8);
        *(float4*)&gv[12] = *(const float4*)(gr + 12);
        *(float4*)&gv[16] = *(const float4*)(gr + 16);
        *(float4*)&gv[20] = *(const float4*)(gr + 20);
        *(float4*)&gv[24] = *(const float4*)(gr + 24);
        #pragma unroll
        for (int j = 0; j < KN; ++j) {
            float pv = Pm[i * KN + j];
            a0 += pv * gv[0 * KN + j];
            a1 += pv * gv[1 * KN + j];
            a2 += pv * gv[2 * KN + j];
        }
    }
    if (v == 5023) { a0 = 0.f; a1 = 0.f; a2 = 0.f; }
    out[(size_t)t * 3 + 0] = a0;
    out[(size_t)t * 3 + 1] = a1;
    out[(size_t)t * 3 + 2] = a2;
}

// ---------------------------------------------------------------------------
extern "C" void kernel_launch(void* const* d_in, const int* in_sizes, int n_in,
                              void* d_out, int out_size, void* d_ws, size_t ws_size,
                              hipStream_t stream)
{
    const float* x     = (const float*)d_in[0];
    const int*   nbr0  = (const int*)d_in[1];
    const int*   nbr1  = (const int*)d_in[2];
    const int*   nbr2  = (const int*)d_in[3];
    const float* D0    = (const float*)d_in[4];
    const float* U0    = (const float*)d_in[5];
    const float* D1    = (const float*)d_in[6];
    const float* U1    = (const float*)d_in[7];
    const float* D2    = (const float*)d_in[8];
    const float* U2    = (const float*)d_in[9];
    const float* e0_wm = (const float*)d_in[10]; const float* e0_bm = (const float*)d_in[11];
    const float* e0_wc = (const float*)d_in[12]; const float* e0_bc = (const float*)d_in[13];
    const float* e1_wm = (const float*)d_in[14]; const float* e1_bm = (const float*)d_in[15];
    const float* e1_wc = (const float*)d_in[16]; const float* e1_bc = (const float*)d_in[17];
    const float* e2_wm = (const float*)d_in[18]; const float* e2_bm = (const float*)d_in[19];
    const float* e2_wc = (const float*)d_in[20]; const float* e2_bc = (const float*)d_in[21];
    const float* fce_w = (const float*)d_in[22]; const float* fce_b = (const float*)d_in[23];
    const float* fcd_w = (const float*)d_in[24]; const float* fcd_b = (const float*)d_in[25];
    const float* d0_wm = (const float*)d_in[26]; const float* d0_bm = (const float*)d_in[27];
    const float* d0_wc = (const float*)d_in[28]; const float* d0_bc = (const float*)d_in[29];
    const float* d1_wm = (const float*)d_in[30]; const float* d1_bm = (const float*)d_in[31];
    const float* d1_wc = (const float*)d_in[32]; const float* d1_bc = (const float*)d_in[33];
    const float* d2_wm = (const float*)d_in[34]; const float* d2_bm = (const float*)d_in[35];
    const float* d2_wc = (const float*)d_in[36]; const float* d2_bc = (const float*)d_in[37];

    char* w = (char*)d_ws;
    int* idxD0 = (int*)(w);              // 1257
    int* idxD1 = idxD0 + 1257;           // 315
    int* idxD2 = idxD1 + 315;            // 80
    int* idxU0 = idxD2 + 80;             // 5024
    int* idxU1 = idxU0 + 5024;           // 1257
    int* idxU2 = idxU1 + 1257;           // 315 -> ends byte 32992
    int* nbrD1  = (int*)(w + 33024);     // 315*12  -> 48144
    int* nbrD2  = (int*)(w + 48144);     // 80*12   -> 51984
    int* nbrU2  = (int*)(w + 51984);     // 315*12  -> 67104
    int* nbrU1  = (int*)(w + 67104);     // 1257*12 -> 127440
    int* nbrU0  = (int*)(w + 127440);    // 5024*12 -> 368592
    int* maskE1 = (int*)(w + 368640);    // 315
    int* maskE2 = (int*)(w + 369920);    // 80
    u16* wcrE1 = (u16*)(w + 370432);     // 128*576
    u16* wcrE2 = (u16*)(w + 517888);     // 256*1152
    u16* wcrD0 = (u16*)(w + 1107712);    // 128*2304
    u16* wcrD1 = (u16*)(w + 1697536);    // 64*1152
    u16* ccwE1 = (u16*)(w + 1844992);    // 64*64
    u16* ccwE2 = (u16*)(w + 1853184);    // 64*128
    u16* ccwD0 = (u16*)(w + 1869568);    // 64*256
    u16* ccwD1 = (u16*)(w + 1902336);    // 64*128
    u16* w3    = (u16*)(w + 1918720);    // 64*64
    float* zbuf = (float*)(w + 1926912); // 32*256 f32 -> 1959680

    u16*   X1   = (u16*)  (w + 2097152);   // [40224][64]
    float* CC1  = (float*)(w + 7245824);   // [40224][16]
    u16*   X2   = (u16*)  (w + 9820160);   // [10080][128]
    float* CC2  = (float*)(w + 12400640);  // [10080][16]
    u16*   X3   = (u16*)  (w + 13045760);  // [2560][256]
    u16*   X3P  = (u16*)  (w + 14356480);  // [2560][256]
    float* CCD0 = (float*)(w + 15667200);  // [2560][16]
    u16*   XD1P = (u16*)  (w + 15831040);  // [10080][128]
    float* CCD1 = (float*)(w + 18411520);  // [10080][16]
    u16*   XD2P = (u16*)  (w + 19056640);  // [40224][64]
    float* CCGW = (float*)(w + 24205312);  // [40224][40] -> ends 30641152

    // prep
    extract_idx_all<<<8248, 256, 0, stream>>>(D0, D1, D2, U0, U1, U2,
                                              idxD0, idxD1, idxD2, idxU0, idxU1, idxU2);
    cvt_weights<<<3072, 256, 0, stream>>>(e1_wc, e2_wc, d0_wc, d1_wc,
                                          e1_wm, e2_wm, d0_wm, d1_wm, d2_wm, d2_wc,
                                          wcrE1, wcrE2, wcrD0, wcrD1,
                                          ccwE1, ccwE2, ccwD0, ccwD1, w3, zbuf);
    compose_tables<<<248, 256, 0, stream>>>(nbr0, nbr1, nbr2,
                                            idxD1, idxD2, idxU0, idxU1, idxU2,
                                            nbrD1, nbrD2, nbrU2, nbrU1, nbrU0,
                                            maskE1, maskE2);

    // encoder
    feast_e0<<<10056, 256, 0, stream>>>(x, nbr0, idxD0, e0_wm, e0_bm, e0_wc, e0_bc,
                                        X1, 5024, 1257, 5024, 40224);
    cc_gemm<16, 16><<<629, 256, 0, stream>>>(X1, ccwE1, CC1, 40224, 64);
    feast_lin<64, 128, 1><<<158, 256, 0, stream>>>(X1, CC1, nbrD1, maskE1, e1_bm,
                                                   wcrE1, e1_bc, X2, 1257, 315, 10080);
    cc_gemm<16, 16><<<158, 256, 0, stream>>>(X2, ccwE2, CC2, 10080, 128);
    feast_lin<128, 256, 1><<<40, 256, 0, stream>>>(X2, CC2, nbrD2, maskE2, e2_bm,
                                                   wcrE2, e2_bc, X3, 315, 80, 2560);

    // bottleneck
    fce2<<<dim3(256, 8), 256, 0, stream>>>(X3, fce_w, fce_b, zbuf);
    gemm_fcd<<<dim3(1, 320), 256, 0, stream>>>(zbuf, fcd_w, fcd_b, X3P, 32, 256, 20480);

    // decoder
    cc_gemm<16, 16><<<40, 256, 0, stream>>>(X3P, ccwD0, CCD0, 2560, 256);
    feast_lin<256, 128, 0><<<158, 256, 0, stream>>>(X3P, CCD0, nbrU2, nullptr, d0_bm,
                                                    wcrD0, d0_bc, XD1P, 80, 315, 10080);
    cc_gemm<16, 16><<<158, 256, 0, stream>>>(XD1P, ccwD1, CCD1, 10080, 128);
    feast_lin<128, 64, 0><<<629, 256, 0, stream>>>(XD1P, CCD1, nbrU1, nullptr, d1_bm,
                                                   wcrD1, d1_bc, XD2P, 315, 1257, 40224);
    cc_gemm<40, 40><<<629, 256, 0, stream>>>(XD2P, w3, CCGW, 40224, 64);
    mix_d2<<<628, 256, 0, stream>>>(CCGW, nbrU0, d2_bm, d2_bc, (float*)d_out);
}

// Round 5
// 370.712 us; speedup vs baseline: 4.0556x; 1.3059x over previous
//
#include <hip/hip_runtime.h>
#include <cstddef>

#define KN 9
typedef unsigned short u16;
typedef unsigned int u32;
typedef __attribute__((ext_vector_type(8))) short short8;
typedef __attribute__((ext_vector_type(4))) float f32x4;

__device__ inline u16 f2b(float f) {
    union { float f; u32 u; } v; v.f = f;
    u32 r = v.u + 0x7FFFu + ((v.u >> 16) & 1u);
    return (u16)(r >> 16);
}
__device__ inline float b2f(u16 h) {
    union { u32 u; float f; } v; v.u = ((u32)h) << 16; return v.f;
}

// ---------------------------------------------------------------------------
// all 6 one-hot pool matrices -> gather indices
// ---------------------------------------------------------------------------
__global__ void extract_idx_all(
    const float* __restrict__ D0, const float* __restrict__ D1, const float* __restrict__ D2,
    const float* __restrict__ U0, const float* __restrict__ U1, const float* __restrict__ U2,
    int* __restrict__ iD0, int* __restrict__ iD1, int* __restrict__ iD2,
    int* __restrict__ iU0, int* __restrict__ iU1, int* __restrict__ iU2)
{
    int blk = blockIdx.x;
    const float* L; int M; int* out; int p;
    if      (blk < 1257) { L = D0; M = 5024; out = iD0; p = blk; }
    else if (blk < 1572) { L = D1; M = 1257; out = iD1; p = blk - 1257; }
    else if (blk < 1652) { L = D2; M = 315;  out = iD2; p = blk - 1572; }
    else if (blk < 6676) { L = U0; M = 1257; out = iU0; p = blk - 1652; }
    else if (blk < 7933) { L = U1; M = 315;  out = iU1; p = blk - 6676; }
    else                 { L = U2; M = 80;   out = iU2; p = blk - 7933; }
    const float* row = L + (size_t)p * M;
    for (int m = threadIdx.x; m < M; m += 256)
        if (row[m] > 0.5f) out[p] = m;
}

// ---------------------------------------------------------------------------
// weight conversions + zbuf zeroing
//   wcr[c][j*F+f]   = wc[c][f*9+j]           (encoder linears)
//   wg [j*C+c][f]   = wc[c][f*9+j]           (decoder G-GEMMs)
//   ccw[n][f]       = (n<9) ? wm[n][f] : 0
//   w3  (d2 fused cc+gw)
// ---------------------------------------------------------------------------
__device__ inline void wcr_one(const float* __restrict__ wc, u16* __restrict__ out, int t, int F) {
    int FK = F * KN;
    int c = t / FK, rem = t - c * FK, j = rem / F, f = rem - j * F;
    out[t] = f2b(wc[(size_t)c * FK + f * KN + j]);
}
__device__ inline void wg_one(const float* __restrict__ wc, u16* __restrict__ out, int t, int F, int C) {
    int n = t / F, f = t - n * F;
    int j = n / C, c = n - j * C;
    out[t] = f2b(wc[(size_t)c * (F * KN) + f * KN + j]);
}
__device__ inline void ccw_one(const float* __restrict__ wm, u16* __restrict__ out, int t, int F) {
    int n = t / F, f = t - n * F;
    out[t] = (n < KN) ? f2b(wm[n * F + f]) : (u16)0;
}
__global__ void cvt_weights(
    const float* __restrict__ e1_wc, const float* __restrict__ e2_wc,
    const float* __restrict__ d0_wc, const float* __restrict__ d1_wc,
    const float* __restrict__ e1_wm, const float* __restrict__ e2_wm,
    const float* __restrict__ d0_wm, const float* __restrict__ d1_wm,
    const float* __restrict__ d2_wm, const float* __restrict__ d2_wc,
    u16* __restrict__ wcrE1, u16* __restrict__ wcrE2,
    u16* __restrict__ wg0, u16* __restrict__ wg1,
    u16* __restrict__ ccwE1, u16* __restrict__ ccwE2,
    u16* __restrict__ ccwD0, u16* __restrict__ ccwD1,
    u16* __restrict__ w3, float* __restrict__ zbuf)
{
    int t = blockIdx.x * 256 + threadIdx.x;
    if (t < 73728)  { wcr_one(e1_wc, wcrE1, t, 64);       return; } t -= 73728;
    if (t < 294912) { wcr_one(e2_wc, wcrE2, t, 128);      return; } t -= 294912;
    if (t < 294912) { wg_one(d0_wc, wg0, t, 256, 128);    return; } t -= 294912;
    if (t < 73728)  { wg_one(d1_wc, wg1, t, 128, 64);     return; } t -= 73728;
    if (t < 4096)   { ccw_one(e1_wm, ccwE1, t, 64);       return; } t -= 4096;
    if (t < 8192)   { ccw_one(e2_wm, ccwE2, t, 128);      return; } t -= 8192;
    if (t < 16384)  { ccw_one(d0_wm, ccwD0, t, 256);      return; } t -= 16384;
    if (t < 8192)   { ccw_one(d1_wm, ccwD1, t, 128);      return; } t -= 8192;
    if (t < 4096) {
        int n = t >> 6, k = t & 63;
        float v = 0.f;
        if (n < KN) v = d2_wm[n * 64 + k];
        else if (n >= 12 && n < 39) {
            int cj = n - 12, c = cj / KN, j = cj - c * KN;
            v = d2_wc[(size_t)c * 576 + k * KN + j];
        }
        w3[t] = f2b(v);
        return;
    } t -= 4096;
    if (t < 8192) zbuf[t] = 0.f;
}

// ---------------------------------------------------------------------------
// composed neighbor tables (stride 12) + encoder pad masks
// ---------------------------------------------------------------------------
__global__ void compose_tables(
    const int* __restrict__ nbr0, const int* __restrict__ nbr1, const int* __restrict__ nbr2,
    const int* __restrict__ idxD1, const int* __restrict__ idxD2,
    const int* __restrict__ idxU0, const int* __restrict__ idxU1, const int* __restrict__ idxU2,
    int* __restrict__ nbrD1, int* __restrict__ nbrD2,
    int* __restrict__ nbrU2, int* __restrict__ nbrU1, int* __restrict__ nbrU0,
    int* __restrict__ maskE1, int* __restrict__ maskE2)
{
    int t = blockIdx.x * 256 + threadIdx.x;
    if (t < 2835)  { int p = t / 9, j = t - p * 9; nbrD1[p * 12 + j] = nbr1[idxD1[p] * 9 + j]; return; } t -= 2835;
    if (t < 720)   { int p = t / 9, j = t - p * 9; nbrD2[p * 12 + j] = nbr2[idxD2[p] * 9 + j]; return; } t -= 720;
    if (t < 2835)  { int p = t / 9, j = t - p * 9; nbrU2[p * 12 + j] = idxU2[nbr2[p * 9 + j]]; return; } t -= 2835;
    if (t < 11313) { int p = t / 9, j = t - p * 9; nbrU1[p * 12 + j] = idxU1[nbr1[p * 9 + j]]; return; } t -= 11313;
    if (t < 45216) { int p = t / 9, j = t - p * 9; nbrU0[p * 12 + j] = idxU0[nbr0[p * 9 + j]]; return; } t -= 45216;
    if (t < 315)   { maskE1[t] = (idxD1[t] == 1256) ? 1 : 0; return; } t -= 315;
    if (t < 80)    { maskE2[t] = (idxD2[t] == 314) ? 1 : 0; }
}

// ---------------------------------------------------------------------------
// cc GEMM: out[m][nn<NW] = sum_f A[m][f]*W[nn][f]   (f32 out, row stride OS)
// ---------------------------------------------------------------------------
template<int NW, int OS>
__global__ __launch_bounds__(256) void cc_gemm(
    const u16* __restrict__ A, const u16* __restrict__ W,
    float* __restrict__ out, int M, int F)
{
    __shared__ u16 As[64 * 72];
    __shared__ u16 Ws[64 * 72];
    int tid = threadIdx.x;
    int mT = blockIdx.x * 64;
    int wid = tid >> 6, lane = tid & 63;
    int wr = wid >> 1, wcq = wid & 1;
    int r = lane & 15, g = lane >> 4;
    f32x4 acc[2][2];
    #pragma unroll
    for (int i = 0; i < 2; ++i)
        #pragma unroll
        for (int j = 0; j < 2; ++j)
            acc[i][j] = (f32x4){0.f, 0.f, 0.f, 0.f};

    for (int k0 = 0; k0 < F; k0 += 64) {
        #pragma unroll
        for (int h = 0; h < 2; ++h) {
            int gi = tid + h * 256;
            int m = gi >> 3, kg = gi & 7;
            uint4 va = {0u, 0u, 0u, 0u};
            int row = mT + m;
            if (row < M) va = *(const uint4*)(A + (size_t)row * F + k0 + kg * 8);
            *(uint4*)&As[m * 72 + kg * 8] = va;
            *(uint4*)&Ws[m * 72 + kg * 8] = *(const uint4*)(W + (size_t)m * F + k0 + kg * 8);
        }
        __syncthreads();
        #pragma unroll
        for (int S = 0; S < 2; ++S) {
            short8 af[2], bf[2];
            #pragma unroll
            for (int R = 0; R < 2; ++R)
                af[R] = *(const short8*)&As[(wr * 32 + R * 16 + r) * 72 + S * 32 + g * 8];
            #pragma unroll
            for (int C2 = 0; C2 < 2; ++C2)
                bf[C2] = *(const short8*)&Ws[(wcq * 32 + C2 * 16 + r) * 72 + S * 32 + g * 8];
            #pragma unroll
            for (int R = 0; R < 2; ++R)
                #pragma unroll
                for (int C2 = 0; C2 < 2; ++C2)
                    acc[R][C2] = __builtin_amdgcn_mfma_f32_16x16x32_bf16(af[R], bf[C2], acc[R][C2], 0, 0, 0);
        }
        __syncthreads();
    }
    #pragma unroll
    for (int R = 0; R < 2; ++R)
        #pragma unroll
        for (int C2 = 0; C2 < 2; ++C2)
            #pragma unroll
            for (int q = 0; q < 4; ++q) {
                int mm = mT + wr * 32 + R * 16 + g * 4 + q;
                int nn = wcq * 32 + C2 * 16 + r;
                if (mm < M && nn < NW)
                    out[(size_t)mm * OS + nn] = acc[R][C2][q];
            }
}

// ---------------------------------------------------------------------------
// GEMM with register double-buffer prefetch:
//   Y[m][n] = act( sum_k A[m][k]*W[n][k] + bias[n] ), bf16 out.
// MASK=1: zero rows where maskT[m % P] != 0. ACT=1: ELU.
// ---------------------------------------------------------------------------
template<int ACT, int MASK>
__global__ __launch_bounds__(256) void lin_gemm(
    const u16* __restrict__ A, const u16* __restrict__ W,
    const float* __restrict__ bias, u16* __restrict__ Y,
    const int* __restrict__ maskT,
    int M, int K, int N, int P)
{
    __shared__ u16 As[64 * 72];
    __shared__ u16 Ws[64 * 72];
    int tid = threadIdx.x;
    int mT = blockIdx.x * 64, nT = blockIdx.y * 64;
    int wid = tid >> 6, lane = tid & 63;
    int wr = wid >> 1, wcq = wid & 1;
    int r = lane & 15, g = lane >> 4;
    int lm = tid >> 3, lkg = tid & 7;       // load row (0..31 step over h), col-group
    f32x4 acc[2][2];
    #pragma unroll
    for (int i = 0; i < 2; ++i)
        #pragma unroll
        for (int j = 0; j < 2; ++j)
            acc[i][j] = (f32x4){0.f, 0.f, 0.f, 0.f};

    uint4 ra[2], rw[2];
    #pragma unroll
    for (int h = 0; h < 2; ++h) {
        int m = lm + h * 32;
        int row = mT + m;
        uint4 z; z.x = z.y = z.z = z.w = 0u;
        ra[h] = (row < M) ? *(const uint4*)(A + (size_t)row * K + lkg * 8) : z;
        rw[h] = *(const uint4*)(W + (size_t)(nT + m) * K + lkg * 8);
    }

    for (int k0 = 0; k0 < K; k0 += 64) {
        #pragma unroll
        for (int h = 0; h < 2; ++h) {
            int m = lm + h * 32;
            *(uint4*)&As[m * 72 + lkg * 8] = ra[h];
            *(uint4*)&Ws[m * 72 + lkg * 8] = rw[h];
        }
        __syncthreads();
        bool more = (k0 + 64 < K);
        if (more) {
            int kn = k0 + 64;
            #pragma unroll
            for (int h = 0; h < 2; ++h) {
                int m = lm + h * 32;
                int row = mT + m;
                uint4 z; z.x = z.y = z.z = z.w = 0u;
                ra[h] = (row < M) ? *(const uint4*)(A + (size_t)row * K + kn + lkg * 8) : z;
                rw[h] = *(const uint4*)(W + (size_t)(nT + m) * K + kn + lkg * 8);
            }
        }
        #pragma unroll
        for (int S = 0; S < 2; ++S) {
            short8 af[2], bf[2];
            #pragma unroll
            for (int R = 0; R < 2; ++R)
                af[R] = *(const short8*)&As[(wr * 32 + R * 16 + r) * 72 + S * 32 + g * 8];
            #pragma unroll
            for (int C2 = 0; C2 < 2; ++C2)
                bf[C2] = *(const short8*)&Ws[(wcq * 32 + C2 * 16 + r) * 72 + S * 32 + g * 8];
            #pragma unroll
            for (int R = 0; R < 2; ++R)
                #pragma unroll
                for (int C2 = 0; C2 < 2; ++C2)
                    acc[R][C2] = __builtin_amdgcn_mfma_f32_16x16x32_bf16(af[R], bf[C2], acc[R][C2], 0, 0, 0);
        }
        __syncthreads();
    }

    #pragma unroll
    for (int R = 0; R < 2; ++R)
        #pragma unroll
        for (int C2 = 0; C2 < 2; ++C2)
            #pragma unroll
            for (int q = 0; q < 4; ++q) {
                int mm = mT + wr * 32 + R * 16 + g * 4 + q;
                if (mm >= M) continue;
                int nn = nT + wcq * 32 + C2 * 16 + r;
                float v = acc[R][C2][q];
                if (bias) v += bias[nn];
                if (ACT == 1) v = v > 0.f ? v : expm1f(v);
                if (MASK) { if (maskT[mm % P] != 0) v = 0.f; }
                Y[(size_t)mm * N + nn] = f2b(v);
            }
}

// ---------------------------------------------------------------------------
// encoder feast agg: P from gathered cc (stride-16), agg via register xn.
//   row = b*P+p, verts = b*Pin + nbrT[p*12+i]; agg[row][j*F+f] bf16.
// ---------------------------------------------------------------------------
template<int F>
__global__ __launch_bounds__(256) void feast_agg(
    const u16* __restrict__ x, const float* __restrict__ cc,
    const int* __restrict__ nbrT, const float* __restrict__ bm,
    u16* __restrict__ agg, int Pin, int P, int Mtot)
{
    constexpr int FC = F / 64;
    __shared__ float s_p[4][81];
    __shared__ int s_nb[4][KN];
    int tid = threadIdx.x, wid = tid >> 6, lane = tid & 63;
    int row = blockIdx.x * 4 + wid;
    bool aw = row < Mtot;
    int b = 0, p = 0;
    if (aw) { b = row / P; p = row - b * P; }
    if (aw && lane < KN) s_nb[wid][lane] = b * Pin + nbrT[p * 12 + lane];
    __syncthreads();

    if (aw && lane < KN) {
        int j = lane;
        const float* c0 = cc + (size_t)s_nb[wid][0] * 16;
        const float* cj = cc + (size_t)s_nb[wid][j] * 16;
        float L[KN];
        #pragma unroll
        for (int i = 0; i < KN; ++i) L[i] = bm[i] + cj[i] - c0[i];
        float mx = L[0];
        #pragma unroll
        for (int i = 1; i < KN; ++i) mx = fmaxf(mx, L[i]);
        float s = 0.f;
        #pragma unroll
        for (int i = 0; i < KN; ++i) { L[i] = __expf(L[i] - mx); s += L[i]; }
        float inv = 1.f / s;
        #pragma unroll
        for (int i = 0; i < KN; ++i) s_p[wid][i * KN + j] = L[i] * inv;
    }
    __syncthreads();

    if (aw) {
        float xn[KN][FC];
        #pragma unroll
        for (int i = 0; i < KN; ++i) {
            const u16* xr = x + (size_t)s_nb[wid][i] * F;
            #pragma unroll
            for (int c = 0; c < FC; ++c) xn[i][c] = b2f(xr[lane + c * 64]);
        }
        #pragma unroll
        for (int j = 0; j < KN; ++j) {
            float a[FC];
            #pragma unroll
            for (int c = 0; c < FC; ++c) a[c] = 0.f;
            #pragma unroll
            for (int i = 0; i < KN; ++i) {
                float pv = s_p[wid][i * KN + j];
                #pragma unroll
                for (int c = 0; c < FC; ++c) a[c] += xn[i][c] * pv;
            }
            u16* orow = agg + (size_t)row * (KN * F) + j * F;
            #pragma unroll
            for (int c = 0; c < FC; ++c) orow[lane + c * 64] = f2b(a[c]);
        }
    }
}

// ---------------------------------------------------------------------------
// decoder mix: y[row][c] = elu( bc[c] + sum_{i,j} P[i][j] * G[vert_i][j*C+c] )
// one wave per row; G bf16 (stride 9*C); pad row (p==P-1) zeroed.
// ---------------------------------------------------------------------------
template<int C>
__global__ __launch_bounds__(256) void mix_feast(
    const u16* __restrict__ G, const float* __restrict__ cc,
    const int* __restrict__ nbrT, const float* __restrict__ bm,
    const float* __restrict__ bc, u16* __restrict__ y,
    int Pin, int P, int Mtot)
{
    constexpr int GS = KN * C;
    constexpr int CC_ = C / 64;
    __shared__ float s_p[4][81];
    __shared__ int s_nb[4][KN];
    int tid = threadIdx.x, wid = tid >> 6, lane = tid & 63;
    int row = blockIdx.x * 4 + wid;
    bool aw = row < Mtot;
    int b = 0, p = 0;
    if (aw) { b = row / P; p = row - b * P; }
    if (aw && lane < KN) s_nb[wid][lane] = b * Pin + nbrT[p * 12 + lane];
    __syncthreads();

    if (aw && lane < KN) {
        int j = lane;
        const float* c0 = cc + (size_t)s_nb[wid][0] * 16;
        const float* cj = cc + (size_t)s_nb[wid][j] * 16;
        float L[KN];
        #pragma unroll
        for (int i = 0; i < KN; ++i) L[i] = bm[i] + cj[i] - c0[i];
        float mx = L[0];
        #pragma unroll
        for (int i = 1; i < KN; ++i) mx = fmaxf(mx, L[i]);
        float s = 0.f;
        #pragma unroll
        for (int i = 0; i < KN; ++i) { L[i] = __expf(L[i] - mx); s += L[i]; }
        float inv = 1.f / s;
        #pragma unroll
        for (int i = 0; i < KN; ++i) s_p[wid][i * KN + j] = L[i] * inv;
    }
    __syncthreads();

    if (aw) {
        float acc[CC_];
        #pragma unroll
        for (int c = 0; c < CC_; ++c) acc[c] = bc[lane + c * 64];
        #pragma unroll
        for (int i = 0; i < KN; ++i) {
            const u16* gr = G + (size_t)s_nb[wid][i] * GS;
            float pv[KN];
            #pragma unroll
            for (int j = 0; j < KN; ++j) pv[j] = s_p[wid][i * KN + j];
            #pragma unroll
            for (int j = 0; j < KN; ++j)
                #pragma unroll
                for (int c = 0; c < CC_; ++c)
                    acc[c] += pv[j] * b2f(gr[j * C + lane + c * 64]);
        }
        #pragma unroll
        for (int c = 0; c < CC_; ++c) {
            float v = acc[c];
            v = v > 0.f ? v : expm1f(v);
            if (p == P - 1) v = 0.f;
            y[(size_t)row * C + lane + c * 64] = f2b(v);
        }
    }
}

// ---------------------------------------------------------------------------
// e0 fused feast (F=3 -> C=64), bf16 output, fused D0 pooling via sel
// ---------------------------------------------------------------------------
__global__ __launch_bounds__(256) void feast_e0(
    const float* __restrict__ x, const int* __restrict__ nbr,
    const int* __restrict__ sel,
    const float* __restrict__ wm, const float* __restrict__ bm,
    const float* __restrict__ wcw, const float* __restrict__ bc,
    u16* __restrict__ y,
    int Nin, int P, int Nlevel, int Mtot)
{
    constexpr int F = 3, C = 64, FS = 4, Q = 27;
    __shared__ float s_wm[KN * FS];
    __shared__ float s_wc[C * Q];
    __shared__ float s_bm[KN];
    __shared__ float s_xn[4][KN * FS];
    __shared__ float s_lg[4][81];
    __shared__ float s_pm[4][81];
    __shared__ float s_ag[4][Q];
    __shared__ int   s_idx[4][KN];

    int tid = threadIdx.x, wid = tid >> 6, lane = tid & 63;
    for (int t = tid; t < KN * F; t += 256) { int i = t / F, f = t - i * F; s_wm[i * FS + f] = wm[t]; }
    for (int t = tid; t < C * Q; t += 256) s_wc[t] = wcw[t];
    if (tid < KN) s_bm[tid] = bm[tid];

    int wg = blockIdx.x * 4 + wid;
    bool aw = wg < Mtot;
    int b = 0, p = 0, n = 0;
    if (aw) {
        b = wg / P; p = wg - b * P;
        n = sel[p];
    }
    if (aw && lane < KN) s_idx[wid][lane] = nbr[n * KN + lane];
    __syncthreads();

    if (aw) {
        const float* xb = x + (size_t)b * Nin * F;
        for (int t = lane; t < KN * F; t += 64) {
            int i = t / F, f = t - i * F;
            s_xn[wid][i * FS + f] = xb[(size_t)s_idx[wid][i] * F + f];
        }
    }
    __syncthreads();

    if (aw) {
        for (int pr = lane; pr < 81; pr += 64) {
            int i = pr / KN, j = pr - i * KN;
            float acc = s_bm[i];
            for (int f = 0; f < F; ++f)
                acc += (s_xn[wid][j * FS + f] - s_xn[wid][f]) * s_wm[i * FS + f];
            s_lg[wid][pr] = acc;
        }
    }
    __syncthreads();

    if (aw && lane < KN) {
        int j = lane;
        float mx = -1e30f;
        #pragma unroll
        for (int i = 0; i < KN; ++i) mx = fmaxf(mx, s_lg[wid][i * KN + j]);
        float sm = 0.f, ev[KN];
        #pragma unroll
        for (int i = 0; i < KN; ++i) { ev[i] = __expf(s_lg[wid][i * KN + j] - mx); sm += ev[i]; }
        float inv = 1.f / sm;
        #pragma unroll
        for (int i = 0; i < KN; ++i) s_pm[wid][i * KN + j] = ev[i] * inv;
    }
    __syncthreads();

    if (aw) {
        for (int t = lane; t < Q; t += 64) {
            int f = t / KN, j = t - f * KN;
            float acc = 0.f;
            #pragma unroll
            for (int i = 0; i < KN; ++i) acc += s_xn[wid][i * FS + f] * s_pm[wid][i * KN + j];
            s_ag[wid][t] = acc;
        }
    }
    __syncthreads();

    if (aw) {
        int c = lane;
        float acc = 0.f;
        #pragma unroll
        for (int q = 0; q < Q; ++q)
            acc += s_wc[c * Q + q] * s_ag[wid][q];
        float val = acc + bc[c];
        val = val > 0.f ? val : expm1f(val);
        if (n == Nlevel - 1) val = 0.f;
        y[(size_t)wg * C + c] = f2b(val);
    }
}

// ---------------------------------------------------------------------------
// fce split-K: z[b][l] += sum_{k in slice} X3[b][k]*w[l][k]  (+bias at ks==0)
// ---------------------------------------------------------------------------
__global__ __launch_bounds__(256) void fce2(
    const u16* __restrict__ X3, const float* __restrict__ w,
    const float* __restrict__ bias, float* __restrict__ z)
{
    int l = blockIdx.x, ks = blockIdx.y;
    int k0 = ks * 2560;
    float acc[32];
    #pragma unroll
    for (int b = 0; b < 32; ++b) acc[b] = 0.f;
    for (int it = 0; it < 10; ++it) {
        int k = k0 + it * 256 + threadIdx.x;
        float wv = w[(size_t)l * 20480 + k];
        #pragma unroll
        for (int b = 0; b < 32; ++b) acc[b] += b2f(X3[(size_t)b * 20480 + k]) * wv;
    }
    __shared__ float sp[4][32];
    int wid = threadIdx.x >> 6, lane = threadIdx.x & 63;
    #pragma unroll
    for (int b = 0; b < 32; ++b) {
        float v = acc[b];
        for (int off = 32; off > 0; off >>= 1) v += __shfl_down(v, off, 64);
        if (lane == 0) sp[wid][b] = v;
    }
    __syncthreads();
    if (threadIdx.x < 32) {
        float sv = sp[0][threadIdx.x] + sp[1][threadIdx.x]
                 + sp[2][threadIdx.x] + sp[3][threadIdx.x];
        if (ks == 0) sv += bias[l];
        atomicAdd(&z[threadIdx.x * 256 + l], sv);
    }
}

// ---------------------------------------------------------------------------
// fp32 tiled GEMM for fcd (M=32, K=256, N=20480), bf16 output
// ---------------------------------------------------------------------------
__global__ __launch_bounds__(256) void gemm_fcd(
    const float* __restrict__ A, const float* __restrict__ W,
    const float* __restrict__ bias, u16* __restrict__ Y,
    int Mc, int Kd, int C)
{
    __shared__ float As[32][68];
    __shared__ float Ws[32][68];
    int tid = threadIdx.x;
    int mBase = blockIdx.x * 64, cBase = blockIdx.y * 64;
    int tx = tid & 15, ty = tid >> 4;
    float acc[4][4] = {};

    for (int k0 = 0; k0 < Kd; k0 += 32) {
        #pragma unroll
        for (int rr = 0; rr < 8; ++rr) {
            int t = tid + rr * 256;
            int kk = t & 31, i = t >> 5;
            int mi = mBase + i;
            As[kk][i] = (mi < Mc) ? A[(size_t)mi * Kd + k0 + kk] : 0.f;
        }
        #pragma unroll
        for (int rr = 0; rr < 8; ++rr) {
            int t = tid + rr * 256;
            int kk = t & 31, i = t >> 5;
            Ws[kk][i] = W[(size_t)(cBase + i) * Kd + k0 + kk];
        }
        __syncthreads();
        #pragma unroll
        for (int kk = 0; kk < 32; ++kk) {
            float4 av = *(const float4*)&As[kk][ty * 4];
            float4 wv = *(const float4*)&Ws[kk][tx * 4];
            float a[4] = {av.x, av.y, av.z, av.w};
            float wv2[4] = {wv.x, wv.y, wv.z, wv.w};
            #pragma unroll
            for (int u = 0; u < 4; ++u)
                #pragma unroll
                for (int v = 0; v < 4; ++v)
                    acc[u][v] += a[u] * wv2[v];
        }
        __syncthreads();
    }
    #pragma unroll
    for (int u = 0; u < 4; ++u) {
        int mi = mBase + ty * 4 + u;
        if (mi >= Mc) continue;
        #pragma unroll
        for (int v = 0; v < 4; ++v) {
            float val = acc[u][v] + bias[cBase + tx * 4 + v];
            Y[(size_t)mi * C + cBase + tx * 4 + v] = f2b(val);
        }
    }
}

// ---------------------------------------------------------------------------
// d2 mix: y[c] = bc[c] + sum_{i,j} P[i][j]*gw[nbr_i][c][j], via composed nbrU0
// ccgw rows stride 40: [0..8]=cc, [12..38]=gw
// ---------------------------------------------------------------------------
__global__ __launch_bounds__(256) void mix_d2(
    const float* __restrict__ ccgw, const int* __restrict__ nbrT,
    const float* __restrict__ bm9, const float* __restrict__ bc3,
    float* __restrict__ out)
{
    int t = blockIdx.x * 256 + threadIdx.x;
    if (t >= 160768) return;
    int b = t / 5024, v = t - b * 5024;
    int nbi[KN];
    #pragma unroll
    for (int i = 0; i < KN; ++i) nbi[i] = nbrT[v * 12 + i];
    const float* base = ccgw + (size_t)b * 1257 * 40;
    float cc0[12];
    {
        const float* r0 = base + (size_t)nbi[0] * 40;
        *(float4*)&cc0[0] = *(const float4*)(r0);
        *(float4*)&cc0[4] = *(const float4*)(r0 + 4);
        *(float4*)&cc0[8] = *(const float4*)(r0 + 8);
    }
    float Pm[81];
    #pragma unroll
    for (int j = 0; j < KN; ++j) {
        float cj[12];
        const float* rj = base + (size_t)nbi[j] * 40;
        *(float4*)&cj[0] = *(const float4*)(rj);
        *(float4*)&cj[4] = *(const float4*)(rj + 4);
        *(float4*)&cj[8] = *(const float4*)(rj + 8);
        #pragma unroll
        for (int i = 0; i < KN; ++i) Pm[i * KN + j] = bm9[i] + cj[i] - cc0[i];
    }
    #pragma unroll
    for (int j = 0; j < KN; ++j) {
        float mx = Pm[j];
        #pragma unroll
        for (int i = 1; i < KN; ++i) mx = fmaxf(mx, Pm[i * KN + j]);
        float sm = 0.f;
        #pragma unroll
        for (int i = 0; i < KN; ++i) { float e = __expf(Pm[i * KN + j] - mx); Pm[i * KN + j] = e; sm += e; }
        float inv = 1.f / sm;
        #pragma unroll
        for (int i = 0; i < KN; ++i) Pm[i * KN + j] *= inv;
    }
    float a0 = bc3[0], a1 = bc3[1], a2 = bc3[2];
    #pragma unroll
    for (int i = 0; i < KN; ++i) {
        float gv[28];
        const float* gr = base + (size_t)nbi[i] * 40 + 12;
        *(float4*)&gv[0]  = *(const float4*)(gr);
        *(float4*)&gv[4]  = *(const float4*)(gr + 4);
        *(float4*)&gv[8]  = *(const float4*)(gr + 8);
        *(float4*)&gv[12] = *(const float4*)(gr + 12);
        *(float4*)&gv[16] = *(const float4*)(gr + 16);
        *(float4*)&gv[20] = *(const float4*)(gr + 20);
        *(float4*)&gv[24] = *(const float4*)(gr + 24);
        #pragma unroll
        for (int j = 0; j < KN; ++j) {
            float pv = Pm[i * KN + j];
            a0 += pv * gv[0 * KN + j];
            a1 += pv * gv[1 * KN + j];
            a2 += pv * gv[2 * KN + j];
        }
    }
    if (v == 5023) { a0 = 0.f; a1 = 0.f; a2 = 0.f; }
    out[(size_t)t * 3 + 0] = a0;
    out[(size_t)t * 3 + 1] = a1;
    out[(size_t)t * 3 + 2] = a2;
}

// ---------------------------------------------------------------------------
extern "C" void kernel_launch(void* const* d_in, const int* in_sizes, int n_in,
                              void* d_out, int out_size, void* d_ws, size_t ws_size,
                              hipStream_t stream)
{
    const float* x     = (const float*)d_in[0];
    const int*   nbr0  = (const int*)d_in[1];
    const int*   nbr1  = (const int*)d_in[2];
    const int*   nbr2  = (const int*)d_in[3];
    const float* D0    = (const float*)d_in[4];
    const float* U0    = (const float*)d_in[5];
    const float* D1    = (const float*)d_in[6];
    const float* U1    = (const float*)d_in[7];
    const float* D2    = (const float*)d_in[8];
    const float* U2    = (const float*)d_in[9];
    const float* e0_wm = (const float*)d_in[10]; const float* e0_bm = (const float*)d_in[11];
    const float* e0_wc = (const float*)d_in[12]; const float* e0_bc = (const float*)d_in[13];
    const float* e1_wm = (const float*)d_in[14]; const float* e1_bm = (const float*)d_in[15];
    const float* e1_wc = (const float*)d_in[16]; const float* e1_bc = (const float*)d_in[17];
    const float* e2_wm = (const float*)d_in[18]; const float* e2_bm = (const float*)d_in[19];
    const float* e2_wc = (const float*)d_in[20]; const float* e2_bc = (const float*)d_in[21];
    const float* fce_w = (const float*)d_in[22]; const float* fce_b = (const float*)d_in[23];
    const float* fcd_w = (const float*)d_in[24]; const float* fcd_b = (const float*)d_in[25];
    const float* d0_wm = (const float*)d_in[26]; const float* d0_bm = (const float*)d_in[27];
    const float* d0_wc = (const float*)d_in[28]; const float* d0_bc = (const float*)d_in[29];
    const float* d1_wm = (const float*)d_in[30]; const float* d1_bm = (const float*)d_in[31];
    const float* d1_wc = (const float*)d_in[32]; const float* d1_bc = (const float*)d_in[33];
    const float* d2_wm = (const float*)d_in[34]; const float* d2_bm = (const float*)d_in[35];
    const float* d2_wc = (const float*)d_in[36]; const float* d2_bc = (const float*)d_in[37];

    char* w = (char*)d_ws;
    int* idxD0 = (int*)(w);              // 1257
    int* idxD1 = idxD0 + 1257;           // 315
    int* idxD2 = idxD1 + 315;            // 80
    int* idxU0 = idxD2 + 80;             // 5024
    int* idxU1 = idxU0 + 5024;           // 1257
    int* idxU2 = idxU1 + 1257;           // 315 -> ends byte 32992
    int* nbrD1  = (int*)(w + 33024);
    int* nbrD2  = (int*)(w + 48144);
    int* nbrU2  = (int*)(w + 51984);
    int* nbrU1  = (int*)(w + 67104);
    int* nbrU0  = (int*)(w + 127440);
    int* maskE1 = (int*)(w + 368640);
    int* maskE2 = (int*)(w + 369920);
    u16* wcrE1 = (u16*)(w + 370432);     // 73728
    u16* wcrE2 = (u16*)(w + 517888);     // 294912
    u16* wg0   = (u16*)(w + 1107712);    // 294912  [1152][256]
    u16* wg1   = (u16*)(w + 1697536);    // 73728   [576][128]
    u16* ccwE1 = (u16*)(w + 1844992);
    u16* ccwE2 = (u16*)(w + 1853184);
    u16* ccwD0 = (u16*)(w + 1869568);
    u16* ccwD1 = (u16*)(w + 1902336);
    u16* w3    = (u16*)(w + 1918720);
    float* zbuf = (float*)(w + 1926912); // -> 1959680

    // activation buffers (alias-packed; peak ~37 MB)
    u16*   X1   = (u16*)  (w + 2097152);   // [40224][64]  -> 7245824
    float* CC1  = (float*)(w + 7245824);   // [40224][16]  -> 9820160
    u16*   AGG1 = (u16*)  (w + 9820160);   // [10080][576] -> 21432320
    u16*   X2   = (u16*)  (w + 21432320);  // [10080][128] -> 24012800
    float* CC2  = (float*)(w + 24012800);  // [10080][16]  -> 24657920
    u16*   AGG2 = (u16*)  (w + 24657920);  // [2560][1152] -> 30556160
    u16*   X3   = (u16*)  (w + 2097152);   // [2560][256]  -> 3407872   (X1 dead)
    u16*   X3P  = (u16*)  (w + 3407872);   // [2560][256]  -> 4718592
    float* CCD0 = (float*)(w + 4718592);   // [2560][16]   -> 4882432
    u16*   G0   = (u16*)  (w + 4882432);   // [2560][1152] -> 10780672  (CC1/AGG1 dead)
    u16*   XD1P = (u16*)  (w + 10780672);  // [10080][128] -> 13361152
    float* CCD1 = (float*)(w + 13361152);  // [10080][16]  -> 14006272
    u16*   G1   = (u16*)  (w + 14006272);  // [10080][576] -> 25618432  (X2/CC2/AGG2 dead by write time)
    u16*   XD2P = (u16*)  (w + 25618432);  // [40224][64]  -> 30767104
    float* CCGW = (float*)(w + 30767104);  // [40224][40]  -> 37202944

    // prep
    extract_idx_all<<<8248, 256, 0, stream>>>(D0, D1, D2, U0, U1, U2,
                                              idxD0, idxD1, idxD2, idxU0, idxU1, idxU2);
    cvt_weights<<<3072, 256, 0, stream>>>(e1_wc, e2_wc, d0_wc, d1_wc,
                                          e1_wm, e2_wm, d0_wm, d1_wm, d2_wm, d2_wc,
                                          wcrE1, wcrE2, wg0, wg1,
                                          ccwE1, ccwE2, ccwD0, ccwD1, w3, zbuf);
    compose_tables<<<248, 256, 0, stream>>>(nbr0, nbr1, nbr2,
                                            idxD1, idxD2, idxU0, idxU1, idxU2,
                                            nbrD1, nbrD2, nbrU2, nbrU1, nbrU0,
                                            maskE1, maskE2);

    // ---- encoder ----
    feast_e0<<<10056, 256, 0, stream>>>(x, nbr0, idxD0, e0_wm, e0_bm, e0_wc, e0_bc,
                                        X1, 5024, 1257, 5024, 40224);
    cc_gemm<16, 16><<<629, 256, 0, stream>>>(X1, ccwE1, CC1, 40224, 64);
    feast_agg<64><<<2520, 256, 0, stream>>>(X1, CC1, nbrD1, e1_bm, AGG1, 1257, 315, 10080);
    lin_gemm<1, 1><<<dim3(158, 2), 256, 0, stream>>>(AGG1, wcrE1, e1_bc, X2, maskE1,
                                                     10080, 576, 128, 315);
    cc_gemm<16, 16><<<158, 256, 0, stream>>>(X2, ccwE2, CC2, 10080, 128);
    feast_agg<128><<<640, 256, 0, stream>>>(X2, CC2, nbrD2, e2_bm, AGG2, 315, 80, 2560);
    lin_gemm<1, 1><<<dim3(40, 4), 256, 0, stream>>>(AGG2, wcrE2, e2_bc, X3, maskE2,
                                                    2560, 1152, 256, 80);

    // ---- bottleneck ----
    fce2<<<dim3(256, 8), 256, 0, stream>>>(X3, fce_w, fce_b, zbuf);
    gemm_fcd<<<dim3(1, 320), 256, 0, stream>>>(zbuf, fcd_w, fcd_b, X3P, 32, 256, 20480);

    // ---- decoder ----
    cc_gemm<16, 16><<<40, 256, 0, stream>>>(X3P, ccwD0, CCD0, 2560, 256);
    lin_gemm<0, 0><<<dim3(40, 18), 256, 0, stream>>>(X3P, wg0, nullptr, G0, nullptr,
                                                     2560, 256, 1152, 1);
    mix_feast<128><<<2520, 256, 0, stream>>>(G0, CCD0, nbrU2, d0_bm, d0_bc, XD1P,
                                             80, 315, 10080);
    cc_gemm<16, 16><<<158, 256, 0, stream>>>(XD1P, ccwD1, CCD1, 10080, 128);
    lin_gemm<0, 0><<<dim3(158, 9), 256, 0, stream>>>(XD1P, wg1, nullptr, G1, nullptr,
                                                     10080, 128, 576, 1);
    mix_feast<64><<<10056, 256, 0, stream>>>(G1, CCD1, nbrU1, d1_bm, d1_bc, XD2P,
                                             315, 1257, 40224);
    cc_gemm<40, 40><<<629, 256, 0, stream>>>(XD2P, w3, CCGW, 40224, 64);
    mix_d2<<<628, 256, 0, stream>>>(CCGW, nbrU0, d2_bm, d2_bc, (float*)d_out);
}

// Round 6
// 357.773 us; speedup vs baseline: 4.2023x; 1.0362x over previous
//
#include <hip/hip_runtime.h>
#include <cstddef>

#define KN 9
typedef unsigned short u16;
typedef unsigned int u32;
typedef __attribute__((ext_vector_type(8))) short short8;
typedef __attribute__((ext_vector_type(4))) float f32x4;

__device__ inline u16 f2b(float f) {
    union { float f; u32 u; } v; v.f = f;
    u32 r = v.u + 0x7FFFu + ((v.u >> 16) & 1u);
    return (u16)(r >> 16);
}
__device__ inline float b2f(u16 h) {
    union { u32 u; float f; } v; v.u = ((u32)h) << 16; return v.f;
}

// bijective XCD-aware block swizzle (m204): blocks with the same bid%8 (same
// XCD under round-robin dispatch) get a CONTIGUOUS chunk of the work space,
// so each XCD's gather working set stays in its private L2.
__device__ inline int xcd_swz(int bid, int n) {
    int q = n >> 3, r = n & 7;
    int x = bid & 7, pos = bid >> 3;
    return (x < r ? x * (q + 1) : r * (q + 1) + (x - r) * q) + pos;
}

// ---------------------------------------------------------------------------
// all 6 one-hot pool matrices -> gather indices
// ---------------------------------------------------------------------------
__global__ void extract_idx_all(
    const float* __restrict__ D0, const float* __restrict__ D1, const float* __restrict__ D2,
    const float* __restrict__ U0, const float* __restrict__ U1, const float* __restrict__ U2,
    int* __restrict__ iD0, int* __restrict__ iD1, int* __restrict__ iD2,
    int* __restrict__ iU0, int* __restrict__ iU1, int* __restrict__ iU2)
{
    int blk = blockIdx.x;
    const float* L; int M; int* out; int p;
    if      (blk < 1257) { L = D0; M = 5024; out = iD0; p = blk; }
    else if (blk < 1572) { L = D1; M = 1257; out = iD1; p = blk - 1257; }
    else if (blk < 1652) { L = D2; M = 315;  out = iD2; p = blk - 1572; }
    else if (blk < 6676) { L = U0; M = 1257; out = iU0; p = blk - 1652; }
    else if (blk < 7933) { L = U1; M = 315;  out = iU1; p = blk - 6676; }
    else                 { L = U2; M = 80;   out = iU2; p = blk - 7933; }
    const float* row = L + (size_t)p * M;
    for (int m = threadIdx.x; m < M; m += 256)
        if (row[m] > 0.5f) out[p] = m;
}

// ---------------------------------------------------------------------------
// weight conversions + zbuf zeroing
// ---------------------------------------------------------------------------
__device__ inline void wcr_one(const float* __restrict__ wc, u16* __restrict__ out, int t, int F) {
    int FK = F * KN;
    int c = t / FK, rem = t - c * FK, j = rem / F, f = rem - j * F;
    out[t] = f2b(wc[(size_t)c * FK + f * KN + j]);
}
__device__ inline void wg_one(const float* __restrict__ wc, u16* __restrict__ out, int t, int F, int C) {
    int n = t / F, f = t - n * F;
    int j = n / C, c = n - j * C;
    out[t] = f2b(wc[(size_t)c * (F * KN) + f * KN + j]);
}
__device__ inline void ccw_one(const float* __restrict__ wm, u16* __restrict__ out, int t, int F) {
    int n = t / F, f = t - n * F;
    out[t] = (n < KN) ? f2b(wm[n * F + f]) : (u16)0;
}
__global__ void cvt_weights(
    const float* __restrict__ e1_wc, const float* __restrict__ e2_wc,
    const float* __restrict__ d0_wc, const float* __restrict__ d1_wc,
    const float* __restrict__ e1_wm, const float* __restrict__ e2_wm,
    const float* __restrict__ d0_wm, const float* __restrict__ d1_wm,
    const float* __restrict__ d2_wm, const float* __restrict__ d2_wc,
    u16* __restrict__ wcrE1, u16* __restrict__ wcrE2,
    u16* __restrict__ wg0, u16* __restrict__ wg1,
    u16* __restrict__ ccwE1, u16* __restrict__ ccwE2,
    u16* __restrict__ ccwD0, u16* __restrict__ ccwD1,
    u16* __restrict__ w3, float* __restrict__ zbuf)
{
    int t = blockIdx.x * 256 + threadIdx.x;
    if (t < 73728)  { wcr_one(e1_wc, wcrE1, t, 64);       return; } t -= 73728;
    if (t < 294912) { wcr_one(e2_wc, wcrE2, t, 128);      return; } t -= 294912;
    if (t < 294912) { wg_one(d0_wc, wg0, t, 256, 128);    return; } t -= 294912;
    if (t < 73728)  { wg_one(d1_wc, wg1, t, 128, 64);     return; } t -= 73728;
    if (t < 4096)   { ccw_one(e1_wm, ccwE1, t, 64);       return; } t -= 4096;
    if (t < 8192)   { ccw_one(e2_wm, ccwE2, t, 128);      return; } t -= 8192;
    if (t < 16384)  { ccw_one(d0_wm, ccwD0, t, 256);      return; } t -= 16384;
    if (t < 8192)   { ccw_one(d1_wm, ccwD1, t, 128);      return; } t -= 8192;
    if (t < 4096) {
        int n = t >> 6, k = t & 63;
        float v = 0.f;
        if (n < KN) v = d2_wm[n * 64 + k];
        else if (n >= 12 && n < 39) {
            int cj = n - 12, c = cj / KN, j = cj - c * KN;
            v = d2_wc[(size_t)c * 576 + k * KN + j];
        }
        w3[t] = f2b(v);
        return;
    } t -= 4096;
    if (t < 8192) zbuf[t] = 0.f;
}

// ---------------------------------------------------------------------------
// composed neighbor tables (stride 12) + encoder pad masks
// ---------------------------------------------------------------------------
__global__ void compose_tables(
    const int* __restrict__ nbr0, const int* __restrict__ nbr1, const int* __restrict__ nbr2,
    const int* __restrict__ idxD1, const int* __restrict__ idxD2,
    const int* __restrict__ idxU0, const int* __restrict__ idxU1, const int* __restrict__ idxU2,
    int* __restrict__ nbrD1, int* __restrict__ nbrD2,
    int* __restrict__ nbrU2, int* __restrict__ nbrU1, int* __restrict__ nbrU0,
    int* __restrict__ maskE1, int* __restrict__ maskE2)
{
    int t = blockIdx.x * 256 + threadIdx.x;
    if (t < 2835)  { int p = t / 9, j = t - p * 9; nbrD1[p * 12 + j] = nbr1[idxD1[p] * 9 + j]; return; } t -= 2835;
    if (t < 720)   { int p = t / 9, j = t - p * 9; nbrD2[p * 12 + j] = nbr2[idxD2[p] * 9 + j]; return; } t -= 720;
    if (t < 2835)  { int p = t / 9, j = t - p * 9; nbrU2[p * 12 + j] = idxU2[nbr2[p * 9 + j]]; return; } t -= 2835;
    if (t < 11313) { int p = t / 9, j = t - p * 9; nbrU1[p * 12 + j] = idxU1[nbr1[p * 9 + j]]; return; } t -= 11313;
    if (t < 45216) { int p = t / 9, j = t - p * 9; nbrU0[p * 12 + j] = idxU0[nbr0[p * 9 + j]]; return; } t -= 45216;
    if (t < 315)   { maskE1[t] = (idxD1[t] == 1256) ? 1 : 0; return; } t -= 315;
    if (t < 80)    { maskE2[t] = (idxD2[t] == 314) ? 1 : 0; }
}

// ---------------------------------------------------------------------------
// cc GEMM: out[m][nn<NW] = sum_f A[m][f]*W[nn][f]   (f32 out, row stride OS)
// ---------------------------------------------------------------------------
template<int NW, int OS>
__global__ __launch_bounds__(256) void cc_gemm(
    const u16* __restrict__ A, const u16* __restrict__ W,
    float* __restrict__ out, int M, int F)
{
    __shared__ u16 As[64 * 72];
    __shared__ u16 Ws[64 * 72];
    int tid = threadIdx.x;
    int mT = blockIdx.x * 64;
    int wid = tid >> 6, lane = tid & 63;
    int wr = wid >> 1, wcq = wid & 1;
    int r = lane & 15, g = lane >> 4;
    f32x4 acc[2][2];
    #pragma unroll
    for (int i = 0; i < 2; ++i)
        #pragma unroll
        for (int j = 0; j < 2; ++j)
            acc[i][j] = (f32x4){0.f, 0.f, 0.f, 0.f};

    for (int k0 = 0; k0 < F; k0 += 64) {
        #pragma unroll
        for (int h = 0; h < 2; ++h) {
            int gi = tid + h * 256;
            int m = gi >> 3, kg = gi & 7;
            uint4 va = {0u, 0u, 0u, 0u};
            int row = mT + m;
            if (row < M) va = *(const uint4*)(A + (size_t)row * F + k0 + kg * 8);
            *(uint4*)&As[m * 72 + kg * 8] = va;
            *(uint4*)&Ws[m * 72 + kg * 8] = *(const uint4*)(W + (size_t)m * F + k0 + kg * 8);
        }
        __syncthreads();
        #pragma unroll
        for (int S = 0; S < 2; ++S) {
            short8 af[2], bf[2];
            #pragma unroll
            for (int R = 0; R < 2; ++R)
                af[R] = *(const short8*)&As[(wr * 32 + R * 16 + r) * 72 + S * 32 + g * 8];
            #pragma unroll
            for (int C2 = 0; C2 < 2; ++C2)
                bf[C2] = *(const short8*)&Ws[(wcq * 32 + C2 * 16 + r) * 72 + S * 32 + g * 8];
            #pragma unroll
            for (int R = 0; R < 2; ++R)
                #pragma unroll
                for (int C2 = 0; C2 < 2; ++C2)
                    acc[R][C2] = __builtin_amdgcn_mfma_f32_16x16x32_bf16(af[R], bf[C2], acc[R][C2], 0, 0, 0);
        }
        __syncthreads();
    }
    #pragma unroll
    for (int R = 0; R < 2; ++R)
        #pragma unroll
        for (int C2 = 0; C2 < 2; ++C2)
            #pragma unroll
            for (int q = 0; q < 4; ++q) {
                int mm = mT + wr * 32 + R * 16 + g * 4 + q;
                int nn = wcq * 32 + C2 * 16 + r;
                if (mm < M && nn < NW)
                    out[(size_t)mm * OS + nn] = acc[R][C2][q];
            }
}

// ---------------------------------------------------------------------------
// GEMM with register double-buffer prefetch (bf16 out)
// ---------------------------------------------------------------------------
template<int ACT, int MASK>
__global__ __launch_bounds__(256) void lin_gemm(
    const u16* __restrict__ A, const u16* __restrict__ W,
    const float* __restrict__ bias, u16* __restrict__ Y,
    const int* __restrict__ maskT,
    int M, int K, int N, int P)
{
    __shared__ u16 As[64 * 72];
    __shared__ u16 Ws[64 * 72];
    int tid = threadIdx.x;
    int mT = blockIdx.x * 64, nT = blockIdx.y * 64;
    int wid = tid >> 6, lane = tid & 63;
    int wr = wid >> 1, wcq = wid & 1;
    int r = lane & 15, g = lane >> 4;
    int lm = tid >> 3, lkg = tid & 7;
    f32x4 acc[2][2];
    #pragma unroll
    for (int i = 0; i < 2; ++i)
        #pragma unroll
        for (int j = 0; j < 2; ++j)
            acc[i][j] = (f32x4){0.f, 0.f, 0.f, 0.f};

    uint4 ra[2], rw[2];
    #pragma unroll
    for (int h = 0; h < 2; ++h) {
        int m = lm + h * 32;
        int row = mT + m;
        uint4 z; z.x = z.y = z.z = z.w = 0u;
        ra[h] = (row < M) ? *(const uint4*)(A + (size_t)row * K + lkg * 8) : z;
        rw[h] = *(const uint4*)(W + (size_t)(nT + m) * K + lkg * 8);
    }

    for (int k0 = 0; k0 < K; k0 += 64) {
        #pragma unroll
        for (int h = 0; h < 2; ++h) {
            int m = lm + h * 32;
            *(uint4*)&As[m * 72 + lkg * 8] = ra[h];
            *(uint4*)&Ws[m * 72 + lkg * 8] = rw[h];
        }
        __syncthreads();
        bool more = (k0 + 64 < K);
        if (more) {
            int kn = k0 + 64;
            #pragma unroll
            for (int h = 0; h < 2; ++h) {
                int m = lm + h * 32;
                int row = mT + m;
                uint4 z; z.x = z.y = z.z = z.w = 0u;
                ra[h] = (row < M) ? *(const uint4*)(A + (size_t)row * K + kn + lkg * 8) : z;
                rw[h] = *(const uint4*)(W + (size_t)(nT + m) * K + kn + lkg * 8);
            }
        }
        #pragma unroll
        for (int S = 0; S < 2; ++S) {
            short8 af[2], bf[2];
            #pragma unroll
            for (int R = 0; R < 2; ++R)
                af[R] = *(const short8*)&As[(wr * 32 + R * 16 + r) * 72 + S * 32 + g * 8];
            #pragma unroll
            for (int C2 = 0; C2 < 2; ++C2)
                bf[C2] = *(const short8*)&Ws[(wcq * 32 + C2 * 16 + r) * 72 + S * 32 + g * 8];
            #pragma unroll
            for (int R = 0; R < 2; ++R)
                #pragma unroll
                for (int C2 = 0; C2 < 2; ++C2)
                    acc[R][C2] = __builtin_amdgcn_mfma_f32_16x16x32_bf16(af[R], bf[C2], acc[R][C2], 0, 0, 0);
        }
        __syncthreads();
    }

    #pragma unroll
    for (int R = 0; R < 2; ++R)
        #pragma unroll
        for (int C2 = 0; C2 < 2; ++C2)
            #pragma unroll
            for (int q = 0; q < 4; ++q) {
                int mm = mT + wr * 32 + R * 16 + g * 4 + q;
                if (mm >= M) continue;
                int nn = nT + wcq * 32 + C2 * 16 + r;
                float v = acc[R][C2][q];
                if (bias) v += bias[nn];
                if (ACT == 1) v = v > 0.f ? v : expm1f(v);
                if (MASK) { if (maskT[mm % P] != 0) v = 0.f; }
                Y[(size_t)mm * N + nn] = f2b(v);
            }
}

// ---------------------------------------------------------------------------
// encoder feast agg (XCD-swizzled)
// ---------------------------------------------------------------------------
template<int F>
__global__ __launch_bounds__(256) void feast_agg(
    const u16* __restrict__ x, const float* __restrict__ cc,
    const int* __restrict__ nbrT, const float* __restrict__ bm,
    u16* __restrict__ agg, int Pin, int P, int Mtot)
{
    constexpr int FC = F / 64;
    __shared__ float s_p[4][81];
    __shared__ int s_nb[4][KN];
    int tid = threadIdx.x, wid = tid >> 6, lane = tid & 63;
    int row = xcd_swz(blockIdx.x, gridDim.x) * 4 + wid;
    bool aw = row < Mtot;
    int b = 0, p = 0;
    if (aw) { b = row / P; p = row - b * P; }
    if (aw && lane < KN) s_nb[wid][lane] = b * Pin + nbrT[p * 12 + lane];
    __syncthreads();

    if (aw && lane < KN) {
        int j = lane;
        const float* c0 = cc + (size_t)s_nb[wid][0] * 16;
        const float* cj = cc + (size_t)s_nb[wid][j] * 16;
        float L[KN];
        #pragma unroll
        for (int i = 0; i < KN; ++i) L[i] = bm[i] + cj[i] - c0[i];
        float mx = L[0];
        #pragma unroll
        for (int i = 1; i < KN; ++i) mx = fmaxf(mx, L[i]);
        float s = 0.f;
        #pragma unroll
        for (int i = 0; i < KN; ++i) { L[i] = __expf(L[i] - mx); s += L[i]; }
        float inv = 1.f / s;
        #pragma unroll
        for (int i = 0; i < KN; ++i) s_p[wid][i * KN + j] = L[i] * inv;
    }
    __syncthreads();

    if (aw) {
        float xn[KN][FC];
        #pragma unroll
        for (int i = 0; i < KN; ++i) {
            const u16* xr = x + (size_t)s_nb[wid][i] * F;
            #pragma unroll
            for (int c = 0; c < FC; ++c) xn[i][c] = b2f(xr[lane + c * 64]);
        }
        #pragma unroll
        for (int j = 0; j < KN; ++j) {
            float a[FC];
            #pragma unroll
            for (int c = 0; c < FC; ++c) a[c] = 0.f;
            #pragma unroll
            for (int i = 0; i < KN; ++i) {
                float pv = s_p[wid][i * KN + j];
                #pragma unroll
                for (int c = 0; c < FC; ++c) a[c] += xn[i][c] * pv;
            }
            u16* orow = agg + (size_t)row * (KN * F) + j * F;
            #pragma unroll
            for (int c = 0; c < FC; ++c) orow[lane + c * 64] = f2b(a[c]);
        }
    }
}

// ---------------------------------------------------------------------------
// decoder mix (XCD-swizzled): y = elu(bc + sum_{i,j} P[i][j]*G[vert_i][j*C+c])
// ---------------------------------------------------------------------------
template<int C>
__global__ __launch_bounds__(256) void mix_feast(
    const u16* __restrict__ G, const float* __restrict__ cc,
    const int* __restrict__ nbrT, const float* __restrict__ bm,
    const float* __restrict__ bc, u16* __restrict__ y,
    int Pin, int P, int Mtot)
{
    constexpr int GS = KN * C;
    constexpr int CC_ = C / 64;
    __shared__ float s_p[4][81];
    __shared__ int s_nb[4][KN];
    int tid = threadIdx.x, wid = tid >> 6, lane = tid & 63;
    int row = xcd_swz(blockIdx.x, gridDim.x) * 4 + wid;
    bool aw = row < Mtot;
    int b = 0, p = 0;
    if (aw) { b = row / P; p = row - b * P; }
    if (aw && lane < KN) s_nb[wid][lane] = b * Pin + nbrT[p * 12 + lane];
    __syncthreads();

    if (aw && lane < KN) {
        int j = lane;
        const float* c0 = cc + (size_t)s_nb[wid][0] * 16;
        const float* cj = cc + (size_t)s_nb[wid][j] * 16;
        float L[KN];
        #pragma unroll
        for (int i = 0; i < KN; ++i) L[i] = bm[i] + cj[i] - c0[i];
        float mx = L[0];
        #pragma unroll
        for (int i = 1; i < KN; ++i) mx = fmaxf(mx, L[i]);
        float s = 0.f;
        #pragma unroll
        for (int i = 0; i < KN; ++i) { L[i] = __expf(L[i] - mx); s += L[i]; }
        float inv = 1.f / s;
        #pragma unroll
        for (int i = 0; i < KN; ++i) s_p[wid][i * KN + j] = L[i] * inv;
    }
    __syncthreads();

    if (aw) {
        float acc[CC_];
        #pragma unroll
        for (int c = 0; c < CC_; ++c) acc[c] = bc[lane + c * 64];
        #pragma unroll
        for (int i = 0; i < KN; ++i) {
            const u16* gr = G + (size_t)s_nb[wid][i] * GS;
            float pv[KN];
            #pragma unroll
            for (int j = 0; j < KN; ++j) pv[j] = s_p[wid][i * KN + j];
            #pragma unroll
            for (int j = 0; j < KN; ++j)
                #pragma unroll
                for (int c = 0; c < CC_; ++c)
                    acc[c] += pv[j] * b2f(gr[j * C + lane + c * 64]);
        }
        #pragma unroll
        for (int c = 0; c < CC_; ++c) {
            float v = acc[c];
            v = v > 0.f ? v : expm1f(v);
            if (p == P - 1) v = 0.f;
            y[(size_t)row * C + lane + c * 64] = f2b(v);
        }
    }
}

// ---------------------------------------------------------------------------
// e0 fused feast (F=3 -> C=64), XCD-swizzled
// ---------------------------------------------------------------------------
__global__ __launch_bounds__(256) void feast_e0(
    const float* __restrict__ x, const int* __restrict__ nbr,
    const int* __restrict__ sel,
    const float* __restrict__ wm, const float* __restrict__ bm,
    const float* __restrict__ wcw, const float* __restrict__ bc,
    u16* __restrict__ y,
    int Nin, int P, int Nlevel, int Mtot)
{
    constexpr int F = 3, C = 64, FS = 4, Q = 27;
    __shared__ float s_wm[KN * FS];
    __shared__ float s_wc[C * Q];
    __shared__ float s_bm[KN];
    __shared__ float s_xn[4][KN * FS];
    __shared__ float s_lg[4][81];
    __shared__ float s_pm[4][81];
    __shared__ float s_ag[4][Q];
    __shared__ int   s_idx[4][KN];

    int tid = threadIdx.x, wid = tid >> 6, lane = tid & 63;
    for (int t = tid; t < KN * F; t += 256) { int i = t / F, f = t - i * F; s_wm[i * FS + f] = wm[t]; }
    for (int t = tid; t < C * Q; t += 256) s_wc[t] = wcw[t];
    if (tid < KN) s_bm[tid] = bm[tid];

    int wg = xcd_swz(blockIdx.x, gridDim.x) * 4 + wid;
    bool aw = wg < Mtot;
    int b = 0, p = 0, n = 0;
    if (aw) {
        b = wg / P; p = wg - b * P;
        n = sel[p];
    }
    if (aw && lane < KN) s_idx[wid][lane] = nbr[n * KN + lane];
    __syncthreads();

    if (aw) {
        const float* xb = x + (size_t)b * Nin * F;
        for (int t = lane; t < KN * F; t += 64) {
            int i = t / F, f = t - i * F;
            s_xn[wid][i * FS + f] = xb[(size_t)s_idx[wid][i] * F + f];
        }
    }
    __syncthreads();

    if (aw) {
        for (int pr = lane; pr < 81; pr += 64) {
            int i = pr / KN, j = pr - i * KN;
            float acc = s_bm[i];
            for (int f = 0; f < F; ++f)
                acc += (s_xn[wid][j * FS + f] - s_xn[wid][f]) * s_wm[i * FS + f];
            s_lg[wid][pr] = acc;
        }
    }
    __syncthreads();

    if (aw && lane < KN) {
        int j = lane;
        float mx = -1e30f;
        #pragma unroll
        for (int i = 0; i < KN; ++i) mx = fmaxf(mx, s_lg[wid][i * KN + j]);
        float sm = 0.f, ev[KN];
        #pragma unroll
        for (int i = 0; i < KN; ++i) { ev[i] = __expf(s_lg[wid][i * KN + j] - mx); sm += ev[i]; }
        float inv = 1.f / sm;
        #pragma unroll
        for (int i = 0; i < KN; ++i) s_pm[wid][i * KN + j] = ev[i] * inv;
    }
    __syncthreads();

    if (aw) {
        for (int t = lane; t < Q; t += 64) {
            int f = t / KN, j = t - f * KN;
            float acc = 0.f;
            #pragma unroll
            for (int i = 0; i < KN; ++i) acc += s_xn[wid][i * FS + f] * s_pm[wid][i * KN + j];
            s_ag[wid][t] = acc;
        }
    }
    __syncthreads();

    if (aw) {
        int c = lane;
        float acc = 0.f;
        #pragma unroll
        for (int q = 0; q < Q; ++q)
            acc += s_wc[c * Q + q] * s_ag[wid][q];
        float val = acc + bc[c];
        val = val > 0.f ? val : expm1f(val);
        if (n == Nlevel - 1) val = 0.f;
        y[(size_t)wg * C + c] = f2b(val);
    }
}

// ---------------------------------------------------------------------------
// fce split-K
// ---------------------------------------------------------------------------
__global__ __launch_bounds__(256) void fce2(
    const u16* __restrict__ X3, const float* __restrict__ w,
    const float* __restrict__ bias, float* __restrict__ z)
{
    int l = blockIdx.x, ks = blockIdx.y;
    int k0 = ks * 2560;
    float acc[32];
    #pragma unroll
    for (int b = 0; b < 32; ++b) acc[b] = 0.f;
    for (int it = 0; it < 10; ++it) {
        int k = k0 + it * 256 + threadIdx.x;
        float wv = w[(size_t)l * 20480 + k];
        #pragma unroll
        for (int b = 0; b < 32; ++b) acc[b] += b2f(X3[(size_t)b * 20480 + k]) * wv;
    }
    __shared__ float sp[4][32];
    int wid = threadIdx.x >> 6, lane = threadIdx.x & 63;
    #pragma unroll
    for (int b = 0; b < 32; ++b) {
        float v = acc[b];
        for (int off = 32; off > 0; off >>= 1) v += __shfl_down(v, off, 64);
        if (lane == 0) sp[wid][b] = v;
    }
    __syncthreads();
    if (threadIdx.x < 32) {
        float sv = sp[0][threadIdx.x] + sp[1][threadIdx.x]
                 + sp[2][threadIdx.x] + sp[3][threadIdx.x];
        if (ks == 0) sv += bias[l];
        atomicAdd(&z[threadIdx.x * 256 + l], sv);
    }
}

// ---------------------------------------------------------------------------
// fp32 tiled GEMM for fcd (M=32, K=256, N=20480), bf16 output
// ---------------------------------------------------------------------------
__global__ __launch_bounds__(256) void gemm_fcd(
    const float* __restrict__ A, const float* __restrict__ W,
    const float* __restrict__ bias, u16* __restrict__ Y,
    int Mc, int Kd, int C)
{
    __shared__ float As[32][68];
    __shared__ float Ws[32][68];
    int tid = threadIdx.x;
    int mBase = blockIdx.x * 64, cBase = blockIdx.y * 64;
    int tx = tid & 15, ty = tid >> 4;
    float acc[4][4] = {};

    for (int k0 = 0; k0 < Kd; k0 += 32) {
        #pragma unroll
        for (int rr = 0; rr < 8; ++rr) {
            int t = tid + rr * 256;
            int kk = t & 31, i = t >> 5;
            int mi = mBase + i;
            As[kk][i] = (mi < Mc) ? A[(size_t)mi * Kd + k0 + kk] : 0.f;
        }
        #pragma unroll
        for (int rr = 0; rr < 8; ++rr) {
            int t = tid + rr * 256;
            int kk = t & 31, i = t >> 5;
            Ws[kk][i] = W[(size_t)(cBase + i) * Kd + k0 + kk];
        }
        __syncthreads();
        #pragma unroll
        for (int kk = 0; kk < 32; ++kk) {
            float4 av = *(const float4*)&As[kk][ty * 4];
            float4 wv = *(const float4*)&Ws[kk][tx * 4];
            float a[4] = {av.x, av.y, av.z, av.w};
            float wv2[4] = {wv.x, wv.y, wv.z, wv.w};
            #pragma unroll
            for (int u = 0; u < 4; ++u)
                #pragma unroll
                for (int v = 0; v < 4; ++v)
                    acc[u][v] += a[u] * wv2[v];
        }
        __syncthreads();
    }
    #pragma unroll
    for (int u = 0; u < 4; ++u) {
        int mi = mBase + ty * 4 + u;
        if (mi >= Mc) continue;
        #pragma unroll
        for (int v = 0; v < 4; ++v) {
            float val = acc[u][v] + bias[cBase + tx * 4 + v];
            Y[(size_t)mi * C + cBase + tx * 4 + v] = f2b(val);
        }
    }
}

// ---------------------------------------------------------------------------
// d2 mix (XCD-swizzled)
// ---------------------------------------------------------------------------
__global__ __launch_bounds__(256) void mix_d2(
    const float* __restrict__ ccgw, const int* __restrict__ nbrT,
    const float* __restrict__ bm9, const float* __restrict__ bc3,
    float* __restrict__ out)
{
    int t = xcd_swz(blockIdx.x, gridDim.x) * 256 + threadIdx.x;
    if (t >= 160768) return;
    int b = t / 5024, v = t - b * 5024;
    int nbi[KN];
    #pragma unroll
    for (int i = 0; i < KN; ++i) nbi[i] = nbrT[v * 12 + i];
    const float* base = ccgw + (size_t)b * 1257 * 40;
    float cc0[12];
    {
        const float* r0 = base + (size_t)nbi[0] * 40;
        *(float4*)&cc0[0] = *(const float4*)(r0);
        *(float4*)&cc0[4] = *(const float4*)(r0 + 4);
        *(float4*)&cc0[8] = *(const float4*)(r0 + 8);
    }
    float Pm[81];
    #pragma unroll
    for (int j = 0; j < KN; ++j) {
        float cj[12];
        const float* rj = base + (size_t)nbi[j] * 40;
        *(float4*)&cj[0] = *(const float4*)(rj);
        *(float4*)&cj[4] = *(const float4*)(rj + 4);
        *(float4*)&cj[8] = *(const float4*)(rj + 8);
        #pragma unroll
        for (int i = 0; i < KN; ++i) Pm[i * KN + j] = bm9[i] + cj[i] - cc0[i];
    }
    #pragma unroll
    for (int j = 0; j < KN; ++j) {
        float mx = Pm[j];
        #pragma unroll
        for (int i = 1; i < KN; ++i) mx = fmaxf(mx, Pm[i * KN + j]);
        float sm = 0.f;
        #pragma unroll
        for (int i = 0; i < KN; ++i) { float e = __expf(Pm[i * KN + j] - mx); Pm[i * KN + j] = e; sm += e; }
        float inv = 1.f / sm;
        #pragma unroll
        for (int i = 0; i < KN; ++i) Pm[i * KN + j] *= inv;
    }
    float a0 = bc3[0], a1 = bc3[1], a2 = bc3[2];
    #pragma unroll
    for (int i = 0; i < KN; ++i) {
        float gv[28];
        const float* gr = base + (size_t)nbi[i] * 40 + 12;
        *(float4*)&gv[0]  = *(const float4*)(gr);
        *(float4*)&gv[4]  = *(const float4*)(gr + 4);
        *(float4*)&gv[8]  = *(const float4*)(gr + 8);
        *(float4*)&gv[12] = *(const float4*)(gr + 12);
        *(float4*)&gv[16] = *(const float4*)(gr + 16);
        *(float4*)&gv[20] = *(const float4*)(gr + 20);
        *(float4*)&gv[24] = *(const float4*)(gr + 24);
        #pragma unroll
        for (int j = 0; j < KN; ++j) {
            float pv = Pm[i * KN + j];
            a0 += pv * gv[0 * KN + j];
            a1 += pv * gv[1 * KN + j];
            a2 += pv * gv[2 * KN + j];
        }
    }
    if (v == 5023) { a0 = 0.f; a1 = 0.f; a2 = 0.f; }
    out[(size_t)t * 3 + 0] = a0;
    out[(size_t)t * 3 + 1] = a1;
    out[(size_t)t * 3 + 2] = a2;
}

// ---------------------------------------------------------------------------
extern "C" void kernel_launch(void* const* d_in, const int* in_sizes, int n_in,
                              void* d_out, int out_size, void* d_ws, size_t ws_size,
                              hipStream_t stream)
{
    const float* x     = (const float*)d_in[0];
    const int*   nbr0  = (const int*)d_in[1];
    const int*   nbr1  = (const int*)d_in[2];
    const int*   nbr2  = (const int*)d_in[3];
    const float* D0    = (const float*)d_in[4];
    const float* U0    = (const float*)d_in[5];
    const float* D1    = (const float*)d_in[6];
    const float* U1    = (const float*)d_in[7];
    const float* D2    = (const float*)d_in[8];
    const float* U2    = (const float*)d_in[9];
    const float* e0_wm = (const float*)d_in[10]; const float* e0_bm = (const float*)d_in[11];
    const float* e0_wc = (const float*)d_in[12]; const float* e0_bc = (const float*)d_in[13];
    const float* e1_wm = (const float*)d_in[14]; const float* e1_bm = (const float*)d_in[15];
    const float* e1_wc = (const float*)d_in[16]; const float* e1_bc = (const float*)d_in[17];
    const float* e2_wm = (const float*)d_in[18]; const float* e2_bm = (const float*)d_in[19];
    const float* e2_wc = (const float*)d_in[20]; const float* e2_bc = (const float*)d_in[21];
    const float* fce_w = (const float*)d_in[22]; const float* fce_b = (const float*)d_in[23];
    const float* fcd_w = (const float*)d_in[24]; const float* fcd_b = (const float*)d_in[25];
    const float* d0_wm = (const float*)d_in[26]; const float* d0_bm = (const float*)d_in[27];
    const float* d0_wc = (const float*)d_in[28]; const float* d0_bc = (const float*)d_in[29];
    const float* d1_wm = (const float*)d_in[30]; const float* d1_bm = (const float*)d_in[31];
    const float* d1_wc = (const float*)d_in[32]; const float* d1_bc = (const float*)d_in[33];
    const float* d2_wm = (const float*)d_in[34]; const float* d2_bm = (const float*)d_in[35];
    const float* d2_wc = (const float*)d_in[36]; const float* d2_bc = (const float*)d_in[37];

    char* w = (char*)d_ws;
    int* idxD0 = (int*)(w);
    int* idxD1 = idxD0 + 1257;
    int* idxD2 = idxD1 + 315;
    int* idxU0 = idxD2 + 80;
    int* idxU1 = idxU0 + 5024;
    int* idxU2 = idxU1 + 1257;
    int* nbrD1  = (int*)(w + 33024);
    int* nbrD2  = (int*)(w + 48144);
    int* nbrU2  = (int*)(w + 51984);
    int* nbrU1  = (int*)(w + 67104);
    int* nbrU0  = (int*)(w + 127440);
    int* maskE1 = (int*)(w + 368640);
    int* maskE2 = (int*)(w + 369920);
    u16* wcrE1 = (u16*)(w + 370432);
    u16* wcrE2 = (u16*)(w + 517888);
    u16* wg0   = (u16*)(w + 1107712);
    u16* wg1   = (u16*)(w + 1697536);
    u16* ccwE1 = (u16*)(w + 1844992);
    u16* ccwE2 = (u16*)(w + 1853184);
    u16* ccwD0 = (u16*)(w + 1869568);
    u16* ccwD1 = (u16*)(w + 1902336);
    u16* w3    = (u16*)(w + 1918720);
    float* zbuf = (float*)(w + 1926912);

    u16*   X1   = (u16*)  (w + 2097152);
    float* CC1  = (float*)(w + 7245824);
    u16*   AGG1 = (u16*)  (w + 9820160);
    u16*   X2   = (u16*)  (w + 21432320);
    float* CC2  = (float*)(w + 24012800);
    u16*   AGG2 = (u16*)  (w + 24657920);
    u16*   X3   = (u16*)  (w + 2097152);
    u16*   X3P  = (u16*)  (w + 3407872);
    float* CCD0 = (float*)(w + 4718592);
    u16*   G0   = (u16*)  (w + 4882432);
    u16*   XD1P = (u16*)  (w + 10780672);
    float* CCD1 = (float*)(w + 13361152);
    u16*   G1   = (u16*)  (w + 14006272);
    u16*   XD2P = (u16*)  (w + 25618432);
    float* CCGW = (float*)(w + 30767104);

    // prep
    extract_idx_all<<<8248, 256, 0, stream>>>(D0, D1, D2, U0, U1, U2,
                                              idxD0, idxD1, idxD2, idxU0, idxU1, idxU2);
    cvt_weights<<<3072, 256, 0, stream>>>(e1_wc, e2_wc, d0_wc, d1_wc,
                                          e1_wm, e2_wm, d0_wm, d1_wm, d2_wm, d2_wc,
                                          wcrE1, wcrE2, wg0, wg1,
                                          ccwE1, ccwE2, ccwD0, ccwD1, w3, zbuf);
    compose_tables<<<248, 256, 0, stream>>>(nbr0, nbr1, nbr2,
                                            idxD1, idxD2, idxU0, idxU1, idxU2,
                                            nbrD1, nbrD2, nbrU2, nbrU1, nbrU0,
                                            maskE1, maskE2);

    // ---- encoder ----
    feast_e0<<<10056, 256, 0, stream>>>(x, nbr0, idxD0, e0_wm, e0_bm, e0_wc, e0_bc,
                                        X1, 5024, 1257, 5024, 40224);
    cc_gemm<16, 16><<<629, 256, 0, stream>>>(X1, ccwE1, CC1, 40224, 64);
    feast_agg<64><<<2520, 256, 0, stream>>>(X1, CC1, nbrD1, e1_bm, AGG1, 1257, 315, 10080);
    lin_gemm<1, 1><<<dim3(158, 2), 256, 0, stream>>>(AGG1, wcrE1, e1_bc, X2, maskE1,
                                                     10080, 576, 128, 315);
    cc_gemm<16, 16><<<158, 256, 0, stream>>>(X2, ccwE2, CC2, 10080, 128);
    feast_agg<128><<<640, 256, 0, stream>>>(X2, CC2, nbrD2, e2_bm, AGG2, 315, 80, 2560);
    lin_gemm<1, 1><<<dim3(40, 4), 256, 0, stream>>>(AGG2, wcrE2, e2_bc, X3, maskE2,
                                                    2560, 1152, 256, 80);

    // ---- bottleneck ----
    fce2<<<dim3(256, 8), 256, 0, stream>>>(X3, fce_w, fce_b, zbuf);
    gemm_fcd<<<dim3(1, 320), 256, 0, stream>>>(zbuf, fcd_w, fcd_b, X3P, 32, 256, 20480);

    // ---- decoder ----
    cc_gemm<16, 16><<<40, 256, 0, stream>>>(X3P, ccwD0, CCD0, 2560, 256);
    lin_gemm<0, 0><<<dim3(40, 18), 256, 0, stream>>>(X3P, wg0, nullptr, G0, nullptr,
                                                     2560, 256, 1152, 1);
    mix_feast<128><<<2520, 256, 0, stream>>>(G0, CCD0, nbrU2, d0_bm, d0_bc, XD1P,
                                             80, 315, 10080);
    cc_gemm<16, 16><<<158, 256, 0, stream>>>(XD1P, ccwD1, CCD1, 10080, 128);
    lin_gemm<0, 0><<<dim3(158, 9), 256, 0, stream>>>(XD1P, wg1, nullptr, G1, nullptr,
                                                     10080, 128, 576, 1);
    mix_feast<64><<<10056, 256, 0, stream>>>(G1, CCD1, nbrU1, d1_bm, d1_bc, XD2P,
                                             315, 1257, 40224);
    cc_gemm<40, 40><<<629, 256, 0, stream>>>(XD2P, w3, CCGW, 40224, 64);
    mix_d2<<<628, 256, 0, stream>>>(CCGW, nbrU0, d2_bm, d2_bc, (float*)d_out);
}

// Round 7
// 310.457 us; speedup vs baseline: 4.8428x; 1.1524x over previous
//
#include <hip/hip_runtime.h>
#include <cstddef>

#define KN 9
typedef unsigned short u16;
typedef unsigned int u32;
typedef __attribute__((ext_vector_type(8))) short short8;
typedef __attribute__((ext_vector_type(4))) float f32x4;

__device__ inline u16 f2b(float f) {
    union { float f; u32 u; } v; v.f = f;
    u32 r = v.u + 0x7FFFu + ((v.u >> 16) & 1u);
    return (u16)(r >> 16);
}
__device__ inline float b2f(u16 h) {
    union { u32 u; float f; } v; v.u = ((u32)h) << 16; return v.f;
}

// bijective XCD-aware block swizzle (m204)
__device__ inline int xcd_swz(int bid, int n) {
    int q = n >> 3, r = n & 7;
    int x = bid & 7, pos = bid >> 3;
    return (x < r ? x * (q + 1) : r * (q + 1) + (x - r) * q) + pos;
}

// ---------------------------------------------------------------------------
// all 6 one-hot pool matrices -> gather indices
// ---------------------------------------------------------------------------
__global__ void extract_idx_all(
    const float* __restrict__ D0, const float* __restrict__ D1, const float* __restrict__ D2,
    const float* __restrict__ U0, const float* __restrict__ U1, const float* __restrict__ U2,
    int* __restrict__ iD0, int* __restrict__ iD1, int* __restrict__ iD2,
    int* __restrict__ iU0, int* __restrict__ iU1, int* __restrict__ iU2)
{
    int blk = blockIdx.x;
    const float* L; int M; int* out; int p;
    if      (blk < 1257) { L = D0; M = 5024; out = iD0; p = blk; }
    else if (blk < 1572) { L = D1; M = 1257; out = iD1; p = blk - 1257; }
    else if (blk < 1652) { L = D2; M = 315;  out = iD2; p = blk - 1572; }
    else if (blk < 6676) { L = U0; M = 1257; out = iU0; p = blk - 1652; }
    else if (blk < 7933) { L = U1; M = 315;  out = iU1; p = blk - 6676; }
    else                 { L = U2; M = 80;   out = iU2; p = blk - 7933; }
    const float* row = L + (size_t)p * M;
    for (int m = threadIdx.x; m < M; m += 256)
        if (row[m] > 0.5f) out[p] = m;
}

// ---------------------------------------------------------------------------
// weight conversions + zbuf zeroing
// ---------------------------------------------------------------------------
__device__ inline void wcr_one(const float* __restrict__ wc, u16* __restrict__ out, int t, int F) {
    int FK = F * KN;
    int c = t / FK, rem = t - c * FK, j = rem / F, f = rem - j * F;
    out[t] = f2b(wc[(size_t)c * FK + f * KN + j]);
}
__device__ inline void wg_one(const float* __restrict__ wc, u16* __restrict__ out, int t, int F, int C) {
    int n = t / F, f = t - n * F;
    int j = n / C, c = n - j * C;
    out[t] = f2b(wc[(size_t)c * (F * KN) + f * KN + j]);
}
__device__ inline void ccw_one(const float* __restrict__ wm, u16* __restrict__ out, int t, int F) {
    int n = t / F, f = t - n * F;
    out[t] = (n < KN) ? f2b(wm[n * F + f]) : (u16)0;
}
__global__ void cvt_weights(
    const float* __restrict__ e1_wc, const float* __restrict__ e2_wc,
    const float* __restrict__ d0_wc, const float* __restrict__ d1_wc,
    const float* __restrict__ e1_wm, const float* __restrict__ e2_wm,
    const float* __restrict__ d0_wm, const float* __restrict__ d1_wm,
    const float* __restrict__ d2_wm, const float* __restrict__ d2_wc,
    u16* __restrict__ wcrE1, u16* __restrict__ wcrE2,
    u16* __restrict__ wg0, u16* __restrict__ wg1,
    u16* __restrict__ ccwE1, u16* __restrict__ ccwE2,
    u16* __restrict__ ccwD0, u16* __restrict__ ccwD1,
    u16* __restrict__ w3, float* __restrict__ zbuf)
{
    int t = blockIdx.x * 256 + threadIdx.x;
    if (t < 73728)  { wcr_one(e1_wc, wcrE1, t, 64);       return; } t -= 73728;
    if (t < 294912) { wcr_one(e2_wc, wcrE2, t, 128);      return; } t -= 294912;
    if (t < 294912) { wg_one(d0_wc, wg0, t, 256, 128);    return; } t -= 294912;
    if (t < 73728)  { wg_one(d1_wc, wg1, t, 128, 64);     return; } t -= 73728;
    if (t < 4096)   { ccw_one(e1_wm, ccwE1, t, 64);       return; } t -= 4096;
    if (t < 8192)   { ccw_one(e2_wm, ccwE2, t, 128);      return; } t -= 8192;
    if (t < 16384)  { ccw_one(d0_wm, ccwD0, t, 256);      return; } t -= 16384;
    if (t < 8192)   { ccw_one(d1_wm, ccwD1, t, 128);      return; } t -= 8192;
    if (t < 4096) {
        int n = t >> 6, k = t & 63;
        float v = 0.f;
        if (n < KN) v = d2_wm[n * 64 + k];
        else if (n >= 12 && n < 39) {
            int cj = n - 12, c = cj / KN, j = cj - c * KN;
            v = d2_wc[(size_t)c * 576 + k * KN + j];
        }
        w3[t] = f2b(v);
        return;
    } t -= 4096;
    if (t < 8192) zbuf[t] = 0.f;
}

// ---------------------------------------------------------------------------
// composed neighbor tables (stride 12) + encoder pad masks
// ---------------------------------------------------------------------------
__global__ void compose_tables(
    const int* __restrict__ nbr0, const int* __restrict__ nbr1, const int* __restrict__ nbr2,
    const int* __restrict__ idxD1, const int* __restrict__ idxD2,
    const int* __restrict__ idxU0, const int* __restrict__ idxU1, const int* __restrict__ idxU2,
    int* __restrict__ nbrD1, int* __restrict__ nbrD2,
    int* __restrict__ nbrU2, int* __restrict__ nbrU1, int* __restrict__ nbrU0,
    int* __restrict__ maskE1, int* __restrict__ maskE2)
{
    int t = blockIdx.x * 256 + threadIdx.x;
    if (t < 2835)  { int p = t / 9, j = t - p * 9; nbrD1[p * 12 + j] = nbr1[idxD1[p] * 9 + j]; return; } t -= 2835;
    if (t < 720)   { int p = t / 9, j = t - p * 9; nbrD2[p * 12 + j] = nbr2[idxD2[p] * 9 + j]; return; } t -= 720;
    if (t < 2835)  { int p = t / 9, j = t - p * 9; nbrU2[p * 12 + j] = idxU2[nbr2[p * 9 + j]]; return; } t -= 2835;
    if (t < 11313) { int p = t / 9, j = t - p * 9; nbrU1[p * 12 + j] = idxU1[nbr1[p * 9 + j]]; return; } t -= 11313;
    if (t < 45216) { int p = t / 9, j = t - p * 9; nbrU0[p * 12 + j] = idxU0[nbr0[p * 9 + j]]; return; } t -= 45216;
    if (t < 315)   { maskE1[t] = (idxD1[t] == 1256) ? 1 : 0; return; } t -= 315;
    if (t < 80)    { maskE2[t] = (idxD2[t] == 314) ? 1 : 0; }
}

// ---------------------------------------------------------------------------
// cc GEMM: out[m][nn<NW] = sum_f A[m][f]*W[nn][f]   (f32 out, row stride OS)
// ---------------------------------------------------------------------------
template<int NW, int OS>
__global__ __launch_bounds__(256) void cc_gemm(
    const u16* __restrict__ A, const u16* __restrict__ W,
    float* __restrict__ out, int M, int F)
{
    __shared__ u16 As[64 * 72];
    __shared__ u16 Ws[64 * 72];
    int tid = threadIdx.x;
    int mT = blockIdx.x * 64;
    int wid = tid >> 6, lane = tid & 63;
    int wr = wid >> 1, wcq = wid & 1;
    int r = lane & 15, g = lane >> 4;
    f32x4 acc[2][2];
    #pragma unroll
    for (int i = 0; i < 2; ++i)
        #pragma unroll
        for (int j = 0; j < 2; ++j)
            acc[i][j] = (f32x4){0.f, 0.f, 0.f, 0.f};

    for (int k0 = 0; k0 < F; k0 += 64) {
        #pragma unroll
        for (int h = 0; h < 2; ++h) {
            int gi = tid + h * 256;
            int m = gi >> 3, kg = gi & 7;
            uint4 va = {0u, 0u, 0u, 0u};
            int row = mT + m;
            if (row < M) va = *(const uint4*)(A + (size_t)row * F + k0 + kg * 8);
            *(uint4*)&As[m * 72 + kg * 8] = va;
            *(uint4*)&Ws[m * 72 + kg * 8] = *(const uint4*)(W + (size_t)m * F + k0 + kg * 8);
        }
        __syncthreads();
        #pragma unroll
        for (int S = 0; S < 2; ++S) {
            short8 af[2], bf[2];
            #pragma unroll
            for (int R = 0; R < 2; ++R)
                af[R] = *(const short8*)&As[(wr * 32 + R * 16 + r) * 72 + S * 32 + g * 8];
            #pragma unroll
            for (int C2 = 0; C2 < 2; ++C2)
                bf[C2] = *(const short8*)&Ws[(wcq * 32 + C2 * 16 + r) * 72 + S * 32 + g * 8];
            #pragma unroll
            for (int R = 0; R < 2; ++R)
                #pragma unroll
                for (int C2 = 0; C2 < 2; ++C2)
                    acc[R][C2] = __builtin_amdgcn_mfma_f32_16x16x32_bf16(af[R], bf[C2], acc[R][C2], 0, 0, 0);
        }
        __syncthreads();
    }
    #pragma unroll
    for (int R = 0; R < 2; ++R)
        #pragma unroll
        for (int C2 = 0; C2 < 2; ++C2)
            #pragma unroll
            for (int q = 0; q < 4; ++q) {
                int mm = mT + wr * 32 + R * 16 + g * 4 + q;
                int nn = wcq * 32 + C2 * 16 + r;
                if (mm < M && nn < NW)
                    out[(size_t)mm * OS + nn] = acc[R][C2][q];
            }
}

// ---------------------------------------------------------------------------
// GEMM with register double-buffer prefetch (bf16 in/out)
// ---------------------------------------------------------------------------
template<int ACT, int MASK>
__global__ __launch_bounds__(256) void lin_gemm(
    const u16* __restrict__ A, const u16* __restrict__ W,
    const float* __restrict__ bias, u16* __restrict__ Y,
    const int* __restrict__ maskT,
    int M, int K, int N, int P)
{
    __shared__ u16 As[64 * 72];
    __shared__ u16 Ws[64 * 72];
    int tid = threadIdx.x;
    int mT = blockIdx.x * 64, nT = blockIdx.y * 64;
    int wid = tid >> 6, lane = tid & 63;
    int wr = wid >> 1, wcq = wid & 1;
    int r = lane & 15, g = lane >> 4;
    int lm = tid >> 3, lkg = tid & 7;
    f32x4 acc[2][2];
    #pragma unroll
    for (int i = 0; i < 2; ++i)
        #pragma unroll
        for (int j = 0; j < 2; ++j)
            acc[i][j] = (f32x4){0.f, 0.f, 0.f, 0.f};

    uint4 ra[2], rw[2];
    #pragma unroll
    for (int h = 0; h < 2; ++h) {
        int m = lm + h * 32;
        int row = mT + m;
        uint4 z; z.x = z.y = z.z = z.w = 0u;
        ra[h] = (row < M) ? *(const uint4*)(A + (size_t)row * K + lkg * 8) : z;
        rw[h] = *(const uint4*)(W + (size_t)(nT + m) * K + lkg * 8);
    }

    for (int k0 = 0; k0 < K; k0 += 64) {
        #pragma unroll
        for (int h = 0; h < 2; ++h) {
            int m = lm + h * 32;
            *(uint4*)&As[m * 72 + lkg * 8] = ra[h];
            *(uint4*)&Ws[m * 72 + lkg * 8] = rw[h];
        }
        __syncthreads();
        bool more = (k0 + 64 < K);
        if (more) {
            int kn = k0 + 64;
            #pragma unroll
            for (int h = 0; h < 2; ++h) {
                int m = lm + h * 32;
                int row = mT + m;
                uint4 z; z.x = z.y = z.z = z.w = 0u;
                ra[h] = (row < M) ? *(const uint4*)(A + (size_t)row * K + kn + lkg * 8) : z;
                rw[h] = *(const uint4*)(W + (size_t)(nT + m) * K + kn + lkg * 8);
            }
        }
        #pragma unroll
        for (int S = 0; S < 2; ++S) {
            short8 af[2], bf[2];
            #pragma unroll
            for (int R = 0; R < 2; ++R)
                af[R] = *(const short8*)&As[(wr * 32 + R * 16 + r) * 72 + S * 32 + g * 8];
            #pragma unroll
            for (int C2 = 0; C2 < 2; ++C2)
                bf[C2] = *(const short8*)&Ws[(wcq * 32 + C2 * 16 + r) * 72 + S * 32 + g * 8];
            #pragma unroll
            for (int R = 0; R < 2; ++R)
                #pragma unroll
                for (int C2 = 0; C2 < 2; ++C2)
                    acc[R][C2] = __builtin_amdgcn_mfma_f32_16x16x32_bf16(af[R], bf[C2], acc[R][C2], 0, 0, 0);
        }
        __syncthreads();
    }

    #pragma unroll
    for (int R = 0; R < 2; ++R)
        #pragma unroll
        for (int C2 = 0; C2 < 2; ++C2)
            #pragma unroll
            for (int q = 0; q < 4; ++q) {
                int mm = mT + wr * 32 + R * 16 + g * 4 + q;
                if (mm >= M) continue;
                int nn = nT + wcq * 32 + C2 * 16 + r;
                float v = acc[R][C2][q];
                if (bias) v += bias[nn];
                if (ACT == 1) v = v > 0.f ? v : expm1f(v);
                if (MASK) { if (maskT[mm % P] != 0) v = 0.f; }
                Y[(size_t)mm * N + nn] = f2b(v);
            }
}

// ---------------------------------------------------------------------------
// fce via split-K MFMA, f32 weights converted in-register on load.
//   A = X3 bf16 [32][20480]; Wf = fce_w f32 [256][20480];
//   z[32][256] f32 pre-zeroed, atomicAdd partials (+bias at blockIdx.y==0).
// grid (4 n-tiles, 80 k-slices of 256)
// ---------------------------------------------------------------------------
__global__ __launch_bounds__(256) void fce_mfma(
    const u16* __restrict__ A, const float* __restrict__ Wf,
    const float* __restrict__ bias, float* __restrict__ z)
{
    __shared__ u16 As[32 * 72];
    __shared__ u16 Ws[64 * 72];
    int tid = threadIdx.x;
    int nT = blockIdx.x * 64;
    int kbase = blockIdx.y * 256;
    int wv = tid >> 6, lane = tid & 63;
    int r = lane & 15, g = lane >> 4;
    int m = tid >> 3, kg = tid & 7;
    f32x4 acc[2];
    acc[0] = (f32x4){0.f, 0.f, 0.f, 0.f};
    acc[1] = (f32x4){0.f, 0.f, 0.f, 0.f};

    for (int ks = 0; ks < 4; ++ks) {
        int k0 = kbase + ks * 64;
        *(uint4*)&As[m * 72 + kg * 8] = *(const uint4*)(A + (size_t)m * 20480 + k0 + kg * 8);
        #pragma unroll
        for (int h = 0; h < 2; ++h) {
            int row = m + h * 32;
            const float* wr2 = Wf + (size_t)(nT + row) * 20480 + k0 + kg * 8;
            float4 w0 = *(const float4*)(wr2);
            float4 w1 = *(const float4*)(wr2 + 4);
            u16 o[8] = { f2b(w0.x), f2b(w0.y), f2b(w0.z), f2b(w0.w),
                         f2b(w1.x), f2b(w1.y), f2b(w1.z), f2b(w1.w) };
            *(uint4*)&Ws[row * 72 + kg * 8] = *(const uint4*)o;
        }
        __syncthreads();
        #pragma unroll
        for (int S = 0; S < 2; ++S) {
            short8 bfr = *(const short8*)&Ws[(wv * 16 + r) * 72 + S * 32 + g * 8];
            #pragma unroll
            for (int R = 0; R < 2; ++R) {
                short8 af = *(const short8*)&As[(R * 16 + r) * 72 + S * 32 + g * 8];
                acc[R] = __builtin_amdgcn_mfma_f32_16x16x32_bf16(af, bfr, acc[R], 0, 0, 0);
            }
        }
        __syncthreads();
    }
    #pragma unroll
    for (int R = 0; R < 2; ++R)
        #pragma unroll
        for (int q = 0; q < 4; ++q) {
            int mm = R * 16 + g * 4 + q;          // 0..31 == full M
            int nn = nT + wv * 16 + r;
            float v = acc[R][q];
            if (blockIdx.y == 0) v += bias[nn];
            atomicAdd(&z[mm * 256 + nn], v);
        }
}

// ---------------------------------------------------------------------------
// fcd via MFMA, both operands f32 converted in-register on load.
//   Af = zbuf f32 [32][256]; Wf = fcd_w f32 [20480][256];
//   Y = X3P bf16 [32][20480]. grid (320).
// ---------------------------------------------------------------------------
__global__ __launch_bounds__(256) void fcd_mfma(
    const float* __restrict__ Af, const float* __restrict__ Wf,
    const float* __restrict__ bias, u16* __restrict__ Y)
{
    __shared__ u16 As[64 * 72];
    __shared__ u16 Ws[64 * 72];
    int tid = threadIdx.x;
    int nT = blockIdx.x * 64;
    int wid = tid >> 6, lane = tid & 63;
    int wr = wid >> 1, wcq = wid & 1;
    int r = lane & 15, g = lane >> 4;
    int m = tid >> 3, kg = tid & 7;
    f32x4 acc[2][2];
    #pragma unroll
    for (int i = 0; i < 2; ++i)
        #pragma unroll
        for (int j = 0; j < 2; ++j)
            acc[i][j] = (f32x4){0.f, 0.f, 0.f, 0.f};

    for (int k0 = 0; k0 < 256; k0 += 64) {
        {   // A rows 0..31 real, 32..63 zero
            const float* ar = Af + (size_t)m * 256 + k0 + kg * 8;
            float4 a0 = *(const float4*)(ar);
            float4 a1 = *(const float4*)(ar + 4);
            u16 o[8] = { f2b(a0.x), f2b(a0.y), f2b(a0.z), f2b(a0.w),
                         f2b(a1.x), f2b(a1.y), f2b(a1.z), f2b(a1.w) };
            *(uint4*)&As[m * 72 + kg * 8] = *(const uint4*)o;
            uint4 z4; z4.x = z4.y = z4.z = z4.w = 0u;
            *(uint4*)&As[(m + 32) * 72 + kg * 8] = z4;
        }
        #pragma unroll
        for (int h = 0; h < 2; ++h) {
            int row = m + h * 32;
            const float* wr2 = Wf + (size_t)(nT + row) * 256 + k0 + kg * 8;
            float4 w0 = *(const float4*)(wr2);
            float4 w1 = *(const float4*)(wr2 + 4);
            u16 o[8] = { f2b(w0.x), f2b(w0.y), f2b(w0.z), f2b(w0.w),
                         f2b(w1.x), f2b(w1.y), f2b(w1.z), f2b(w1.w) };
            *(uint4*)&Ws[row * 72 + kg * 8] = *(const uint4*)o;
        }
        __syncthreads();
        #pragma unroll
        for (int S = 0; S < 2; ++S) {
            short8 af[2], bf[2];
            #pragma unroll
            for (int R = 0; R < 2; ++R)
                af[R] = *(const short8*)&As[(wr * 32 + R * 16 + r) * 72 + S * 32 + g * 8];
            #pragma unroll
            for (int C2 = 0; C2 < 2; ++C2)
                bf[C2] = *(const short8*)&Ws[(wcq * 32 + C2 * 16 + r) * 72 + S * 32 + g * 8];
            #pragma unroll
            for (int R = 0; R < 2; ++R)
                #pragma unroll
                for (int C2 = 0; C2 < 2; ++C2)
                    acc[R][C2] = __builtin_amdgcn_mfma_f32_16x16x32_bf16(af[R], bf[C2], acc[R][C2], 0, 0, 0);
        }
        __syncthreads();
    }
    #pragma unroll
    for (int R = 0; R < 2; ++R)
        #pragma unroll
        for (int C2 = 0; C2 < 2; ++C2)
            #pragma unroll
            for (int q = 0; q < 4; ++q) {
                int mm = wr * 32 + R * 16 + g * 4 + q;
                if (mm >= 32) continue;
                int nn = nT + wcq * 32 + C2 * 16 + r;
                float v = acc[R][C2][q] + bias[nn];
                Y[(size_t)mm * 20480 + nn] = f2b(v);
            }
}

// ---------------------------------------------------------------------------
// encoder feast agg (XCD-swizzled)
// ---------------------------------------------------------------------------
template<int F>
__global__ __launch_bounds__(256) void feast_agg(
    const u16* __restrict__ x, const float* __restrict__ cc,
    const int* __restrict__ nbrT, const float* __restrict__ bm,
    u16* __restrict__ agg, int Pin, int P, int Mtot)
{
    constexpr int FC = F / 64;
    __shared__ float s_p[4][81];
    __shared__ int s_nb[4][KN];
    int tid = threadIdx.x, wid = tid >> 6, lane = tid & 63;
    int row = xcd_swz(blockIdx.x, gridDim.x) * 4 + wid;
    bool aw = row < Mtot;
    int b = 0, p = 0;
    if (aw) { b = row / P; p = row - b * P; }
    if (aw && lane < KN) s_nb[wid][lane] = b * Pin + nbrT[p * 12 + lane];
    __syncthreads();

    if (aw && lane < KN) {
        int j = lane;
        const float* c0 = cc + (size_t)s_nb[wid][0] * 16;
        const float* cj = cc + (size_t)s_nb[wid][j] * 16;
        float L[KN];
        #pragma unroll
        for (int i = 0; i < KN; ++i) L[i] = bm[i] + cj[i] - c0[i];
        float mx = L[0];
        #pragma unroll
        for (int i = 1; i < KN; ++i) mx = fmaxf(mx, L[i]);
        float s = 0.f;
        #pragma unroll
        for (int i = 0; i < KN; ++i) { L[i] = __expf(L[i] - mx); s += L[i]; }
        float inv = 1.f / s;
        #pragma unroll
        for (int i = 0; i < KN; ++i) s_p[wid][i * KN + j] = L[i] * inv;
    }
    __syncthreads();

    if (aw) {
        float xn[KN][FC];
        #pragma unroll
        for (int i = 0; i < KN; ++i) {
            const u16* xr = x + (size_t)s_nb[wid][i] * F;
            #pragma unroll
            for (int c = 0; c < FC; ++c) xn[i][c] = b2f(xr[lane + c * 64]);
        }
        #pragma unroll
        for (int j = 0; j < KN; ++j) {
            float a[FC];
            #pragma unroll
            for (int c = 0; c < FC; ++c) a[c] = 0.f;
            #pragma unroll
            for (int i = 0; i < KN; ++i) {
                float pv = s_p[wid][i * KN + j];
                #pragma unroll
                for (int c = 0; c < FC; ++c) a[c] += xn[i][c] * pv;
            }
            u16* orow = agg + (size_t)row * (KN * F) + j * F;
            #pragma unroll
            for (int c = 0; c < FC; ++c) orow[lane + c * 64] = f2b(a[c]);
        }
    }
}

// ---------------------------------------------------------------------------
// decoder mix (XCD-swizzled)
// ---------------------------------------------------------------------------
template<int C>
__global__ __launch_bounds__(256) void mix_feast(
    const u16* __restrict__ G, const float* __restrict__ cc,
    const int* __restrict__ nbrT, const float* __restrict__ bm,
    const float* __restrict__ bc, u16* __restrict__ y,
    int Pin, int P, int Mtot)
{
    constexpr int GS = KN * C;
    constexpr int CC_ = C / 64;
    __shared__ float s_p[4][81];
    __shared__ int s_nb[4][KN];
    int tid = threadIdx.x, wid = tid >> 6, lane = tid & 63;
    int row = xcd_swz(blockIdx.x, gridDim.x) * 4 + wid;
    bool aw = row < Mtot;
    int b = 0, p = 0;
    if (aw) { b = row / P; p = row - b * P; }
    if (aw && lane < KN) s_nb[wid][lane] = b * Pin + nbrT[p * 12 + lane];
    __syncthreads();

    if (aw && lane < KN) {
        int j = lane;
        const float* c0 = cc + (size_t)s_nb[wid][0] * 16;
        const float* cj = cc + (size_t)s_nb[wid][j] * 16;
        float L[KN];
        #pragma unroll
        for (int i = 0; i < KN; ++i) L[i] = bm[i] + cj[i] - c0[i];
        float mx = L[0];
        #pragma unroll
        for (int i = 1; i < KN; ++i) mx = fmaxf(mx, L[i]);
        float s = 0.f;
        #pragma unroll
        for (int i = 0; i < KN; ++i) { L[i] = __expf(L[i] - mx); s += L[i]; }
        float inv = 1.f / s;
        #pragma unroll
        for (int i = 0; i < KN; ++i) s_p[wid][i * KN + j] = L[i] * inv;
    }
    __syncthreads();

    if (aw) {
        float acc[CC_];
        #pragma unroll
        for (int c = 0; c < CC_; ++c) acc[c] = bc[lane + c * 64];
        #pragma unroll
        for (int i = 0; i < KN; ++i) {
            const u16* gr = G + (size_t)s_nb[wid][i] * GS;
            float pv[KN];
            #pragma unroll
            for (int j = 0; j < KN; ++j) pv[j] = s_p[wid][i * KN + j];
            #pragma unroll
            for (int j = 0; j < KN; ++j)
                #pragma unroll
                for (int c = 0; c < CC_; ++c)
                    acc[c] += pv[j] * b2f(gr[j * C + lane + c * 64]);
        }
        #pragma unroll
        for (int c = 0; c < CC_; ++c) {
            float v = acc[c];
            v = v > 0.f ? v : expm1f(v);
            if (p == P - 1) v = 0.f;
            y[(size_t)row * C + lane + c * 64] = f2b(v);
        }
    }
}

// ---------------------------------------------------------------------------
// e0 fused feast (F=3 -> C=64), XCD-swizzled
// ---------------------------------------------------------------------------
__global__ __launch_bounds__(256) void feast_e0(
    const float* __restrict__ x, const int* __restrict__ nbr,
    const int* __restrict__ sel,
    const float* __restrict__ wm, const float* __restrict__ bm,
    const float* __restrict__ wcw, const float* __restrict__ bc,
    u16* __restrict__ y,
    int Nin, int P, int Nlevel, int Mtot)
{
    constexpr int F = 3, C = 64, FS = 4, Q = 27;
    __shared__ float s_wm[KN * FS];
    __shared__ float s_wc[C * Q];
    __shared__ float s_bm[KN];
    __shared__ float s_xn[4][KN * FS];
    __shared__ float s_lg[4][81];
    __shared__ float s_pm[4][81];
    __shared__ float s_ag[4][Q];
    __shared__ int   s_idx[4][KN];

    int tid = threadIdx.x, wid = tid >> 6, lane = tid & 63;
    for (int t = tid; t < KN * F; t += 256) { int i = t / F, f = t - i * F; s_wm[i * FS + f] = wm[t]; }
    for (int t = tid; t < C * Q; t += 256) s_wc[t] = wcw[t];
    if (tid < KN) s_bm[tid] = bm[tid];

    int wg = xcd_swz(blockIdx.x, gridDim.x) * 4 + wid;
    bool aw = wg < Mtot;
    int b = 0, p = 0, n = 0;
    if (aw) {
        b = wg / P; p = wg - b * P;
        n = sel[p];
    }
    if (aw && lane < KN) s_idx[wid][lane] = nbr[n * KN + lane];
    __syncthreads();

    if (aw) {
        const float* xb = x + (size_t)b * Nin * F;
        for (int t = lane; t < KN * F; t += 64) {
            int i = t / F, f = t - i * F;
            s_xn[wid][i * FS + f] = xb[(size_t)s_idx[wid][i] * F + f];
        }
    }
    __syncthreads();

    if (aw) {
        for (int pr = lane; pr < 81; pr += 64) {
            int i = pr / KN, j = pr - i * KN;
            float acc = s_bm[i];
            for (int f = 0; f < F; ++f)
                acc += (s_xn[wid][j * FS + f] - s_xn[wid][f]) * s_wm[i * FS + f];
            s_lg[wid][pr] = acc;
        }
    }
    __syncthreads();

    if (aw && lane < KN) {
        int j = lane;
        float mx = -1e30f;
        #pragma unroll
        for (int i = 0; i < KN; ++i) mx = fmaxf(mx, s_lg[wid][i * KN + j]);
        float sm = 0.f, ev[KN];
        #pragma unroll
        for (int i = 0; i < KN; ++i) { ev[i] = __expf(s_lg[wid][i * KN + j] - mx); sm += ev[i]; }
        float inv = 1.f / sm;
        #pragma unroll
        for (int i = 0; i < KN; ++i) s_pm[wid][i * KN + j] = ev[i] * inv;
    }
    __syncthreads();

    if (aw) {
        for (int t = lane; t < Q; t += 64) {
            int f = t / KN, j = t - f * KN;
            float acc = 0.f;
            #pragma unroll
            for (int i = 0; i < KN; ++i) acc += s_xn[wid][i * FS + f] * s_pm[wid][i * KN + j];
            s_ag[wid][t] = acc;
        }
    }
    __syncthreads();

    if (aw) {
        int c = lane;
        float acc = 0.f;
        #pragma unroll
        for (int q = 0; q < Q; ++q)
            acc += s_wc[c * Q + q] * s_ag[wid][q];
        float val = acc + bc[c];
        val = val > 0.f ? val : expm1f(val);
        if (n == Nlevel - 1) val = 0.f;
        y[(size_t)wg * C + c] = f2b(val);
    }
}

// ---------------------------------------------------------------------------
// d2 mix (XCD-swizzled)
// ---------------------------------------------------------------------------
__global__ __launch_bounds__(256) void mix_d2(
    const float* __restrict__ ccgw, const int* __restrict__ nbrT,
    const float* __restrict__ bm9, const float* __restrict__ bc3,
    float* __restrict__ out)
{
    int t = xcd_swz(blockIdx.x, gridDim.x) * 256 + threadIdx.x;
    if (t >= 160768) return;
    int b = t / 5024, v = t - b * 5024;
    int nbi[KN];
    #pragma unroll
    for (int i = 0; i < KN; ++i) nbi[i] = nbrT[v * 12 + i];
    const float* base = ccgw + (size_t)b * 1257 * 40;
    float cc0[12];
    {
        const float* r0 = base + (size_t)nbi[0] * 40;
        *(float4*)&cc0[0] = *(const float4*)(r0);
        *(float4*)&cc0[4] = *(const float4*)(r0 + 4);
        *(float4*)&cc0[8] = *(const float4*)(r0 + 8);
    }
    float Pm[81];
    #pragma unroll
    for (int j = 0; j < KN; ++j) {
        float cj[12];
        const float* rj = base + (size_t)nbi[j] * 40;
        *(float4*)&cj[0] = *(const float4*)(rj);
        *(float4*)&cj[4] = *(const float4*)(rj + 4);
        *(float4*)&cj[8] = *(const float4*)(rj + 8);
        #pragma unroll
        for (int i = 0; i < KN; ++i) Pm[i * KN + j] = bm9[i] + cj[i] - cc0[i];
    }
    #pragma unroll
    for (int j = 0; j < KN; ++j) {
        float mx = Pm[j];
        #pragma unroll
        for (int i = 1; i < KN; ++i) mx = fmaxf(mx, Pm[i * KN + j]);
        float sm = 0.f;
        #pragma unroll
        for (int i = 0; i < KN; ++i) { float e = __expf(Pm[i * KN + j] - mx); Pm[i * KN + j] = e; sm += e; }
        float inv = 1.f / sm;
        #pragma unroll
        for (int i = 0; i < KN; ++i) Pm[i * KN + j] *= inv;
    }
    float a0 = bc3[0], a1 = bc3[1], a2 = bc3[2];
    #pragma unroll
    for (int i = 0; i < KN; ++i) {
        float gv[28];
        const float* gr = base + (size_t)nbi[i] * 40 + 12;
        *(float4*)&gv[0]  = *(const float4*)(gr);
        *(float4*)&gv[4]  = *(const float4*)(gr + 4);
        *(float4*)&gv[8]  = *(const float4*)(gr + 8);
        *(float4*)&gv[12] = *(const float4*)(gr + 12);
        *(float4*)&gv[16] = *(const float4*)(gr + 16);
        *(float4*)&gv[20] = *(const float4*)(gr + 20);
        *(float4*)&gv[24] = *(const float4*)(gr + 24);
        #pragma unroll
        for (int j = 0; j < KN; ++j) {
            float pv = Pm[i * KN + j];
            a0 += pv * gv[0 * KN + j];
            a1 += pv * gv[1 * KN + j];
            a2 += pv * gv[2 * KN + j];
        }
    }
    if (v == 5023) { a0 = 0.f; a1 = 0.f; a2 = 0.f; }
    out[(size_t)t * 3 + 0] = a0;
    out[(size_t)t * 3 + 1] = a1;
    out[(size_t)t * 3 + 2] = a2;
}

// ---------------------------------------------------------------------------
extern "C" void kernel_launch(void* const* d_in, const int* in_sizes, int n_in,
                              void* d_out, int out_size, void* d_ws, size_t ws_size,
                              hipStream_t stream)
{
    const float* x     = (const float*)d_in[0];
    const int*   nbr0  = (const int*)d_in[1];
    const int*   nbr1  = (const int*)d_in[2];
    const int*   nbr2  = (const int*)d_in[3];
    const float* D0    = (const float*)d_in[4];
    const float* U0    = (const float*)d_in[5];
    const float* D1    = (const float*)d_in[6];
    const float* U1    = (const float*)d_in[7];
    const float* D2    = (const float*)d_in[8];
    const float* U2    = (const float*)d_in[9];
    const float* e0_wm = (const float*)d_in[10]; const float* e0_bm = (const float*)d_in[11];
    const float* e0_wc = (const float*)d_in[12]; const float* e0_bc = (const float*)d_in[13];
    const float* e1_wm = (const float*)d_in[14]; const float* e1_bm = (const float*)d_in[15];
    const float* e1_wc = (const float*)d_in[16]; const float* e1_bc = (const float*)d_in[17];
    const float* e2_wm = (const float*)d_in[18]; const float* e2_bm = (const float*)d_in[19];
    const float* e2_wc = (const float*)d_in[20]; const float* e2_bc = (const float*)d_in[21];
    const float* fce_w = (const float*)d_in[22]; const float* fce_b = (const float*)d_in[23];
    const float* fcd_w = (const float*)d_in[24]; const float* fcd_b = (const float*)d_in[25];
    const float* d0_wm = (const float*)d_in[26]; const float* d0_bm = (const float*)d_in[27];
    const float* d0_wc = (const float*)d_in[28]; const float* d0_bc = (const float*)d_in[29];
    const float* d1_wm = (const float*)d_in[30]; const float* d1_bm = (const float*)d_in[31];
    const float* d1_wc = (const float*)d_in[32]; const float* d1_bc = (const float*)d_in[33];
    const float* d2_wm = (const float*)d_in[34]; const float* d2_bm = (const float*)d_in[35];
    const float* d2_wc = (const float*)d_in[36]; const float* d2_bc = (const float*)d_in[37];

    char* w = (char*)d_ws;
    int* idxD0 = (int*)(w);
    int* idxD1 = idxD0 + 1257;
    int* idxD2 = idxD1 + 315;
    int* idxU0 = idxD2 + 80;
    int* idxU1 = idxU0 + 5024;
    int* idxU2 = idxU1 + 1257;
    int* nbrD1  = (int*)(w + 33024);
    int* nbrD2  = (int*)(w + 48144);
    int* nbrU2  = (int*)(w + 51984);
    int* nbrU1  = (int*)(w + 67104);
    int* nbrU0  = (int*)(w + 127440);
    int* maskE1 = (int*)(w + 368640);
    int* maskE2 = (int*)(w + 369920);
    u16* wcrE1 = (u16*)(w + 370432);
    u16* wcrE2 = (u16*)(w + 517888);
    u16* wg0   = (u16*)(w + 1107712);
    u16* wg1   = (u16*)(w + 1697536);
    u16* ccwE1 = (u16*)(w + 1844992);
    u16* ccwE2 = (u16*)(w + 1853184);
    u16* ccwD0 = (u16*)(w + 1869568);
    u16* ccwD1 = (u16*)(w + 1902336);
    u16* w3    = (u16*)(w + 1918720);
    float* zbuf = (float*)(w + 1926912);

    u16*   X1   = (u16*)  (w + 2097152);
    float* CC1  = (float*)(w + 7245824);
    u16*   AGG1 = (u16*)  (w + 9820160);
    u16*   X2   = (u16*)  (w + 21432320);
    float* CC2  = (float*)(w + 24012800);
    u16*   AGG2 = (u16*)  (w + 24657920);
    u16*   X3   = (u16*)  (w + 2097152);
    u16*   X3P  = (u16*)  (w + 3407872);
    float* CCD0 = (float*)(w + 4718592);
    u16*   G0   = (u16*)  (w + 4882432);
    u16*   XD1P = (u16*)  (w + 10780672);
    float* CCD1 = (float*)(w + 13361152);
    u16*   G1   = (u16*)  (w + 14006272);
    u16*   XD2P = (u16*)  (w + 25618432);
    float* CCGW = (float*)(w + 30767104);

    // prep
    extract_idx_all<<<8248, 256, 0, stream>>>(D0, D1, D2, U0, U1, U2,
                                              idxD0, idxD1, idxD2, idxU0, idxU1, idxU2);
    cvt_weights<<<3072, 256, 0, stream>>>(e1_wc, e2_wc, d0_wc, d1_wc,
                                          e1_wm, e2_wm, d0_wm, d1_wm, d2_wm, d2_wc,
                                          wcrE1, wcrE2, wg0, wg1,
                                          ccwE1, ccwE2, ccwD0, ccwD1, w3, zbuf);
    compose_tables<<<248, 256, 0, stream>>>(nbr0, nbr1, nbr2,
                                            idxD1, idxD2, idxU0, idxU1, idxU2,
                                            nbrD1, nbrD2, nbrU2, nbrU1, nbrU0,
                                            maskE1, maskE2);

    // ---- encoder ----
    feast_e0<<<10056, 256, 0, stream>>>(x, nbr0, idxD0, e0_wm, e0_bm, e0_wc, e0_bc,
                                        X1, 5024, 1257, 5024, 40224);
    cc_gemm<16, 16><<<629, 256, 0, stream>>>(X1, ccwE1, CC1, 40224, 64);
    feast_agg<64><<<2520, 256, 0, stream>>>(X1, CC1, nbrD1, e1_bm, AGG1, 1257, 315, 10080);
    lin_gemm<1, 1><<<dim3(158, 2), 256, 0, stream>>>(AGG1, wcrE1, e1_bc, X2, maskE1,
                                                     10080, 576, 128, 315);
    cc_gemm<16, 16><<<158, 256, 0, stream>>>(X2, ccwE2, CC2, 10080, 128);
    feast_agg<128><<<640, 256, 0, stream>>>(X2, CC2, nbrD2, e2_bm, AGG2, 315, 80, 2560);
    lin_gemm<1, 1><<<dim3(40, 4), 256, 0, stream>>>(AGG2, wcrE2, e2_bc, X3, maskE2,
                                                    2560, 1152, 256, 80);

    // ---- bottleneck ----
    fce_mfma<<<dim3(4, 80), 256, 0, stream>>>(X3, fce_w, fce_b, zbuf);
    fcd_mfma<<<320, 256, 0, stream>>>(zbuf, fcd_w, fcd_b, X3P);

    // ---- decoder ----
    cc_gemm<16, 16><<<40, 256, 0, stream>>>(X3P, ccwD0, CCD0, 2560, 256);
    lin_gemm<0, 0><<<dim3(40, 18), 256, 0, stream>>>(X3P, wg0, nullptr, G0, nullptr,
                                                     2560, 256, 1152, 1);
    mix_feast<128><<<2520, 256, 0, stream>>>(G0, CCD0, nbrU2, d0_bm, d0_bc, XD1P,
                                             80, 315, 10080);
    cc_gemm<16, 16><<<158, 256, 0, stream>>>(XD1P, ccwD1, CCD1, 10080, 128);
    lin_gemm<0, 0><<<dim3(158, 9), 256, 0, stream>>>(XD1P, wg1, nullptr, G1, nullptr,
                                                     10080, 128, 576, 1);
    mix_feast<64><<<10056, 256, 0, stream>>>(G1, CCD1, nbrU1, d1_bm, d1_bc, XD2P,
                                             315, 1257, 40224);
    cc_gemm<40, 40><<<629, 256, 0, stream>>>(XD2P, w3, CCGW, 40224, 64);
    mix_d2<<<628, 256, 0, stream>>>(CCGW, nbrU0, d2_bm, d2_bc, (float*)d_out);
}